// Round 2
// baseline (807.433 us; speedup 1.0000x reference)
//
#include <hip/hip_runtime.h>
#include <stdint.h>

// ---------- types / helpers ----------
typedef unsigned short u16;
typedef unsigned int   u32;
typedef __attribute__((ext_vector_type(4))) float f32x4;
typedef __attribute__((ext_vector_type(4))) u32   u32x4;
typedef __attribute__((ext_vector_type(8))) __bf16 bf16x8;

#define MFMA16(a,b,c) __builtin_amdgcn_mfma_f32_16x16x32_bf16((a),(b),(c),0,0,0)

#define QSCALE 0.08838834764831845f   // 128^-0.5
#define RMAX   20480                  // sum roundup(min(n,2048),128) <= 16384+32*127

__device__ __forceinline__ float bf2f(u16 x){ u32 u=((u32)x)<<16; float f; __builtin_memcpy(&f,&u,4); return f; }
__device__ __forceinline__ u16 f2bf(float f){ u32 u; __builtin_memcpy(&u,&f,4); u = u + 0x7FFFu + ((u>>16)&1u); return (u16)(u>>16); }
__device__ __forceinline__ u32 pack2(float a, float b){ return (u32)f2bf(a) | ((u32)f2bf(b)<<16); }

// meta layout (ints): [0,32) n  [32,64) nact  [64,96) npad  [96,129) base  [129,161) nchunks  [161] R_total

// ---------- combined weights: W[(h,m)][c] = sum_d fm[m][d] * w[h*128+d][c] ----------
__global__ __launch_bounds__(256) void k_prep(
  const float* __restrict__ q_w, const float* __restrict__ k_w,
  const float* __restrict__ fmq1, const float* __restrict__ fmq2,
  const float* __restrict__ fmk1, const float* __restrict__ fmk2,
  u16* __restrict__ wA1, u16* __restrict__ wA2,
  u16* __restrict__ wB1, u16* __restrict__ wB2)
{
  __shared__ float fmL[128*128];
  int gi = blockIdx.y;
  const float* fm; const float* ws; u16* wd;
  if (gi < 8)      { fm=fmq1; ws=q_w + (size_t)gi*131072;          wd=wA1 + (size_t)gi*131072; }
  else if (gi < 16){ int h=gi-8;  fm=fmq2; ws=q_w + (size_t)h*131072; wd=wA2 + (size_t)h*131072; }
  else if (gi < 80){ int t=gi-16, e=t>>3, h=t&7; fm=fmk1; ws=k_w + (size_t)(e*8+h)*131072; wd=wB1 + (size_t)(e*8+h)*131072; }
  else             { int t=gi-80, e=t>>3, h=t&7; fm=fmk2; ws=k_w + (size_t)(e*8+h)*131072; wd=wB2 + (size_t)(e*8+h)*131072; }
  int tid = threadIdx.x;
  for (int i=tid; i<4096; i+=256) *(f32x4*)&fmL[i*4] = *(const f32x4*)&fm[i*4];
  __syncthreads();
  int m0 = (blockIdx.x>>1)*32;
  int c  = (blockIdx.x&1)*512 + tid;
  float acc0[32], acc1[32];
  #pragma unroll
  for (int m=0;m<32;m++){ acc0[m]=0.f; acc1[m]=0.f; }
  for (int d=0; d<128; ++d){
    float w0 = ws[(size_t)d*1024 + c];
    float w1 = ws[(size_t)d*1024 + c + 256];
    #pragma unroll
    for (int m=0;m<32;m++){
      float f = fmL[(m0+m)*128 + d];
      acc0[m] += f*w0; acc1[m] += f*w1;
    }
  }
  for (int m=0;m<32;m++){
    wd[(size_t)(m0+m)*1024 + c]       = f2bf(acc0[m]);
    wd[(size_t)(m0+m)*1024 + c + 256] = f2bf(acc1[m]);
  }
}

// ---------- routing: logits, top2 (jax tie semantics), rw ----------
__global__ __launch_bounds__(256) void k_route(const float* __restrict__ x, const float* __restrict__ gw,
  int* __restrict__ sel, float* __restrict__ rw)
{
  int w = threadIdx.x>>6, lane = threadIdx.x&63;
  int tok = blockIdx.x*4 + w;                 // < 8192
  const float* xr = x + (size_t)tok*1024 + lane*16;
  f32x4 xv[4];
  #pragma unroll
  for (int q=0;q<4;q++) xv[q] = *(const f32x4*)(xr + q*4);
  float part[8];
  #pragma unroll
  for (int e=0;e<8;e++){
    const float* g = gw + e*1024 + lane*16;
    float s = 0.f;
    #pragma unroll
    for (int q=0;q<4;q++){
      f32x4 gv = *(const f32x4*)(g + q*4);
      s += xv[q][0]*gv[0] + xv[q][1]*gv[1] + xv[q][2]*gv[2] + xv[q][3]*gv[3];
    }
    part[e]=s;
  }
  #pragma unroll
  for (int e=0;e<8;e++){
    float v = part[e];
    #pragma unroll
    for (int off=32; off>0; off>>=1) v += __shfl_xor(v, off, 64);
    part[e]=v;
  }
  if (lane==0){
    int i0=0; float m0=part[0];
    #pragma unroll
    for (int e=1;e<8;e++) if (part[e]>m0){ m0=part[e]; i0=e; }
    int i1=0; float m1=-3.4e38f;
    #pragma unroll
    for (int e=0;e<8;e++) if (e!=i0 && part[e]>m1){ m1=part[e]; i1=e; }
    sel[tok] = i0 | (i1<<8);
    float e1 = expf(m1-m0);
    float inv = 1.f/(1.f+e1);
    rw[tok*2+0] = inv;
    rw[tok*2+1] = e1*inv;
  }
}

// ---------- per-(b,e) counting sort: ranks, slots, counts ----------
__global__ __launch_bounds__(256) void k_count(const int* __restrict__ sel,
  int* __restrict__ slot_of, int* __restrict__ src_of, int* __restrict__ meta)
{
  int g = blockIdx.x, b = g>>3, e = g&7;
  int tid = threadIdx.x;
  __shared__ int cn[256];
  unsigned char ex[16];
  int cnt=0;
  #pragma unroll
  for (int i=0;i<16;i++){
    int t = tid*16+i;                     // 0..4095 = s*2+k
    int sv = sel[b*2048 + (t>>1)];
    int ee = (t&1) ? ((sv>>8)&255) : (sv&255);
    ex[i]=(unsigned char)ee;
    cnt += (ee==e);
  }
  cn[tid]=cnt;
  __syncthreads();
  for (int off=1; off<256; off<<=1){
    int v = (tid>=off) ? cn[tid-off] : 0;
    __syncthreads();
    cn[tid] += v;
    __syncthreads();
  }
  int total = cn[255];
  int run = cn[tid]-cnt;                  // exclusive prefix
  int shift = total>2048 ? total-2048 : 0;
  #pragma unroll
  for (int i=0;i<16;i++){
    int t = tid*16+i;
    if (ex[i]==e){
      int j = run - shift;
      run++;
      slot_of[b*4096 + t] = (j>=0)? j : -1;
      if (j>=0) src_of[g*2048 + j] = t;
    }
  }
  if (tid==0) meta[g]=total;
}

// ---------- group bases (128-aligned compact layout) ----------
__global__ void k_bases(int* meta){
  if (threadIdx.x || blockIdx.x) return;
  int basev=0;
  meta[96]=0;
  for (int g=0; g<32; ++g){
    int n = meta[g];
    int nact = n<2048 ? n : 2048;
    int npad = (nact+127)&~127;
    meta[32+g]=nact;
    meta[64+g]=npad;
    meta[129+g]=(nact+63)>>6;
    basev += npad;
    meta[97+g]=basev;
  }
  meta[161]=basev;
}

// ---------- gather x rows -> compact bf16 (zero pad) ----------
__global__ __launch_bounds__(256) void k_gather(const float* __restrict__ x,
  const int* __restrict__ src_of, const int* __restrict__ meta, u16* __restrict__ xg)
{
  int g = blockIdx.y, jb = blockIdx.x;
  int npad = meta[64+g];
  if (jb*64 >= npad) return;
  int nact = meta[32+g], base = meta[96+g];
  int tid = threadIdx.x;
  int j = jb*64 + (tid>>2);
  int quart = tid&3;
  int src = (j<nact) ? src_of[g*2048+j] : -1;
  u16* orow = xg + ((size_t)(base+j))*1024 + quart*256;
  if (src>=0){
    const float* xr = x + ((size_t)((g>>3)*2048 + (src>>1)))*1024 + quart*256;
    for (int i=0;i<256;i+=8){
      f32x4 a  = *(const f32x4*)(xr+i);
      f32x4 bv = *(const f32x4*)(xr+i+4);
      u32x4 o;
      o[0]=pack2(a[0],a[1]); o[1]=pack2(a[2],a[3]); o[2]=pack2(bv[0],bv[1]); o[3]=pack2(bv[2],bv[3]);
      *(u32x4*)(orow+i)=o;
    }
  } else {
    u32x4 z = {0,0,0,0};
    for (int i=0;i<256;i+=8) *(u32x4*)(orow+i)=z;
  }
}

// ---------- dual 128x128 MFMA bt-GEMM: out = (A.W1^T) * (A.W2^T) [*QSCALE] ----------
// MODE 0: shared W (q path, apply QSCALE) ; MODE 1: per-expert W (k path)
template<int MODE>
__global__ __launch_bounds__(256) void k_gemm2(const u16* __restrict__ A,
  const u16* __restrict__ W1, const u16* __restrict__ W2,
  u16* __restrict__ outB, const int* __restrict__ meta)
{
  int tm = blockIdx.y, tn = blockIdx.x;
  int M = meta[161];
  if (tm*128 >= M) return;
  const u16 *W1p=W1, *W2p=W2;
  if (MODE==1){
    int row0 = tm*128, g=0;
    while (meta[97+g] <= row0) ++g;
    W1p = W1 + (size_t)(g&7)*1048576;
    W2p = W2 + (size_t)(g&7)*1048576;
  }
  __shared__ __align__(16) u16 As[128*72];
  __shared__ __align__(16) u16 Bs1[128*72];
  __shared__ __align__(16) u16 Bs2[128*72];
  int tid=threadIdx.x, w=tid>>6, lane=tid&63;
  int wr=w>>1, wc=w&1;
  const f32x4 Z4 = {0.f,0.f,0.f,0.f};
  f32x4 acc1[4][4], acc2[4][4];
  #pragma unroll
  for(int i=0;i<4;i++){
    #pragma unroll
    for(int j=0;j<4;j++){ acc1[i][j]=Z4; acc2[i][j]=Z4; }
  }
  const u16* Abase = A   + (size_t)tm*128*1024;
  const u16* B1b   = W1p + (size_t)tn*128*1024;
  const u16* B2b   = W2p + (size_t)tn*128*1024;
  for (int kt=0; kt<16; ++kt){
    #pragma unroll
    for (int it=0; it<12; ++it){
      int id = tid + it*256;
      int buf = id>>10, rem = id&1023;
      int row = rem>>3, kc = rem&7;
      const u16* s = (buf==0)? Abase : (buf==1)? B1b : B2b;
      u16* d = (buf==0)? As : (buf==1)? Bs1 : Bs2;
      *(u32x4*)&d[row*72 + kc*8] = *(const u32x4*)(s + (size_t)row*1024 + kt*64 + kc*8);
    }
    __syncthreads();
    #pragma unroll
    for (int kk=0; kk<2; ++kk){
      bf16x8 a[4], b1[4], b2[4];
      #pragma unroll
      for (int mi=0;mi<4;mi++) a[mi]  = *(const bf16x8*)&As [(wr*64+mi*16+(lane&15))*72 + kk*32 + (lane>>4)*8];
      #pragma unroll
      for (int ni=0;ni<4;ni++) b1[ni] = *(const bf16x8*)&Bs1[(wc*64+ni*16+(lane&15))*72 + kk*32 + (lane>>4)*8];
      #pragma unroll
      for (int ni=0;ni<4;ni++) b2[ni] = *(const bf16x8*)&Bs2[(wc*64+ni*16+(lane&15))*72 + kk*32 + (lane>>4)*8];
      #pragma unroll
      for (int mi=0;mi<4;mi++){
        #pragma unroll
        for (int ni=0;ni<4;ni++){
          acc1[mi][ni] = MFMA16(a[mi], b1[ni], acc1[mi][ni]);
          acc2[mi][ni] = MFMA16(a[mi], b2[ni], acc2[mi][ni]);
        }
      }
    }
    __syncthreads();
  }
  int r0=(lane>>4)*4, c0=lane&15;
  #pragma unroll
  for (int mi=0;mi<4;mi++){
    #pragma unroll
    for (int ni=0;ni<4;ni++){
      int col = tn*128 + wc*64 + ni*16 + c0;
      #pragma unroll
      for (int r=0;r<4;r++){
        int row = tm*128 + wr*64 + mi*16 + r0 + r;
        float v = acc1[mi][ni][r]*acc2[mi][ni][r];
        if (MODE==0) v *= QSCALE;
        outB[(size_t)row*1024 + col] = f2bf(v);
      }
    }
  }
}

// ---------- single 128x128 MFMA bt-GEMM with f32 weights: C = A.W^T ----------
// PEREXP: per-expert W offset ; OUTF: f32 output (else bf16)
template<int PEREXP, int OUTF>
__global__ __launch_bounds__(256) void k_gemm1(const u16* __restrict__ A, const float* __restrict__ W,
  u16* __restrict__ outB, float* __restrict__ outF, const int* __restrict__ meta, int Mfixed)
{
  int tm = blockIdx.y, tn = blockIdx.x;
  int M = Mfixed ? Mfixed : meta[161];
  if (tm*128 >= M) return;
  const float* Wp = W;
  if (PEREXP){
    int row0 = tm*128, g=0;
    while (meta[97+g] <= row0) ++g;
    Wp = W + (size_t)(g&7)*1048576;
  }
  __shared__ __align__(16) u16 As[128*72];
  __shared__ __align__(16) u16 Bs[128*72];
  int tid=threadIdx.x, w=tid>>6, lane=tid&63;
  int wr=w>>1, wc=w&1;
  const f32x4 Z4 = {0.f,0.f,0.f,0.f};
  f32x4 acc[4][4];
  #pragma unroll
  for(int i=0;i<4;i++){
    #pragma unroll
    for(int j=0;j<4;j++) acc[i][j]=Z4;
  }
  const u16* Abase  = A  + (size_t)tm*128*1024;
  const float* Bbase= Wp + (size_t)tn*128*1024;
  for (int kt=0; kt<16; ++kt){
    #pragma unroll
    for (int it=0; it<8; ++it){
      int id = tid + it*256;
      int buf = id>>10, rem = id&1023;
      int row = rem>>3, kc = rem&7;
      if (buf==0){
        *(u32x4*)&As[row*72 + kc*8] = *(const u32x4*)(Abase + (size_t)row*1024 + kt*64 + kc*8);
      } else {
        const float* src = Bbase + (size_t)row*1024 + kt*64 + kc*8;
        f32x4 w0 = *(const f32x4*)src;
        f32x4 w1 = *(const f32x4*)(src+4);
        u32x4 o;
        o[0]=pack2(w0[0],w0[1]); o[1]=pack2(w0[2],w0[3]); o[2]=pack2(w1[0],w1[1]); o[3]=pack2(w1[2],w1[3]);
        *(u32x4*)&Bs[row*72 + kc*8] = o;
      }
    }
    __syncthreads();
    #pragma unroll
    for (int kk=0; kk<2; ++kk){
      bf16x8 a[4], b[4];
      #pragma unroll
      for (int mi=0;mi<4;mi++) a[mi] = *(const bf16x8*)&As[(wr*64+mi*16+(lane&15))*72 + kk*32 + (lane>>4)*8];
      #pragma unroll
      for (int ni=0;ni<4;ni++) b[ni] = *(const bf16x8*)&Bs[(wc*64+ni*16+(lane&15))*72 + kk*32 + (lane>>4)*8];
      #pragma unroll
      for (int mi=0;mi<4;mi++){
        #pragma unroll
        for (int ni=0;ni<4;ni++)
          acc[mi][ni] = MFMA16(a[mi], b[ni], acc[mi][ni]);
      }
    }
    __syncthreads();
  }
  int r0=(lane>>4)*4, c0=lane&15;
  #pragma unroll
  for (int mi=0;mi<4;mi++){
    #pragma unroll
    for (int ni=0;ni<4;ni++){
      int col = tn*128 + wc*64 + ni*16 + c0;
      #pragma unroll
      for (int r=0;r<4;r++){
        int row = tm*128 + wr*64 + mi*16 + r0 + r;
        if (OUTF) outF[(size_t)row*1024 + col] = acc[mi][ni][r];
        else      outB[(size_t)row*1024 + col] = f2bf(acc[mi][ni][r]);
      }
    }
  }
}

// ---------- chunked causal linear attention, one block per (group, head) ----------
__global__ __launch_bounds__(256,1) void k_attn(const u16* __restrict__ qv, const u16* __restrict__ kv,
  const u16* __restrict__ vv, u16* __restrict__ o, const int* __restrict__ meta)
{
  int g = blockIdx.x>>3, h = blockIdx.x&7;
  int nch = meta[129+g];
  if (nch==0) return;
  int base = meta[96+g];
  __shared__ __align__(16) u16 Qs[64*136];
  __shared__ __align__(16) u16 Ks[64*136];
  __shared__ __align__(16) u16 KTs[128*72];
  __shared__ __align__(16) u16 VTs[128*72];
  __shared__ __align__(16) u16 Ts[128*136];   // T = S^T (e-major), bf16 copy of state
  __shared__ __align__(16) u16 Ps[64*72];
  int tid=threadIdx.x, w=tid>>6, lane=tid&63;
  int wr=w>>1, wc=w&1;
  int lr=lane>>4, lc=lane&15;
  {
    u32x4 z={0,0,0,0};
    for (int i=tid; i<128*136/8; i+=256) *(u32x4*)&Ts[i*8]=z;
  }
  const f32x4 Z4 = {0.f,0.f,0.f,0.f};
  f32x4 accT[4][4];
  #pragma unroll
  for (int i=0;i<4;i++){
    #pragma unroll
    for (int j=0;j<4;j++) accT[i][j]=Z4;
  }
  __syncthreads();
  const u16* qb = qv + (size_t)base*1024 + h*128;
  const u16* kb = kv + (size_t)base*1024 + h*128;
  const u16* vb = vv + (size_t)base*1024 + h*128;
  u16* ob = o + (size_t)base*1024 + h*128;

  for (int c=0; c<nch; ++c){
    // stage q,k row-major
    #pragma unroll
    for (int it=0; it<4; ++it){
      int id = tid + it*256;
      int row = id>>4, kc = id&15;
      *(u32x4*)&Qs[row*136 + kc*8] = *(const u32x4*)(qb + (size_t)(c*64+row)*1024 + kc*8);
      *(u32x4*)&Ks[row*136 + kc*8] = *(const u32x4*)(kb + (size_t)(c*64+row)*1024 + kc*8);
    }
    // transpose-stage k^T, v^T straight from global
    #pragma unroll
    for (int it=0; it<4; ++it){
      int id = tid + it*256;
      int j = id>>4, dg = id&15;
      u32x4 kx = *(const u32x4*)(kb + (size_t)(c*64+j)*1024 + dg*8);
      u32x4 vx = *(const u32x4*)(vb + (size_t)(c*64+j)*1024 + dg*8);
      #pragma unroll
      for (int t=0;t<4;t++){
        KTs[(dg*8+t*2  )*72 + j] = (u16)(kx[t]&0xffff);
        KTs[(dg*8+t*2+1)*72 + j] = (u16)(kx[t]>>16);
        VTs[(dg*8+t*2  )*72 + j] = (u16)(vx[t]&0xffff);
        VTs[(dg*8+t*2+1)*72 + j] = (u16)(vx[t]>>16);
      }
    }
    __syncthreads();
    // q fragments (shared between inter and P)
    bf16x8 qf[2][4];
    #pragma unroll
    for (int ti=0; ti<2; ++ti){
      #pragma unroll
      for (int ks=0; ks<4; ++ks)
        qf[ti][ks] = *(const bf16x8*)&Qs[(wr*32+ti*16+lc)*136 + ks*32 + lr*8];
    }
    f32x4 accO[2][4];
    #pragma unroll
    for (int i=0;i<2;i++){
      #pragma unroll
      for (int j=0;j<4;j++) accO[i][j]=Z4;
    }
    // inter = q . S  (S[d][e] = Ts[e][d]); uses OLD Ts
    #pragma unroll
    for (int ks=0; ks<4; ++ks){
      bf16x8 bt[4];
      #pragma unroll
      for (int te=0; te<4; ++te)
        bt[te] = *(const bf16x8*)&Ts[(wc*64+te*16+lc)*136 + ks*32 + lr*8];
      #pragma unroll
      for (int ti=0; ti<2; ++ti){
        #pragma unroll
        for (int te=0; te<4; ++te)
          accO[ti][te] = MFMA16(qf[ti][ks], bt[te], accO[ti][te]);
      }
    }
    // P = q . k^T (causal masked)
    f32x4 accP[2][2];
    #pragma unroll
    for (int i=0;i<2;i++){
      #pragma unroll
      for (int j=0;j<2;j++) accP[i][j]=Z4;
    }
    #pragma unroll
    for (int ks=0; ks<4; ++ks){
      bf16x8 bk[2];
      #pragma unroll
      for (int tj=0; tj<2; ++tj)
        bk[tj] = *(const bf16x8*)&Ks[(wc*32+tj*16+lc)*136 + ks*32 + lr*8];
      #pragma unroll
      for (int ti=0; ti<2; ++ti){
        #pragma unroll
        for (int tj=0; tj<2; ++tj)
          accP[ti][tj] = MFMA16(qf[ti][ks], bk[tj], accP[ti][tj]);
      }
    }
    #pragma unroll
    for (int ti=0; ti<2; ++ti){
      #pragma unroll
      for (int tj=0; tj<2; ++tj){
        #pragma unroll
        for (int r=0;r<4;r++){
          int i = wr*32+ti*16+lr*4+r;
          int j = wc*32+tj*16+lc;
          Ps[i*72 + j] = f2bf( (j<=i) ? accP[ti][tj][r] : 0.f );
        }
      }
    }
    __syncthreads();
    // intra = P . V   (B rows from VTs)
    #pragma unroll
    for (int ks=0; ks<2; ++ks){
      bf16x8 ap[2], bv[4];
      #pragma unroll
      for (int ti=0; ti<2; ++ti)
        ap[ti] = *(const bf16x8*)&Ps[(wr*32+ti*16+lc)*72 + ks*32 + lr*8];
      #pragma unroll
      for (int te=0; te<4; ++te)
        bv[te] = *(const bf16x8*)&VTs[(wc*64+te*16+lc)*72 + ks*32 + lr*8];
      #pragma unroll
      for (int ti=0; ti<2; ++ti){
        #pragma unroll
        for (int te=0; te<4; ++te)
          accO[ti][te] = MFMA16(ap[ti], bv[te], accO[ti][te]);
      }
    }
    // state: T[e][dk] += sum_j v[j][e] k[j][dk]
    #pragma unroll
    for (int ks=0; ks<2; ++ks){
      bf16x8 av[4], bk2[4];
      #pragma unroll
      for (int te=0; te<4; ++te)
        av[te] = *(const bf16x8*)&VTs[(wr*64+te*16+lc)*72 + ks*32 + lr*8];
      #pragma unroll
      for (int td=0; td<4; ++td)
        bk2[td] = *(const bf16x8*)&KTs[(wc*64+td*16+lc)*72 + ks*32 + lr*8];
      #pragma unroll
      for (int te=0; te<4; ++te){
        #pragma unroll
        for (int td=0; td<4; ++td)
          accT[te][td] = MFMA16(av[te], bk2[td], accT[te][td]);
      }
    }
    // write O chunk (bf16)
    #pragma unroll
    for (int ti=0; ti<2; ++ti){
      #pragma unroll
      for (int te=0; te<4; ++te){
        int ecol = wc*64+te*16+lc;
        #pragma unroll
        for (int r=0;r<4;r++){
          int i = wr*32+ti*16+lr*4+r;
          ob[(size_t)(c*64+i)*1024 + ecol] = f2bf(accO[ti][te][r]);
        }
      }
    }
    __syncthreads();   // all inter reads of Ts are done
    // refresh bf16 state copy from f32 accumulators
    #pragma unroll
    for (int te=0; te<4; ++te){
      #pragma unroll
      for (int td=0; td<4; ++td){
        int dk = wc*64+td*16+lc;
        #pragma unroll
        for (int r=0;r<4;r++){
          int erow = wr*64+te*16+lr*4+r;
          Ts[erow*136 + dk] = f2bf(accT[te][td][r]);
        }
      }
    }
    __syncthreads();
  }
}

// ---------- combine (rw-weighted sum) + per-head RMSNorm -> fin bf16 ----------
__global__ __launch_bounds__(256) void k_comb(const u16* __restrict__ o, const int* __restrict__ sel,
  const float* __restrict__ rw, const int* __restrict__ slot_of, const int* __restrict__ meta,
  const float* __restrict__ nw, u16* __restrict__ fin)
{
  int w=threadIdx.x>>6, lane=threadIdx.x&63;
  int tok = blockIdx.x*4 + w;           // b*2048+s
  int b = tok>>11;
  int sv = sel[tok];
  float acc[16];
  #pragma unroll
  for (int i=0;i<16;i++) acc[i]=0.f;
  #pragma unroll
  for (int kk=0; kk<2; ++kk){
    int e = kk ? ((sv>>8)&255) : (sv&255);
    int j = slot_of[tok*2 + kk];
    if (j < 0) continue;
    float wgt = rw[tok*2+kk];
    int row = meta[96 + b*8 + e] + j;
    const u16* orow = o + (size_t)row*1024 + lane*16;
    #pragma unroll
    for (int q=0;q<2;q++){
      u32x4 v = *(const u32x4*)(orow + q*8);
      #pragma unroll
      for (int t=0;t<4;t++){
        acc[q*8+t*2]   += wgt * bf2f((u16)(v[t]&0xffff));
        acc[q*8+t*2+1] += wgt * bf2f((u16)(v[t]>>16));
      }
    }
  }
  float ssq=0.f;
  #pragma unroll
  for (int i=0;i<16;i++) ssq += acc[i]*acc[i];
  ssq += __shfl_xor(ssq,1,64);
  ssq += __shfl_xor(ssq,2,64);
  ssq += __shfl_xor(ssq,4,64);           // head = 8 lanes (128 elems)
  float sc = rsqrtf(ssq*(1.f/128.f) + 1e-5f);
  int cbase = (lane&7)*16;
  u32x4 o0, o1;
  #pragma unroll
  for (int t=0;t<4;t++)
    o0[t] = pack2(acc[2*t]*sc*nw[cbase+2*t], acc[2*t+1]*sc*nw[cbase+2*t+1]);
  #pragma unroll
  for (int t=0;t<4;t++)
    o1[t] = pack2(acc[8+2*t]*sc*nw[cbase+8+2*t], acc[8+2*t+1]*sc*nw[cbase+8+2*t+1]);
  u16* fp = fin + (size_t)tok*1024 + lane*16;
  *(u32x4*)fp     = o0;
  *(u32x4*)(fp+8) = o1;
}

// ---------- host launcher ----------
extern "C" void kernel_launch(void* const* d_in, const int* in_sizes, int n_in,
                              void* d_out, int out_size, void* d_ws, size_t ws_size,
                              hipStream_t stream)
{
  (void)in_sizes; (void)n_in;
  const float* x     = (const float*)d_in[0];
  const float* gate  = (const float*)d_in[1];
  const float* q_w   = (const float*)d_in[2];
  const float* k_w   = (const float*)d_in[3];
  const float* v_w   = (const float*)d_in[4];
  const float* fmq1  = (const float*)d_in[5];
  const float* fmq2  = (const float*)d_in[6];
  const float* fmk1  = (const float*)d_in[7];
  const float* fmk2  = (const float*)d_in[8];
  const float* norm_w= (const float*)d_in[9];
  const float* o_w   = (const float*)d_in[10];
  float* out = (float*)d_out;

  uint8_t* ws = (uint8_t*)d_ws;
  size_t off = 0;
  auto alloc = [&](size_t bytes)->void*{ void* p = ws + off; off += (bytes + 255) & ~(size_t)255; return p; };
  int*   meta = (int*)alloc(4096);
  int*   sel  = (int*)alloc(8192*4);
  float* rwb  = (float*)alloc(8192*2*4);
  int*   slot = (int*)alloc(16384*4);
  int*   srcf = (int*)alloc((size_t)32*2048*4);
  u16* wA1 = (u16*)alloc((size_t)1048576*2);
  u16* wA2 = (u16*)alloc((size_t)1048576*2);
  u16* wB1 = (u16*)alloc((size_t)8388608*2);
  u16* wB2 = (u16*)alloc((size_t)8388608*2);
  u16* xg  = (u16*)alloc((size_t)RMAX*1024*2);
  u16* qh  = (u16*)alloc((size_t)RMAX*1024*2);
  u16* kh  = (u16*)alloc((size_t)RMAX*1024*2);
  u16* vv  = (u16*)alloc((size_t)RMAX*1024*2);
  if (off > ws_size){
    // sentinel: absmax ~3.4e38 signals "workspace too small"
    hipMemsetAsync(d_out, 0x7F, (size_t)out_size*4, stream);
    return;
  }
  u16* ob  = xg;   // reuse after GEMMs consumed xg
  u16* fin = qh;   // reuse after attn consumed qh

  k_prep<<<dim3(8,144),256,0,stream>>>(q_w, k_w, fmq1, fmq2, fmk1, fmk2, wA1, wA2, wB1, wB2);
  k_route<<<2048,256,0,stream>>>(x, gate, sel, rwb);
  k_count<<<32,256,0,stream>>>(sel, slot, srcf, meta);
  k_bases<<<1,64,0,stream>>>(meta);
  k_gather<<<dim3(32,32),256,0,stream>>>(x, srcf, meta, xg);
  k_gemm2<0><<<dim3(8,160),256,0,stream>>>(xg, wA1, wA2, qh, meta);
  k_gemm2<1><<<dim3(8,160),256,0,stream>>>(xg, wB1, wB2, kh, meta);
  k_gemm1<1,0><<<dim3(8,160),256,0,stream>>>(xg, v_w, vv, nullptr, meta, 0);
  k_attn<<<256,256,0,stream>>>(qh, kh, vv, ob, meta);
  k_comb<<<2048,256,0,stream>>>(ob, sel, rwb, slot, meta, norm_w, fin);
  k_gemm1<0,1><<<dim3(8,64),256,0,stream>>>(fin, o_w, nullptr, out, meta, 8192);
}

// Round 3
// 686.632 us; speedup vs baseline: 1.1759x; 1.1759x over previous
//
#include <hip/hip_runtime.h>
#include <stdint.h>

// ---------- types / helpers ----------
typedef unsigned short u16;
typedef unsigned int   u32;
typedef __attribute__((ext_vector_type(4))) float f32x4;
typedef __attribute__((ext_vector_type(4))) u32   u32x4;
typedef __attribute__((ext_vector_type(8))) __bf16 bf16x8;

#define MFMA16(a,b,c) __builtin_amdgcn_mfma_f32_16x16x32_bf16((a),(b),(c),0,0,0)

#define QSCALE 0.08838834764831845f   // 128^-0.5
#define RMAX   20480                  // sum roundup(min(n,2048),128) <= 16384+32*127

__device__ __forceinline__ float bf2f(u16 x){ u32 u=((u32)x)<<16; float f; __builtin_memcpy(&f,&u,4); return f; }
__device__ __forceinline__ u16 f2bf(float f){ u32 u; __builtin_memcpy(&u,&f,4); u = u + 0x7FFFu + ((u>>16)&1u); return (u16)(u>>16); }
__device__ __forceinline__ u32 pack2(float a, float b){ return (u32)f2bf(a) | ((u32)f2bf(b)<<16); }

// async global->LDS, 16B per lane; LDS side is wave-uniform base + lane*16
__device__ __forceinline__ void gl_lds(const u16* g, u16* l){
  __builtin_amdgcn_global_load_lds(
      (const __attribute__((address_space(1))) void*)g,
      (__attribute__((address_space(3))) void*)l, 16, 0, 0);
}

// meta layout (ints): [0,32) n  [32,64) nact  [64,96) npad  [96,129) base
// [129,161) nchunks  [161] R_total  [192,352) tile->group map

// ---------- f32 -> bf16 convert ----------
__global__ __launch_bounds__(256) void k_cvt(const float* __restrict__ s, u16* __restrict__ d, long n8){
  long idx = (long)blockIdx.x*256 + threadIdx.x;
  long stride = (long)gridDim.x*256;
  for (long i=idx; i<n8; i+=stride){
    const float* p = s + i*8;
    f32x4 a = *(const f32x4*)p;
    f32x4 b = *(const f32x4*)(p+4);
    u32x4 o;
    o[0]=pack2(a[0],a[1]); o[1]=pack2(a[2],a[3]); o[2]=pack2(b[0],b[1]); o[3]=pack2(b[2],b[3]);
    *(u32x4*)(d + i*8) = o;
  }
}

// ---------- combined weights via MFMA: W[(h,m)][c] = sum_d fm[m][d] * w[h*128+d][c] ----------
__global__ __launch_bounds__(256) void k_prep(
  const float* __restrict__ q_w, const float* __restrict__ k_w,
  const float* __restrict__ fmq1, const float* __restrict__ fmq2,
  const float* __restrict__ fmk1, const float* __restrict__ fmk2,
  u16* __restrict__ wA1, u16* __restrict__ wA2,
  u16* __restrict__ wB1, u16* __restrict__ wB2)
{
  int gi = blockIdx.y;
  const float* fm; const float* ws; u16* wd;
  if (gi < 8)      { fm=fmq1; ws=q_w + (size_t)gi*131072;          wd=wA1 + (size_t)gi*131072; }
  else if (gi < 16){ int h=gi-8;  fm=fmq2; ws=q_w + (size_t)h*131072; wd=wA2 + (size_t)h*131072; }
  else if (gi < 80){ int t=gi-16, e=t>>3, h=t&7; fm=fmk1; ws=k_w + (size_t)(e*8+h)*131072; wd=wB1 + (size_t)(e*8+h)*131072; }
  else             { int t=gi-80, e=t>>3, h=t&7; fm=fmk2; ws=k_w + (size_t)(e*8+h)*131072; wd=wB2 + (size_t)(e*8+h)*131072; }
  int c0 = blockIdx.x*128;
  __shared__ __align__(16) u16 Af[128*136];
  __shared__ __align__(16) u16 Bf[128*136];
  int tid = threadIdx.x;
  // stage A = fm (128x128 f32 -> bf16, row-major)
  for (int i=tid; i<4096; i+=256){
    int row = i>>5, col = (i&31)*4;
    f32x4 v = *(const f32x4*)&fm[row*128 + col];
    u16* dp = &Af[row*136 + col];
    *(u32*)dp     = pack2(v[0],v[1]);
    *(u32*)(dp+2) = pack2(v[2],v[3]);
  }
  // stage B = w[d][c0:c0+128] transposed -> Bf[c][d ^ swz(c)]
  for (int i=tid; i<4096; i+=256){
    int dd = i>>5, cq = (i&31)*4;
    f32x4 v = *(const f32x4*)&ws[(size_t)dd*1024 + c0 + cq];
    #pragma unroll
    for (int j=0;j<4;j++){
      int c = cq+j;
      Bf[c*136 + (dd ^ (((c>>2)&3)<<3))] = f2bf(v[j]);
    }
  }
  __syncthreads();
  int lane=tid&63, w=tid>>6, wr=w>>1, wc=w&1, lc=lane&15, lr=lane>>4;
  const f32x4 Z4 = {0.f,0.f,0.f,0.f};
  f32x4 acc[4][4];
  #pragma unroll
  for (int i=0;i<4;i++){
    #pragma unroll
    for (int j=0;j<4;j++) acc[i][j]=Z4;
  }
  #pragma unroll
  for (int kk=0; kk<4; ++kk){
    bf16x8 a[4], b[4];
    #pragma unroll
    for (int mi=0;mi<4;mi++)
      a[mi] = *(const bf16x8*)&Af[(wr*64+mi*16+lc)*136 + kk*32 + lr*8];
    #pragma unroll
    for (int ni=0;ni<4;ni++){
      int c = wc*64+ni*16+lc;
      b[ni] = *(const bf16x8*)&Bf[c*136 + ((kk*32 + lr*8) ^ (((c>>2)&3)<<3))];
    }
    #pragma unroll
    for (int mi=0;mi<4;mi++){
      #pragma unroll
      for (int ni=0;ni<4;ni++)
        acc[mi][ni] = MFMA16(a[mi], b[ni], acc[mi][ni]);
    }
  }
  int r0=lr*4;
  #pragma unroll
  for (int mi=0;mi<4;mi++){
    #pragma unroll
    for (int ni=0;ni<4;ni++){
      int col = c0 + wc*64 + ni*16 + lc;
      #pragma unroll
      for (int r=0;r<4;r++){
        int row = wr*64 + mi*16 + r0 + r;
        wd[(size_t)row*1024 + col] = f2bf(acc[mi][ni][r]);
      }
    }
  }
}

// ---------- routing: logits, top2 (jax tie semantics), rw ----------
__global__ __launch_bounds__(256) void k_route(const float* __restrict__ x, const float* __restrict__ gw,
  int* __restrict__ sel, float* __restrict__ rw)
{
  int w = threadIdx.x>>6, lane = threadIdx.x&63;
  int tok = blockIdx.x*4 + w;                 // < 8192
  const float* xr = x + (size_t)tok*1024 + lane*16;
  f32x4 xv[4];
  #pragma unroll
  for (int q=0;q<4;q++) xv[q] = *(const f32x4*)(xr + q*4);
  float part[8];
  #pragma unroll
  for (int e=0;e<8;e++){
    const float* g = gw + e*1024 + lane*16;
    float s = 0.f;
    #pragma unroll
    for (int q=0;q<4;q++){
      f32x4 gv = *(const f32x4*)(g + q*4);
      s += xv[q][0]*gv[0] + xv[q][1]*gv[1] + xv[q][2]*gv[2] + xv[q][3]*gv[3];
    }
    part[e]=s;
  }
  #pragma unroll
  for (int e=0;e<8;e++){
    float v = part[e];
    #pragma unroll
    for (int off=32; off>0; off>>=1) v += __shfl_xor(v, off, 64);
    part[e]=v;
  }
  if (lane==0){
    int i0=0; float m0=part[0];
    #pragma unroll
    for (int e=1;e<8;e++) if (part[e]>m0){ m0=part[e]; i0=e; }
    int i1=0; float m1=-3.4e38f;
    #pragma unroll
    for (int e=0;e<8;e++) if (e!=i0 && part[e]>m1){ m1=part[e]; i1=e; }
    sel[tok] = i0 | (i1<<8);
    float e1 = expf(m1-m0);
    float inv = 1.f/(1.f+e1);
    rw[tok*2+0] = inv;
    rw[tok*2+1] = e1*inv;
  }
}

// ---------- per-(b,e) counting sort: ranks, slots, counts ----------
__global__ __launch_bounds__(256) void k_count(const int* __restrict__ sel,
  int* __restrict__ slot_of, int* __restrict__ src_of, int* __restrict__ meta)
{
  int g = blockIdx.x, b = g>>3, e = g&7;
  int tid = threadIdx.x;
  __shared__ int cn[256];
  unsigned char ex[16];
  int cnt=0;
  #pragma unroll
  for (int i=0;i<16;i++){
    int t = tid*16+i;                     // 0..4095 = s*2+k
    int sv = sel[b*2048 + (t>>1)];
    int ee = (t&1) ? ((sv>>8)&255) : (sv&255);
    ex[i]=(unsigned char)ee;
    cnt += (ee==e);
  }
  cn[tid]=cnt;
  __syncthreads();
  for (int off=1; off<256; off<<=1){
    int v = (tid>=off) ? cn[tid-off] : 0;
    __syncthreads();
    cn[tid] += v;
    __syncthreads();
  }
  int total = cn[255];
  int run = cn[tid]-cnt;                  // exclusive prefix
  int shift = total>2048 ? total-2048 : 0;
  #pragma unroll
  for (int i=0;i<16;i++){
    int t = tid*16+i;
    if (ex[i]==e){
      int j = run - shift;
      run++;
      slot_of[b*4096 + t] = (j>=0)? j : -1;
      if (j>=0) src_of[g*2048 + j] = t;
    }
  }
  if (tid==0) meta[g]=total;
}

// ---------- group bases (128-aligned compact layout) + tile->group map ----------
__global__ void k_bases(int* meta){
  if (threadIdx.x || blockIdx.x) return;
  int basev=0, t=0;
  meta[96]=0;
  for (int g=0; g<32; ++g){
    int n = meta[g];
    int nact = n<2048 ? n : 2048;
    int npad = (nact+127)&~127;
    meta[32+g]=nact;
    meta[64+g]=npad;
    meta[129+g]=(nact+63)>>6;
    for (int i=0;i<(npad>>7);++i) meta[192+t++]=g;
    basev += npad;
    meta[97+g]=basev;
  }
  meta[161]=basev;
}

// ---------- gather x rows -> compact bf16 (zero pad) ----------
__global__ __launch_bounds__(256) void k_gather(const float* __restrict__ x,
  const int* __restrict__ src_of, const int* __restrict__ meta, u16* __restrict__ xg)
{
  int g = blockIdx.y, jb = blockIdx.x;
  int npad = meta[64+g];
  if (jb*64 >= npad) return;
  int nact = meta[32+g], base = meta[96+g];
  int tid = threadIdx.x;
  int j = jb*64 + (tid>>2);
  int quart = tid&3;
  int src = (j<nact) ? src_of[g*2048+j] : -1;
  u16* orow = xg + ((size_t)(base+j))*1024 + quart*256;
  if (src>=0){
    const float* xr = x + ((size_t)((g>>3)*2048 + (src>>1)))*1024 + quart*256;
    for (int i=0;i<256;i+=8){
      f32x4 a  = *(const f32x4*)(xr+i);
      f32x4 bv = *(const f32x4*)(xr+i+4);
      u32x4 o;
      o[0]=pack2(a[0],a[1]); o[1]=pack2(a[2],a[3]); o[2]=pack2(bv[0],bv[1]); o[3]=pack2(bv[2],bv[3]);
      *(u32x4*)(orow+i)=o;
    }
  } else {
    u32x4 z = {0,0,0,0};
    for (int i=0;i<256;i+=8) *(u32x4*)(orow+i)=z;
  }
}

// ---------- dual 128x128 MFMA bt-GEMM (global_load_lds): out = (A.W1^T)*(A.W2^T) [*QSCALE] ----------
// MODE 0: shared W (q path, QSCALE) ; MODE 1: per-expert W (k path)
template<int MODE>
__global__ __launch_bounds__(256) void k_gemm2(const u16* __restrict__ A,
  const u16* __restrict__ W1, const u16* __restrict__ W2,
  u16* __restrict__ outB, const int* __restrict__ meta)
{
  int tm = blockIdx.y, tn = blockIdx.x;
  if (tm*128 >= meta[161]) return;
  const u16 *W1p=W1, *W2p=W2;
  if (MODE==1){
    int g = meta[192+tm]&7;
    W1p = W1 + (size_t)g*1048576;
    W2p = W2 + (size_t)g*1048576;
  }
  __shared__ __align__(16) u16 As [128*64];
  __shared__ __align__(16) u16 B1s[128*64];
  __shared__ __align__(16) u16 B2s[128*64];
  int tid=threadIdx.x, lane=tid&63;
  int w=tid>>6, wr=w>>1, wc=w&1, lc=lane&15, lr=lane>>4;
  const f32x4 Z4 = {0.f,0.f,0.f,0.f};
  f32x4 acc1[4][4], acc2[4][4];
  #pragma unroll
  for(int i=0;i<4;i++){
    #pragma unroll
    for(int j=0;j<4;j++){ acc1[i][j]=Z4; acc2[i][j]=Z4; }
  }
  // per-lane global base: row tid>>3 (+32/iter), 16B chunk tid&7
  size_t lanoff = (size_t)(tid>>3)*1024 + (tid&7)*8;
  const u16* Ab  = A   + (size_t)tm*131072 + lanoff;
  const u16* B1b = W1p + (size_t)tn*131072 + lanoff;
  const u16* B2b = W2p + (size_t)tn*131072 + lanoff;
  for (int kt=0; kt<16; ++kt){
    #pragma unroll
    for (int it=0; it<4; ++it){
      size_t go = (size_t)it*32768 + kt*64;
      int lo = it*2048 + tid*8;
      gl_lds(Ab  + go, &As [lo]);
      gl_lds(B1b + go, &B1s[lo]);
      gl_lds(B2b + go, &B2s[lo]);
    }
    __syncthreads();
    #pragma unroll
    for (int kk=0; kk<2; ++kk){
      bf16x8 a[4], b1[4], b2[4];
      #pragma unroll
      for (int mi=0;mi<4;mi++) a[mi]  = *(const bf16x8*)&As [(wr*64+mi*16+lc)*64 + kk*32 + lr*8];
      #pragma unroll
      for (int ni=0;ni<4;ni++) b1[ni] = *(const bf16x8*)&B1s[(wc*64+ni*16+lc)*64 + kk*32 + lr*8];
      #pragma unroll
      for (int ni=0;ni<4;ni++) b2[ni] = *(const bf16x8*)&B2s[(wc*64+ni*16+lc)*64 + kk*32 + lr*8];
      #pragma unroll
      for (int mi=0;mi<4;mi++){
        #pragma unroll
        for (int ni=0;ni<4;ni++){
          acc1[mi][ni] = MFMA16(a[mi], b1[ni], acc1[mi][ni]);
          acc2[mi][ni] = MFMA16(a[mi], b2[ni], acc2[mi][ni]);
        }
      }
    }
    __syncthreads();
  }
  int r0=lr*4;
  #pragma unroll
  for (int mi=0;mi<4;mi++){
    #pragma unroll
    for (int ni=0;ni<4;ni++){
      int col = tn*128 + wc*64 + ni*16 + lc;
      #pragma unroll
      for (int r=0;r<4;r++){
        int row = tm*128 + wr*64 + mi*16 + r0 + r;
        float v = acc1[mi][ni][r]*acc2[mi][ni][r];
        if (MODE==0) v *= QSCALE;
        outB[(size_t)row*1024 + col] = f2bf(v);
      }
    }
  }
}

// ---------- single 128x128 MFMA bt-GEMM (global_load_lds, bf16 W) ----------
// PEREXP: per-expert W ; OUTF: f32 output
template<int PEREXP, int OUTF>
__global__ __launch_bounds__(256) void k_gemmS(const u16* __restrict__ A, const u16* __restrict__ W,
  u16* __restrict__ outB, float* __restrict__ outF, const int* __restrict__ meta, int Mfixed)
{
  int tm = blockIdx.y, tn = blockIdx.x;
  int M = Mfixed ? Mfixed : meta[161];
  if (tm*128 >= M) return;
  const u16* Wp = W;
  if (PEREXP){
    int g = meta[192+tm]&7;
    Wp = W + (size_t)g*1048576;
  }
  __shared__ __align__(16) u16 As[128*64];
  __shared__ __align__(16) u16 Bs[128*64];
  int tid=threadIdx.x, lane=tid&63;
  int w=tid>>6, wr=w>>1, wc=w&1, lc=lane&15, lr=lane>>4;
  const f32x4 Z4 = {0.f,0.f,0.f,0.f};
  f32x4 acc[4][4];
  #pragma unroll
  for(int i=0;i<4;i++){
    #pragma unroll
    for(int j=0;j<4;j++) acc[i][j]=Z4;
  }
  size_t lanoff = (size_t)(tid>>3)*1024 + (tid&7)*8;
  const u16* Ab = A  + (size_t)tm*131072 + lanoff;
  const u16* Bb = Wp + (size_t)tn*131072 + lanoff;
  for (int kt=0; kt<16; ++kt){
    #pragma unroll
    for (int it=0; it<4; ++it){
      size_t go = (size_t)it*32768 + kt*64;
      int lo = it*2048 + tid*8;
      gl_lds(Ab + go, &As[lo]);
      gl_lds(Bb + go, &Bs[lo]);
    }
    __syncthreads();
    #pragma unroll
    for (int kk=0; kk<2; ++kk){
      bf16x8 a[4], b[4];
      #pragma unroll
      for (int mi=0;mi<4;mi++) a[mi] = *(const bf16x8*)&As[(wr*64+mi*16+lc)*64 + kk*32 + lr*8];
      #pragma unroll
      for (int ni=0;ni<4;ni++) b[ni] = *(const bf16x8*)&Bs[(wc*64+ni*16+lc)*64 + kk*32 + lr*8];
      #pragma unroll
      for (int mi=0;mi<4;mi++){
        #pragma unroll
        for (int ni=0;ni<4;ni++)
          acc[mi][ni] = MFMA16(a[mi], b[ni], acc[mi][ni]);
      }
    }
    __syncthreads();
  }
  int r0=lr*4;
  #pragma unroll
  for (int mi=0;mi<4;mi++){
    #pragma unroll
    for (int ni=0;ni<4;ni++){
      int col = tn*128 + wc*64 + ni*16 + lc;
      #pragma unroll
      for (int r=0;r<4;r++){
        int row = tm*128 + wr*64 + mi*16 + r0 + r;
        if (OUTF) outF[(size_t)row*1024 + col] = acc[mi][ni][r];
        else      outB[(size_t)row*1024 + col] = f2bf(acc[mi][ni][r]);
      }
    }
  }
}

// ---------- chunked causal linear attention, one block per (group, head) ----------
__global__ __launch_bounds__(256,1) void k_attn(const u16* __restrict__ qv, const u16* __restrict__ kv,
  const u16* __restrict__ vv, u16* __restrict__ o, const int* __restrict__ meta)
{
  int g = blockIdx.x>>3, h = blockIdx.x&7;
  int nch = meta[129+g];
  if (nch==0) return;
  int base = meta[96+g];
  __shared__ __align__(16) u16 Qs[64*136];
  __shared__ __align__(16) u16 Ks[64*136];
  __shared__ __align__(16) u16 KTs[128*72];
  __shared__ __align__(16) u16 VTs[128*72];
  __shared__ __align__(16) u16 Ts[128*136];   // T = S^T (e-major), bf16 copy of state
  __shared__ __align__(16) u16 Ps[64*72];
  int tid=threadIdx.x, w=tid>>6, lane=tid&63;
  int wr=w>>1, wc=w&1;
  int lr=lane>>4, lc=lane&15;
  {
    u32x4 z={0,0,0,0};
    for (int i=tid; i<128*136/8; i+=256) *(u32x4*)&Ts[i*8]=z;
  }
  const f32x4 Z4 = {0.f,0.f,0.f,0.f};
  f32x4 accT[4][4];
  #pragma unroll
  for (int i=0;i<4;i++){
    #pragma unroll
    for (int j=0;j<4;j++) accT[i][j]=Z4;
  }
  __syncthreads();
  const u16* qb = qv + (size_t)base*1024 + h*128;
  const u16* kb = kv + (size_t)base*1024 + h*128;
  const u16* vb = vv + (size_t)base*1024 + h*128;
  u16* ob = o + (size_t)base*1024 + h*128;

  for (int c=0; c<nch; ++c){
    // stage q,k row-major
    #pragma unroll
    for (int it=0; it<4; ++it){
      int id = tid + it*256;
      int row = id>>4, kc = id&15;
      *(u32x4*)&Qs[row*136 + kc*8] = *(const u32x4*)(qb + (size_t)(c*64+row)*1024 + kc*8);
      *(u32x4*)&Ks[row*136 + kc*8] = *(const u32x4*)(kb + (size_t)(c*64+row)*1024 + kc*8);
    }
    // transpose-stage k^T, v^T straight from global
    #pragma unroll
    for (int it=0; it<4; ++it){
      int id = tid + it*256;
      int j = id>>4, dg = id&15;
      u32x4 kx = *(const u32x4*)(kb + (size_t)(c*64+j)*1024 + dg*8);
      u32x4 vx = *(const u32x4*)(vb + (size_t)(c*64+j)*1024 + dg*8);
      #pragma unroll
      for (int t=0;t<4;t++){
        KTs[(dg*8+t*2  )*72 + j] = (u16)(kx[t]&0xffff);
        KTs[(dg*8+t*2+1)*72 + j] = (u16)(kx[t]>>16);
        VTs[(dg*8+t*2  )*72 + j] = (u16)(vx[t]&0xffff);
        VTs[(dg*8+t*2+1)*72 + j] = (u16)(vx[t]>>16);
      }
    }
    __syncthreads();
    // q fragments (shared between inter and P)
    bf16x8 qf[2][4];
    #pragma unroll
    for (int ti=0; ti<2; ++ti){
      #pragma unroll
      for (int ks=0; ks<4; ++ks)
        qf[ti][ks] = *(const bf16x8*)&Qs[(wr*32+ti*16+lc)*136 + ks*32 + lr*8];
    }
    f32x4 accO[2][4];
    #pragma unroll
    for (int i=0;i<2;i++){
      #pragma unroll
      for (int j=0;j<4;j++) accO[i][j]=Z4;
    }
    // inter = q . S  (S[d][e] = Ts[e][d]); uses OLD Ts
    #pragma unroll
    for (int ks=0; ks<4; ++ks){
      bf16x8 bt[4];
      #pragma unroll
      for (int te=0; te<4; ++te)
        bt[te] = *(const bf16x8*)&Ts[(wc*64+te*16+lc)*136 + ks*32 + lr*8];
      #pragma unroll
      for (int ti=0; ti<2; ++ti){
        #pragma unroll
        for (int te=0; te<4; ++te)
          accO[ti][te] = MFMA16(qf[ti][ks], bt[te], accO[ti][te]);
      }
    }
    // P = q . k^T (causal masked)
    f32x4 accP[2][2];
    #pragma unroll
    for (int i=0;i<2;i++){
      #pragma unroll
      for (int j=0;j<2;j++) accP[i][j]=Z4;
    }
    #pragma unroll
    for (int ks=0; ks<4; ++ks){
      bf16x8 bk[2];
      #pragma unroll
      for (int tj=0; tj<2; ++tj)
        bk[tj] = *(const bf16x8*)&Ks[(wc*32+tj*16+lc)*136 + ks*32 + lr*8];
      #pragma unroll
      for (int ti=0; ti<2; ++ti){
        #pragma unroll
        for (int tj=0; tj<2; ++tj)
          accP[ti][tj] = MFMA16(qf[ti][ks], bk[tj], accP[ti][tj]);
      }
    }
    #pragma unroll
    for (int ti=0; ti<2; ++ti){
      #pragma unroll
      for (int tj=0; tj<2; ++tj){
        #pragma unroll
        for (int r=0;r<4;r++){
          int i = wr*32+ti*16+lr*4+r;
          int j = wc*32+tj*16+lc;
          Ps[i*72 + j] = f2bf( (j<=i) ? accP[ti][tj][r] : 0.f );
        }
      }
    }
    __syncthreads();
    // intra = P . V   (B rows from VTs)
    #pragma unroll
    for (int ks=0; ks<2; ++ks){
      bf16x8 ap[2], bv[4];
      #pragma unroll
      for (int ti=0; ti<2; ++ti)
        ap[ti] = *(const bf16x8*)&Ps[(wr*32+ti*16+lc)*72 + ks*32 + lr*8];
      #pragma unroll
      for (int te=0; te<4; ++te)
        bv[te] = *(const bf16x8*)&VTs[(wc*64+te*16+lc)*72 + ks*32 + lr*8];
      #pragma unroll
      for (int ti=0; ti<2; ++ti){
        #pragma unroll
        for (int te=0; te<4; ++te)
          accO[ti][te] = MFMA16(ap[ti], bv[te], accO[ti][te]);
      }
    }
    // state: T[e][dk] += sum_j v[j][e] k[j][dk]
    #pragma unroll
    for (int ks=0; ks<2; ++ks){
      bf16x8 av[4], bk2[4];
      #pragma unroll
      for (int te=0; te<4; ++te)
        av[te] = *(const bf16x8*)&VTs[(wr*64+te*16+lc)*72 + ks*32 + lr*8];
      #pragma unroll
      for (int td=0; td<4; ++td)
        bk2[td] = *(const bf16x8*)&KTs[(wc*64+td*16+lc)*72 + ks*32 + lr*8];
      #pragma unroll
      for (int te=0; te<4; ++te){
        #pragma unroll
        for (int td=0; td<4; ++td)
          accT[te][td] = MFMA16(av[te], bk2[td], accT[te][td]);
      }
    }
    // write O chunk (bf16)
    #pragma unroll
    for (int ti=0; ti<2; ++ti){
      #pragma unroll
      for (int te=0; te<4; ++te){
        int ecol = wc*64+te*16+lc;
        #pragma unroll
        for (int r=0;r<4;r++){
          int i = wr*32+ti*16+lr*4+r;
          ob[(size_t)(c*64+i)*1024 + ecol] = f2bf(accO[ti][te][r]);
        }
      }
    }
    __syncthreads();   // all inter reads of Ts are done
    // refresh bf16 state copy from f32 accumulators
    #pragma unroll
    for (int te=0; te<4; ++te){
      #pragma unroll
      for (int td=0; td<4; ++td){
        int dk = wc*64+td*16+lc;
        #pragma unroll
        for (int r=0;r<4;r++){
          int erow = wr*64+te*16+lr*4+r;
          Ts[erow*136 + dk] = f2bf(accT[te][td][r]);
        }
      }
    }
    __syncthreads();
  }
}

// ---------- combine (rw-weighted sum) + per-head RMSNorm -> fin bf16 ----------
__global__ __launch_bounds__(256) void k_comb(const u16* __restrict__ o, const int* __restrict__ sel,
  const float* __restrict__ rw, const int* __restrict__ slot_of, const int* __restrict__ meta,
  const float* __restrict__ nw, u16* __restrict__ fin)
{
  int w=threadIdx.x>>6, lane=threadIdx.x&63;
  int tok = blockIdx.x*4 + w;           // b*2048+s
  int b = tok>>11;
  int sv = sel[tok];
  float acc[16];
  #pragma unroll
  for (int i=0;i<16;i++) acc[i]=0.f;
  #pragma unroll
  for (int kk=0; kk<2; ++kk){
    int e = kk ? ((sv>>8)&255) : (sv&255);
    int j = slot_of[tok*2 + kk];
    if (j < 0) continue;
    float wgt = rw[tok*2+kk];
    int row = meta[96 + b*8 + e] + j;
    const u16* orow = o + (size_t)row*1024 + lane*16;
    #pragma unroll
    for (int q=0;q<2;q++){
      u32x4 v = *(const u32x4*)(orow + q*8);
      #pragma unroll
      for (int t=0;t<4;t++){
        acc[q*8+t*2]   += wgt * bf2f((u16)(v[t]&0xffff));
        acc[q*8+t*2+1] += wgt * bf2f((u16)(v[t]>>16));
      }
    }
  }
  float ssq=0.f;
  #pragma unroll
  for (int i=0;i<16;i++) ssq += acc[i]*acc[i];
  ssq += __shfl_xor(ssq,1,64);
  ssq += __shfl_xor(ssq,2,64);
  ssq += __shfl_xor(ssq,4,64);           // head = 8 lanes (128 elems)
  float sc = rsqrtf(ssq*(1.f/128.f) + 1e-5f);
  int cbase = (lane&7)*16;
  u32x4 o0, o1;
  #pragma unroll
  for (int t=0;t<4;t++)
    o0[t] = pack2(acc[2*t]*sc*nw[cbase+2*t], acc[2*t+1]*sc*nw[cbase+2*t+1]);
  #pragma unroll
  for (int t=0;t<4;t++)
    o1[t] = pack2(acc[8+2*t]*sc*nw[cbase+8+2*t], acc[8+2*t+1]*sc*nw[cbase+8+2*t+1]);
  u16* fp = fin + (size_t)tok*1024 + lane*16;
  *(u32x4*)fp     = o0;
  *(u32x4*)(fp+8) = o1;
}

// ---------- host launcher ----------
extern "C" void kernel_launch(void* const* d_in, const int* in_sizes, int n_in,
                              void* d_out, int out_size, void* d_ws, size_t ws_size,
                              hipStream_t stream)
{
  (void)in_sizes; (void)n_in;
  const float* x     = (const float*)d_in[0];
  const float* gate  = (const float*)d_in[1];
  const float* q_w   = (const float*)d_in[2];
  const float* k_w   = (const float*)d_in[3];
  const float* v_w   = (const float*)d_in[4];
  const float* fmq1  = (const float*)d_in[5];
  const float* fmq2  = (const float*)d_in[6];
  const float* fmk1  = (const float*)d_in[7];
  const float* fmk2  = (const float*)d_in[8];
  const float* norm_w= (const float*)d_in[9];
  const float* o_w   = (const float*)d_in[10];
  float* out = (float*)d_out;

  uint8_t* ws = (uint8_t*)d_ws;
  size_t off = 0;
  auto alloc = [&](size_t bytes)->void*{ void* p = ws + off; off += (bytes + 255) & ~(size_t)255; return p; };
  int*   meta = (int*)alloc(4096);
  int*   sel  = (int*)alloc(8192*4);
  float* rwb  = (float*)alloc(8192*2*4);
  int*   slot = (int*)alloc(16384*4);
  int*   srcf = (int*)alloc((size_t)32*2048*4);
  u16* wA1 = (u16*)alloc((size_t)1048576*2);
  u16* wA2 = (u16*)alloc((size_t)1048576*2);
  u16* wB1 = (u16*)alloc((size_t)8388608*2);
  u16* wB2 = (u16*)alloc((size_t)8388608*2);
  u16* xg  = (u16*)alloc((size_t)RMAX*1024*2);
  u16* qh  = (u16*)alloc((size_t)RMAX*1024*2);
  u16* kh  = (u16*)alloc((size_t)RMAX*1024*2);
  u16* vv  = (u16*)alloc((size_t)RMAX*1024*2);
  if (off > ws_size){
    // sentinel: absmax ~3.4e38 signals "workspace too small"
    hipMemsetAsync(d_out, 0x7F, (size_t)out_size*4, stream);
    return;
  }
  u16* ob  = xg;    // reuse after GEMMs consumed xg
  u16* fin = qh;    // reuse after attn consumed qh
  u16* wOb = wA1;   // reuse after k_gemm2<0> consumed wA1
  u16* wVb = wB1;   // reuse after k_gemm2<1> consumed wB1

  k_route<<<2048,256,0,stream>>>(x, gate, sel, rwb);
  k_count<<<32,256,0,stream>>>(sel, slot, srcf, meta);
  k_bases<<<1,64,0,stream>>>(meta);
  k_gather<<<dim3(32,32),256,0,stream>>>(x, srcf, meta, xg);
  k_prep<<<dim3(8,144),256,0,stream>>>(q_w, k_w, fmq1, fmq2, fmk1, fmk2, wA1, wA2, wB1, wB2);
  k_gemm2<0><<<dim3(8,160),256,0,stream>>>(xg, wA1, wA2, qh, meta);
  k_cvt<<<256,256,0,stream>>>(o_w, wOb, 131072L);
  k_gemm2<1><<<dim3(8,160),256,0,stream>>>(xg, wB1, wB2, kh, meta);
  k_cvt<<<1024,256,0,stream>>>(v_w, wVb, 1048576L);
  k_gemmS<1,0><<<dim3(8,160),256,0,stream>>>(xg, wVb, vv, nullptr, meta, 0);
  k_attn<<<256,256,0,stream>>>(qh, kh, vv, ob, meta);
  k_comb<<<2048,256,0,stream>>>(ob, sel, rwb, slot, meta, norm_w, fin);
  k_gemmS<0,1><<<dim3(8,64),256,0,stream>>>(fin, wOb, nullptr, out, meta, 8192);
}

// Round 5
// 580.384 us; speedup vs baseline: 1.3912x; 1.1831x over previous
//
#include <hip/hip_runtime.h>
#include <stdint.h>

// ---------- types / helpers ----------
typedef unsigned short u16;
typedef unsigned int   u32;
typedef __attribute__((ext_vector_type(4))) float f32x4;
typedef __attribute__((ext_vector_type(4))) u32   u32x4;
typedef __attribute__((ext_vector_type(8))) __bf16 bf16x8;

#define MFMA16(a,b,c) __builtin_amdgcn_mfma_f32_16x16x32_bf16((a),(b),(c),0,0,0)

#define QSCALE 0.08838834764831845f   // 128^-0.5
#define RMAX   20480                  // sum roundup(min(n,2048),128) <= 16384+32*127

__device__ __forceinline__ float bf2f(u16 x){ u32 u=((u32)x)<<16; float f; __builtin_memcpy(&f,&u,4); return f; }
__device__ __forceinline__ u16 f2bf(float f){ u32 u; __builtin_memcpy(&u,&f,4); u = u + 0x7FFFu + ((u>>16)&1u); return (u16)(u>>16); }
__device__ __forceinline__ u32 pack2(float a, float b){ return (u32)f2bf(a) | ((u32)f2bf(b)<<16); }

// async global->LDS, 16B per lane
__device__ __forceinline__ void gl_lds(const u16* g, u16* l){
  __builtin_amdgcn_global_load_lds(
      (const __attribute__((address_space(1))) void*)g,
      (__attribute__((address_space(3))) void*)l, 16, 0, 0);
}

// meta layout (ints): [0,32) n  [32,64) nact  [64,96) npad  [96,129) base
// [129,161) nchunks  [161] R_total  [192,352) 128-tile -> group map

// ---------- f32 -> bf16 convert ----------
__global__ __launch_bounds__(256) void k_cvt(const float* __restrict__ s, u16* __restrict__ d, long n8){
  long idx = (long)blockIdx.x*256 + threadIdx.x;
  long stride = (long)gridDim.x*256;
  for (long i=idx; i<n8; i+=stride){
    const float* p = s + i*8;
    f32x4 a = *(const f32x4*)p;
    f32x4 b = *(const f32x4*)(p+4);
    u32x4 o;
    o[0]=pack2(a[0],a[1]); o[1]=pack2(a[2],a[3]); o[2]=pack2(b[0],b[1]); o[3]=pack2(b[2],b[3]);
    *(u32x4*)(d + i*8) = o;
  }
}

// ---------- combined weights via MFMA into CAT layout ----------
// cat layout: pair p (=head h): rows [p*256, p*256+128) = fm1-combined, rows [p*256+128, +256) = fm2-combined
__global__ __launch_bounds__(256) void k_prep(
  const float* __restrict__ q_w, const float* __restrict__ k_w,
  const float* __restrict__ fmq1, const float* __restrict__ fmq2,
  const float* __restrict__ fmk1, const float* __restrict__ fmk2,
  u16* __restrict__ wA, u16* __restrict__ wB)
{
  int gi = blockIdx.y;
  const float* fm; const float* ws; u16* wd;
  if (gi < 8)      { int h=gi;    fm=fmq1; ws=q_w + (size_t)h*131072; wd=wA + (size_t)h*262144; }
  else if (gi < 16){ int h=gi-8;  fm=fmq2; ws=q_w + (size_t)h*131072; wd=wA + (size_t)h*262144 + 131072; }
  else if (gi < 80){ int t=gi-16, e=t>>3, h=t&7; fm=fmk1; ws=k_w + (size_t)(e*8+h)*131072; wd=wB + (size_t)e*2097152 + (size_t)h*262144; }
  else             { int t=gi-80, e=t>>3, h=t&7; fm=fmk2; ws=k_w + (size_t)(e*8+h)*131072; wd=wB + (size_t)e*2097152 + (size_t)h*262144 + 131072; }
  int c0 = blockIdx.x*128;
  __shared__ __align__(16) u16 Af[128*136];
  __shared__ __align__(16) u16 Bf[128*136];
  int tid = threadIdx.x;
  for (int i=tid; i<4096; i+=256){
    int row = i>>5, col = (i&31)*4;
    f32x4 v = *(const f32x4*)&fm[row*128 + col];
    u16* dp = &Af[row*136 + col];
    *(u32*)dp     = pack2(v[0],v[1]);
    *(u32*)(dp+2) = pack2(v[2],v[3]);
  }
  for (int i=tid; i<4096; i+=256){
    int dd = i>>5, cq = (i&31)*4;
    f32x4 v = *(const f32x4*)&ws[(size_t)dd*1024 + c0 + cq];
    #pragma unroll
    for (int j=0;j<4;j++){
      int c = cq+j;
      Bf[c*136 + (dd ^ (((c>>2)&3)<<3))] = f2bf(v[j]);
    }
  }
  __syncthreads();
  int lane=tid&63, w=tid>>6, wr=w>>1, wc=w&1, lc=lane&15, lr=lane>>4;
  const f32x4 Z4 = {0.f,0.f,0.f,0.f};
  f32x4 acc[4][4];
  #pragma unroll
  for (int i=0;i<4;i++){
    #pragma unroll
    for (int j=0;j<4;j++) acc[i][j]=Z4;
  }
  #pragma unroll
  for (int kk=0; kk<4; ++kk){
    bf16x8 a[4], b[4];
    #pragma unroll
    for (int mi=0;mi<4;mi++)
      a[mi] = *(const bf16x8*)&Af[(wr*64+mi*16+lc)*136 + kk*32 + lr*8];
    #pragma unroll
    for (int ni=0;ni<4;ni++){
      int c = wc*64+ni*16+lc;
      b[ni] = *(const bf16x8*)&Bf[c*136 + ((kk*32 + lr*8) ^ (((c>>2)&3)<<3))];
    }
    #pragma unroll
    for (int mi=0;mi<4;mi++){
      #pragma unroll
      for (int ni=0;ni<4;ni++)
        acc[mi][ni] = MFMA16(a[mi], b[ni], acc[mi][ni]);
    }
  }
  int r0=lr*4;
  #pragma unroll
  for (int mi=0;mi<4;mi++){
    #pragma unroll
    for (int ni=0;ni<4;ni++){
      int col = c0 + wc*64 + ni*16 + lc;
      #pragma unroll
      for (int r=0;r<4;r++){
        int row = wr*64 + mi*16 + r0 + r;
        wd[(size_t)row*1024 + col] = f2bf(acc[mi][ni][r]);
      }
    }
  }
}

// ---------- routing ----------
__global__ __launch_bounds__(256) void k_route(const float* __restrict__ x, const float* __restrict__ gw,
  int* __restrict__ sel, float* __restrict__ rw)
{
  int w = threadIdx.x>>6, lane = threadIdx.x&63;
  int tok = blockIdx.x*4 + w;
  const float* xr = x + (size_t)tok*1024 + lane*16;
  f32x4 xv[4];
  #pragma unroll
  for (int q=0;q<4;q++) xv[q] = *(const f32x4*)(xr + q*4);
  float part[8];
  #pragma unroll
  for (int e=0;e<8;e++){
    const float* g = gw + e*1024 + lane*16;
    float s = 0.f;
    #pragma unroll
    for (int q=0;q<4;q++){
      f32x4 gv = *(const f32x4*)(g + q*4);
      s += xv[q][0]*gv[0] + xv[q][1]*gv[1] + xv[q][2]*gv[2] + xv[q][3]*gv[3];
    }
    part[e]=s;
  }
  #pragma unroll
  for (int e=0;e<8;e++){
    float v = part[e];
    #pragma unroll
    for (int off=32; off>0; off>>=1) v += __shfl_xor(v, off, 64);
    part[e]=v;
  }
  if (lane==0){
    int i0=0; float m0=part[0];
    #pragma unroll
    for (int e=1;e<8;e++) if (part[e]>m0){ m0=part[e]; i0=e; }
    int i1=0; float m1=-3.4e38f;
    #pragma unroll
    for (int e=0;e<8;e++) if (e!=i0 && part[e]>m1){ m1=part[e]; i1=e; }
    sel[tok] = i0 | (i1<<8);
    float e1 = expf(m1-m0);
    float inv = 1.f/(1.f+e1);
    rw[tok*2+0] = inv;
    rw[tok*2+1] = e1*inv;
  }
}

// ---------- per-(b,e) counting sort ----------
__global__ __launch_bounds__(256) void k_count(const int* __restrict__ sel,
  int* __restrict__ slot_of, int* __restrict__ src_of, int* __restrict__ meta)
{
  int g = blockIdx.x, b = g>>3, e = g&7;
  int tid = threadIdx.x;
  __shared__ int cn[256];
  unsigned char ex[16];
  int cnt=0;
  #pragma unroll
  for (int i=0;i<16;i++){
    int t = tid*16+i;
    int sv = sel[b*2048 + (t>>1)];
    int ee = (t&1) ? ((sv>>8)&255) : (sv&255);
    ex[i]=(unsigned char)ee;
    cnt += (ee==e);
  }
  cn[tid]=cnt;
  __syncthreads();
  for (int off=1; off<256; off<<=1){
    int v = (tid>=off) ? cn[tid-off] : 0;
    __syncthreads();
    cn[tid] += v;
    __syncthreads();
  }
  int total = cn[255];
  int run = cn[tid]-cnt;
  int shift = total>2048 ? total-2048 : 0;
  #pragma unroll
  for (int i=0;i<16;i++){
    int t = tid*16+i;
    if (ex[i]==e){
      int j = run - shift;
      run++;
      slot_of[b*4096 + t] = (j>=0)? j : -1;
      if (j>=0) src_of[g*2048 + j] = t;
    }
  }
  if (tid==0) meta[g]=total;
}

// ---------- group bases + tile->group map ----------
__global__ void k_bases(int* meta){
  if (threadIdx.x || blockIdx.x) return;
  int basev=0, t=0;
  meta[96]=0;
  for (int g=0; g<32; ++g){
    int n = meta[g];
    int nact = n<2048 ? n : 2048;
    int npad = (nact+127)&~127;
    meta[32+g]=nact;
    meta[64+g]=npad;
    meta[129+g]=(nact+63)>>6;
    for (int i=0;i<(npad>>7);++i) meta[192+t++]=g;
    basev += npad;
    meta[97+g]=basev;
  }
  meta[161]=basev;
}

// ---------- gather x rows -> compact bf16 ----------
__global__ __launch_bounds__(256) void k_gather(const float* __restrict__ x,
  const int* __restrict__ src_of, const int* __restrict__ meta, u16* __restrict__ xg)
{
  int g = blockIdx.y, jb = blockIdx.x;
  int npad = meta[64+g];
  if (jb*64 >= npad) return;
  int nact = meta[32+g], base = meta[96+g];
  int tid = threadIdx.x;
  int j = jb*64 + (tid>>2);
  int quart = tid&3;
  int src = (j<nact) ? src_of[g*2048+j] : -1;
  u16* orow = xg + ((size_t)(base+j))*1024 + quart*256;
  if (src>=0){
    const float* xr = x + ((size_t)((g>>3)*2048 + (src>>1)))*1024 + quart*256;
    for (int i=0;i<256;i+=8){
      f32x4 a  = *(const f32x4*)(xr+i);
      f32x4 bv = *(const f32x4*)(xr+i+4);
      u32x4 o;
      o[0]=pack2(a[0],a[1]); o[1]=pack2(a[2],a[3]); o[2]=pack2(bv[0],bv[1]); o[3]=pack2(bv[2],bv[3]);
      *(u32x4*)(orow+i)=o;
    }
  } else {
    u32x4 z = {0,0,0,0};
    for (int i=0;i<256;i+=8) *(u32x4*)(orow+i)=z;
  }
}

// ======== 128x256 8-wave prefetch-2ph GEMM over CAT weights, fused Hadamard product ========
// smem offsets (u16 units): A buffers at 0 / 8192 ; B buffers at 16384 / 32768
// C[r][tn*128+c] = (A.W1^T)[r][c] * (A.W2^T)[r][c] [*QSCALE if MODE==0]; MODE1: per-expert W
template<int MODE>
__global__ __launch_bounds__(512) void k_gemmP(const u16* __restrict__ A, const u16* __restrict__ W,
  u16* __restrict__ outB, const int* __restrict__ meta)
{
  int tnN = gridDim.x;
  int bid = blockIdx.y*tnN + blockIdx.x;
  int chunk = gridDim.y >> 3;
  int xcd = bid & 7, j = bid >> 3;
  int jd = j / tnN;
  int tm = xcd*chunk + jd;
  int tn = j - jd*tnN;
  if (tm*128 >= meta[161]) return;
  const u16* Wp = W;
  if (MODE==1) Wp = W + (size_t)(meta[192+tm]&7)*2097152;

  __shared__ __align__(16) u16 smem[49152];   // 96 KB

  int tid=threadIdx.x, lane=tid&63;
  int w=tid>>6, wr=w>>2, wc=w&3, lc=lane&15, lr=lane>>4;
  const f32x4 Z4 = {0.f,0.f,0.f,0.f};
  f32x4 acc[4][4];
  #pragma unroll
  for(int i=0;i<4;i++){
    #pragma unroll
    for(int j2=0;j2<4;j2++) acc[i][j2]=Z4;
  }
  const u16* Ag = A  + (size_t)tm*131072 + (size_t)(tid>>3)*1024 + (tid&7)*8;
  const u16* Bg = Wp + (size_t)tn*262144 + (size_t)(tid>>3)*1024 + (tid&7)*8;
  int lo = tid*8;

  #define STAGEP(ao, bo, kt) { \
    const u16* ga = Ag + (kt)*64; const u16* gb = Bg + (kt)*64; \
    gl_lds(ga,                 &smem[(ao) + lo]); \
    gl_lds(ga + (size_t)65536, &smem[(ao) + 4096 + lo]); \
    gl_lds(gb,                  &smem[(bo) + lo]); \
    gl_lds(gb + (size_t)65536,  &smem[(bo) + 4096 + lo]); \
    gl_lds(gb + (size_t)131072, &smem[(bo) + 8192 + lo]); \
    gl_lds(gb + (size_t)196608, &smem[(bo) + 12288 + lo]); }

  STAGEP(0, 16384, 0);
  __syncthreads();
  int cur = 0;
  for (int kt=0; kt<16; ++kt){
    if (kt<15) STAGEP((cur^1)*8192, 16384 + (cur^1)*16384, kt+1);
    int ao = cur*8192, bo = 16384 + cur*16384;
    #pragma unroll
    for (int kk=0; kk<2; ++kk){
      bf16x8 a[4], b[4];
      #pragma unroll
      for (int mi=0;mi<4;mi++) a[mi] = *(const bf16x8*)&smem[ao + (wr*64+mi*16+lc)*64 + kk*32 + lr*8];
      #pragma unroll
      for (int ni=0;ni<4;ni++) b[ni] = *(const bf16x8*)&smem[bo + (wc*64+ni*16+lc)*64 + kk*32 + lr*8];
      #pragma unroll
      for (int mi=0;mi<4;mi++){
        #pragma unroll
        for (int ni=0;ni<4;ni++)
          acc[mi][ni] = MFMA16(a[mi], b[ni], acc[mi][ni]);
      }
    }
    __syncthreads();     // drains prefetch (vmcnt0) + protects buffer reuse
    cur ^= 1;
  }
  // epilogue: waves wc>=2 hold factor-2 (cat rows 128..255); stash f32, multiply in wc<2
  if (wc >= 2){
    #pragma unroll
    for (int mi=0;mi<4;mi++){
      #pragma unroll
      for (int ni=0;ni<4;ni++){
        int col = (wc-2)*64 + ni*16 + lc;
        #pragma unroll
        for (int r=0;r<4;r++)
          ((float*)smem)[(wr*64+mi*16+lr*4+r)*129 + col] = acc[mi][ni][r];
      }
    }
  }
  __syncthreads();
  if (wc < 2){
    #pragma unroll
    for (int mi=0;mi<4;mi++){
      #pragma unroll
      for (int ni=0;ni<4;ni++){
        int col = wc*64 + ni*16 + lc;
        #pragma unroll
        for (int r=0;r<4;r++){
          int row = wr*64+mi*16+lr*4+r;
          float v = acc[mi][ni][r] * ((float*)smem)[row*129 + col];
          if (MODE==0) v *= QSCALE;
          outB[(size_t)(tm*128+row)*1024 + tn*128 + col] = f2bf(v);
        }
      }
    }
  }
  #undef STAGEP
}

// ======== 128x256 8-wave prefetch-2ph single GEMM (bf16 W) ========
// PEREXP: per-expert W ; OUTF: f32 out
template<int PEREXP, int OUTF>
__global__ __launch_bounds__(512) void k_gemmS(const u16* __restrict__ A, const u16* __restrict__ W,
  u16* __restrict__ outB, float* __restrict__ outF, const int* __restrict__ meta, int Mfixed)
{
  int tnN = gridDim.x;
  int bid = blockIdx.y*tnN + blockIdx.x;
  int chunk = gridDim.y >> 3;
  int xcd = bid & 7, j = bid >> 3;
  int jd = j / tnN;
  int tm = xcd*chunk + jd;
  int tn = j - jd*tnN;
  int M = Mfixed ? Mfixed : meta[161];
  if (tm*128 >= M) return;
  const u16* Wp = W;
  if (PEREXP) Wp = W + (size_t)(meta[192+tm]&7)*1048576;

  __shared__ __align__(16) u16 smem[49152];

  int tid=threadIdx.x, lane=tid&63;
  int w=tid>>6, wr=w>>2, wc=w&3, lc=lane&15, lr=lane>>4;
  const f32x4 Z4 = {0.f,0.f,0.f,0.f};
  f32x4 acc[4][4];
  #pragma unroll
  for(int i=0;i<4;i++){
    #pragma unroll
    for(int j2=0;j2<4;j2++) acc[i][j2]=Z4;
  }
  const u16* Ag = A  + (size_t)tm*131072 + (size_t)(tid>>3)*1024 + (tid&7)*8;
  const u16* Bg = Wp + (size_t)tn*262144 + (size_t)(tid>>3)*1024 + (tid&7)*8;
  int lo = tid*8;

  #define STAGES(ao, bo, kt) { \
    const u16* ga = Ag + (kt)*64; const u16* gb = Bg + (kt)*64; \
    gl_lds(ga,                 &smem[(ao) + lo]); \
    gl_lds(ga + (size_t)65536, &smem[(ao) + 4096 + lo]); \
    gl_lds(gb,                  &smem[(bo) + lo]); \
    gl_lds(gb + (size_t)65536,  &smem[(bo) + 4096 + lo]); \
    gl_lds(gb + (size_t)131072, &smem[(bo) + 8192 + lo]); \
    gl_lds(gb + (size_t)196608, &smem[(bo) + 12288 + lo]); }

  STAGES(0, 16384, 0);
  __syncthreads();
  int cur = 0;
  for (int kt=0; kt<16; ++kt){
    if (kt<15) STAGES((cur^1)*8192, 16384 + (cur^1)*16384, kt+1);
    int ao = cur*8192, bo = 16384 + cur*16384;
    #pragma unroll
    for (int kk=0; kk<2; ++kk){
      bf16x8 a[4], b[4];
      #pragma unroll
      for (int mi=0;mi<4;mi++) a[mi] = *(const bf16x8*)&smem[ao + (wr*64+mi*16+lc)*64 + kk*32 + lr*8];
      #pragma unroll
      for (int ni=0;ni<4;ni++) b[ni] = *(const bf16x8*)&smem[bo + (wc*64+ni*16+lc)*64 + kk*32 + lr*8];
      #pragma unroll
      for (int mi=0;mi<4;mi++){
        #pragma unroll
        for (int ni=0;ni<4;ni++)
          acc[mi][ni] = MFMA16(a[mi], b[ni], acc[mi][ni]);
      }
    }
    __syncthreads();
    cur ^= 1;
  }
  #pragma unroll
  for (int mi=0;mi<4;mi++){
    #pragma unroll
    for (int ni=0;ni<4;ni++){
      int col = tn*256 + wc*64 + ni*16 + lc;
      #pragma unroll
      for (int r=0;r<4;r++){
        int row = tm*128 + wr*64 + mi*16 + lr*4 + r;
        if (OUTF) outF[(size_t)row*1024 + col] = acc[mi][ni][r];
        else      outB[(size_t)row*1024 + col] = f2bf(acc[mi][ni][r]);
      }
    }
  }
  #undef STAGES
}

// ---------- chunked causal linear attention, one block per (group, head) ----------
__global__ __launch_bounds__(256,1) void k_attn(const u16* __restrict__ qv, const u16* __restrict__ kv,
  const u16* __restrict__ vv, u16* __restrict__ o, const int* __restrict__ meta)
{
  int g = blockIdx.x>>3, h = blockIdx.x&7;
  int nch = meta[129+g];
  if (nch==0) return;
  int base = meta[96+g];
  __shared__ __align__(16) u16 Qs[64*136];
  __shared__ __align__(16) u16 Ks[64*136];
  __shared__ __align__(16) u16 KTs[128*72];
  __shared__ __align__(16) u16 VTs[128*72];
  __shared__ __align__(16) u16 Ts[128*136];
  __shared__ __align__(16) u16 Ps[64*72];
  int tid=threadIdx.x, w=tid>>6, lane=tid&63;
  int wr=w>>1, wc=w&1;
  int lr=lane>>4, lc=lane&15;
  {
    u32x4 z={0,0,0,0};
    for (int i=tid; i<128*136/8; i+=256) *(u32x4*)&Ts[i*8]=z;
  }
  const f32x4 Z4 = {0.f,0.f,0.f,0.f};
  f32x4 accT[4][4];
  #pragma unroll
  for (int i=0;i<4;i++){
    #pragma unroll
    for (int j=0;j<4;j++) accT[i][j]=Z4;
  }
  __syncthreads();
  const u16* qb = qv + (size_t)base*1024 + h*128;
  const u16* kb = kv + (size_t)base*1024 + h*128;
  const u16* vb = vv + (size_t)base*1024 + h*128;
  u16* ob = o + (size_t)base*1024 + h*128;

  for (int c=0; c<nch; ++c){
    #pragma unroll
    for (int it=0; it<4; ++it){
      int id = tid + it*256;
      int row = id>>4, kc = id&15;
      *(u32x4*)&Qs[row*136 + kc*8] = *(const u32x4*)(qb + (size_t)(c*64+row)*1024 + kc*8);
      *(u32x4*)&Ks[row*136 + kc*8] = *(const u32x4*)(kb + (size_t)(c*64+row)*1024 + kc*8);
    }
    #pragma unroll
    for (int it=0; it<4; ++it){
      int id = tid + it*256;
      int j = id>>4, dg = id&15;
      u32x4 kx = *(const u32x4*)(kb + (size_t)(c*64+j)*1024 + dg*8);
      u32x4 vx = *(const u32x4*)(vb + (size_t)(c*64+j)*1024 + dg*8);
      #pragma unroll
      for (int t=0;t<4;t++){
        KTs[(dg*8+t*2  )*72 + j] = (u16)(kx[t]&0xffff);
        KTs[(dg*8+t*2+1)*72 + j] = (u16)(kx[t]>>16);
        VTs[(dg*8+t*2  )*72 + j] = (u16)(vx[t]&0xffff);
        VTs[(dg*8+t*2+1)*72 + j] = (u16)(vx[t]>>16);
      }
    }
    __syncthreads();
    bf16x8 qf[2][4];
    #pragma unroll
    for (int ti=0; ti<2; ++ti){
      #pragma unroll
      for (int ks=0; ks<4; ++ks)
        qf[ti][ks] = *(const bf16x8*)&Qs[(wr*32+ti*16+lc)*136 + ks*32 + lr*8];
    }
    f32x4 accO[2][4];
    #pragma unroll
    for (int i=0;i<2;i++){
      #pragma unroll
      for (int j=0;j<4;j++) accO[i][j]=Z4;
    }
    #pragma unroll
    for (int ks=0; ks<4; ++ks){
      bf16x8 bt[4];
      #pragma unroll
      for (int te=0; te<4; ++te)
        bt[te] = *(const bf16x8*)&Ts[(wc*64+te*16+lc)*136 + ks*32 + lr*8];
      #pragma unroll
      for (int ti=0; ti<2; ++ti){
        #pragma unroll
        for (int te=0; te<4; ++te)
          accO[ti][te] = MFMA16(qf[ti][ks], bt[te], accO[ti][te]);
      }
    }
    f32x4 accP[2][2];
    #pragma unroll
    for (int i=0;i<2;i++){
      #pragma unroll
      for (int j=0;j<2;j++) accP[i][j]=Z4;
    }
    #pragma unroll
    for (int ks=0; ks<4; ++ks){
      bf16x8 bk[2];
      #pragma unroll
      for (int tj=0; tj<2; ++tj)
        bk[tj] = *(const bf16x8*)&Ks[(wc*32+tj*16+lc)*136 + ks*32 + lr*8];
      #pragma unroll
      for (int ti=0; ti<2; ++ti){
        #pragma unroll
        for (int tj=0; tj<2; ++tj)
          accP[ti][tj] = MFMA16(qf[ti][ks], bk[tj], accP[ti][tj]);
      }
    }
    #pragma unroll
    for (int ti=0; ti<2; ++ti){
      #pragma unroll
      for (int tj=0; tj<2; ++tj){
        #pragma unroll
        for (int r=0;r<4;r++){
          int i = wr*32+ti*16+lr*4+r;
          int j = wc*32+tj*16+lc;
          Ps[i*72 + j] = f2bf( (j<=i) ? accP[ti][tj][r] : 0.f );
        }
      }
    }
    __syncthreads();
    #pragma unroll
    for (int ks=0; ks<2; ++ks){
      bf16x8 ap[2], bv[4];
      #pragma unroll
      for (int ti=0; ti<2; ++ti)
        ap[ti] = *(const bf16x8*)&Ps[(wr*32+ti*16+lc)*72 + ks*32 + lr*8];
      #pragma unroll
      for (int te=0; te<4; ++te)
        bv[te] = *(const bf16x8*)&VTs[(wc*64+te*16+lc)*72 + ks*32 + lr*8];
      #pragma unroll
      for (int ti=0; ti<2; ++ti){
        #pragma unroll
        for (int te=0; te<4; ++te)
          accO[ti][te] = MFMA16(ap[ti], bv[te], accO[ti][te]);
      }
    }
    #pragma unroll
    for (int ks=0; ks<2; ++ks){
      bf16x8 av[4], bk2[4];
      #pragma unroll
      for (int te=0; te<4; ++te)
        av[te] = *(const bf16x8*)&VTs[(wr*64+te*16+lc)*72 + ks*32 + lr*8];
      #pragma unroll
      for (int td=0; td<4; ++td)
        bk2[td] = *(const bf16x8*)&KTs[(wc*64+td*16+lc)*72 + ks*32 + lr*8];
      #pragma unroll
      for (int te=0; te<4; ++te){
        #pragma unroll
        for (int td=0; td<4; ++td)
          accT[te][td] = MFMA16(av[te], bk2[td], accT[te][td]);
      }
    }
    #pragma unroll
    for (int ti=0; ti<2; ++ti){
      #pragma unroll
      for (int te=0; te<4; ++te){
        int ecol = wc*64+te*16+lc;
        #pragma unroll
        for (int r=0;r<4;r++){
          int i = wr*32+ti*16+lr*4+r;
          ob[(size_t)(c*64+i)*1024 + ecol] = f2bf(accO[ti][te][r]);
        }
      }
    }
    __syncthreads();
    #pragma unroll
    for (int te=0; te<4; ++te){
      #pragma unroll
      for (int td=0; td<4; ++td){
        int dk = wc*64+td*16+lc;
        #pragma unroll
        for (int r=0;r<4;r++){
          int erow = wr*64+te*16+lr*4+r;
          Ts[erow*136 + dk] = f2bf(accT[te][td][r]);
        }
      }
    }
    __syncthreads();
  }
}

// ---------- combine + per-head RMSNorm ----------
__global__ __launch_bounds__(256) void k_comb(const u16* __restrict__ o, const int* __restrict__ sel,
  const float* __restrict__ rw, const int* __restrict__ slot_of, const int* __restrict__ meta,
  const float* __restrict__ nw, u16* __restrict__ fin)
{
  int w=threadIdx.x>>6, lane=threadIdx.x&63;
  int tok = blockIdx.x*4 + w;
  int b = tok>>11;
  int sv = sel[tok];
  float acc[16];
  #pragma unroll
  for (int i=0;i<16;i++) acc[i]=0.f;
  #pragma unroll
  for (int kk=0; kk<2; ++kk){
    int e = kk ? ((sv>>8)&255) : (sv&255);
    int j = slot_of[tok*2 + kk];
    if (j < 0) continue;
    float wgt = rw[tok*2+kk];
    int row = meta[96 + b*8 + e] + j;
    const u16* orow = o + (size_t)row*1024 + lane*16;
    #pragma unroll
    for (int q=0;q<2;q++){
      u32x4 v = *(const u32x4*)(orow + q*8);
      #pragma unroll
      for (int t=0;t<4;t++){
        acc[q*8+t*2]   += wgt * bf2f((u16)(v[t]&0xffff));
        acc[q*8+t*2+1] += wgt * bf2f((u16)(v[t]>>16));
      }
    }
  }
  float ssq=0.f;
  #pragma unroll
  for (int i=0;i<16;i++) ssq += acc[i]*acc[i];
  ssq += __shfl_xor(ssq,1,64);
  ssq += __shfl_xor(ssq,2,64);
  ssq += __shfl_xor(ssq,4,64);
  float sc = rsqrtf(ssq*(1.f/128.f) + 1e-5f);
  int cbase = (lane&7)*16;
  u32x4 o0, o1;
  #pragma unroll
  for (int t=0;t<4;t++)
    o0[t] = pack2(acc[2*t]*sc*nw[cbase+2*t], acc[2*t+1]*sc*nw[cbase+2*t+1]);
  #pragma unroll
  for (int t=0;t<4;t++)
    o1[t] = pack2(acc[8+2*t]*sc*nw[cbase+8+2*t], acc[8+2*t+1]*sc*nw[cbase+8+2*t+1]);
  u16* fp = fin + (size_t)tok*1024 + lane*16;
  *(u32x4*)fp     = o0;
  *(u32x4*)(fp+8) = o1;
}

// ---------- host launcher ----------
extern "C" void kernel_launch(void* const* d_in, const int* in_sizes, int n_in,
                              void* d_out, int out_size, void* d_ws, size_t ws_size,
                              hipStream_t stream)
{
  (void)in_sizes; (void)n_in;
  const float* x     = (const float*)d_in[0];
  const float* gate  = (const float*)d_in[1];
  const float* q_w   = (const float*)d_in[2];
  const float* k_w   = (const float*)d_in[3];
  const float* v_w   = (const float*)d_in[4];
  const float* fmq1  = (const float*)d_in[5];
  const float* fmq2  = (const float*)d_in[6];
  const float* fmk1  = (const float*)d_in[7];
  const float* fmk2  = (const float*)d_in[8];
  const float* norm_w= (const float*)d_in[9];
  const float* o_w   = (const float*)d_in[10];
  float* out = (float*)d_out;

  uint8_t* ws = (uint8_t*)d_ws;
  size_t off = 0;
  auto alloc = [&](size_t bytes)->void*{ void* p = ws + off; off += (bytes + 255) & ~(size_t)255; return p; };
  int*   meta = (int*)alloc(4096);
  int*   sel  = (int*)alloc(8192*4);
  float* rwb  = (float*)alloc(8192*2*4);
  int*   slot = (int*)alloc(16384*4);
  int*   srcf = (int*)alloc((size_t)32*2048*4);
  u16* wA = (u16*)alloc((size_t)2097152*2);            // q cat weights (2048x1024)
  u16* wB = (u16*)alloc((size_t)8*2097152*2);          // k cat weights per expert
  u16* xg  = (u16*)alloc((size_t)RMAX*1024*2);
  u16* qh  = (u16*)alloc((size_t)RMAX*1024*2);
  u16* kh  = (u16*)alloc((size_t)RMAX*1024*2);
  u16* vv  = (u16*)alloc((size_t)RMAX*1024*2);
  if (off > ws_size){
    hipMemsetAsync(d_out, 0x7F, (size_t)out_size*4, stream);
    return;
  }
  u16* ob  = xg;    // reuse after GEMMs consumed xg
  u16* fin = qh;    // reuse after attn consumed qh
  u16* wOb = wA;    // reuse after q-GEMM consumed wA
  u16* wVb = wB;    // reuse after k-GEMM consumed wB

  k_route<<<2048,256,0,stream>>>(x, gate, sel, rwb);
  k_count<<<32,256,0,stream>>>(sel, slot, srcf, meta);
  k_bases<<<1,64,0,stream>>>(meta);
  k_gather<<<dim3(32,32),256,0,stream>>>(x, srcf, meta, xg);
  k_prep<<<dim3(8,144),256,0,stream>>>(q_w, k_w, fmq1, fmq2, fmk1, fmk2, wA, wB);
  k_gemmP<0><<<dim3(8,160),512,0,stream>>>(xg, wA, qh, meta);
  k_cvt<<<256,256,0,stream>>>(o_w, wOb, 131072L);
  k_gemmP<1><<<dim3(8,160),512,0,stream>>>(xg, wB, kh, meta);
  k_cvt<<<1024,256,0,stream>>>(v_w, wVb, 1048576L);
  k_gemmS<1,0><<<dim3(4,160),512,0,stream>>>(xg, wVb, vv, nullptr, meta, 0);
  k_attn<<<256,256,0,stream>>>(qh, kh, vv, ob, meta);
  k_comb<<<2048,256,0,stream>>>(ob, sel, rwb, slot, meta, norm_w, fin);
  k_gemmS<0,1><<<dim3(4,64),512,0,stream>>>(fin, wOb, nullptr, out, meta, 8192);
}

// Round 6
// 502.712 us; speedup vs baseline: 1.6062x; 1.1545x over previous
//
#include <hip/hip_runtime.h>
#include <stdint.h>

// ---------- types / helpers ----------
typedef unsigned short u16;
typedef unsigned int   u32;
typedef __attribute__((ext_vector_type(4))) float f32x4;
typedef __attribute__((ext_vector_type(4))) u32   u32x4;
typedef __attribute__((ext_vector_type(8))) __bf16 bf16x8;

#define MFMA16(a,b,c) __builtin_amdgcn_mfma_f32_16x16x32_bf16((a),(b),(c),0,0,0)

#define QSCALE 0.08838834764831845f   // 128^-0.5
#define RMAX   20480                  // sum roundup(min(n,2048),128) <= 16384+32*127

__device__ __forceinline__ float bf2f(u16 x){ u32 u=((u32)x)<<16; float f; __builtin_memcpy(&f,&u,4); return f; }
__device__ __forceinline__ u16 f2bf(float f){ u32 u; __builtin_memcpy(&u,&f,4); u = u + 0x7FFFu + ((u>>16)&1u); return (u16)(u>>16); }
__device__ __forceinline__ u32 pack2(float a, float b){ return (u32)f2bf(a) | ((u32)f2bf(b)<<16); }

// async global->LDS, 16B per lane
__device__ __forceinline__ void gl_lds(const u16* g, u16* l){
  __builtin_amdgcn_global_load_lds(
      (const __attribute__((address_space(1))) void*)g,
      (__attribute__((address_space(3))) void*)l, 16, 0, 0);
}

// meta layout (ints): [0,32) n  [32,64) nact  [64,96) npad  [96,129) base
// [129,161) nchunks  [161] R_total  [192,352) 128-tile -> group map

// ---------- f32 -> bf16 convert ----------
__global__ __launch_bounds__(256) void k_cvt(const float* __restrict__ s, u16* __restrict__ d, long n8){
  long idx = (long)blockIdx.x*256 + threadIdx.x;
  long stride = (long)gridDim.x*256;
  for (long i=idx; i<n8; i+=stride){
    const float* p = s + i*8;
    f32x4 a = *(const f32x4*)p;
    f32x4 b = *(const f32x4*)(p+4);
    u32x4 o;
    o[0]=pack2(a[0],a[1]); o[1]=pack2(a[2],a[3]); o[2]=pack2(b[0],b[1]); o[3]=pack2(b[2],b[3]);
    *(u32x4*)(d + i*8) = o;
  }
}

// ---------- combined weights via MFMA into CAT layout ----------
__global__ __launch_bounds__(256) void k_prep(
  const float* __restrict__ q_w, const float* __restrict__ k_w,
  const float* __restrict__ fmq1, const float* __restrict__ fmq2,
  const float* __restrict__ fmk1, const float* __restrict__ fmk2,
  u16* __restrict__ wA, u16* __restrict__ wB)
{
  int gi = blockIdx.y;
  const float* fm; const float* ws; u16* wd;
  if (gi < 8)      { int h=gi;    fm=fmq1; ws=q_w + (size_t)h*131072; wd=wA + (size_t)h*262144; }
  else if (gi < 16){ int h=gi-8;  fm=fmq2; ws=q_w + (size_t)h*131072; wd=wA + (size_t)h*262144 + 131072; }
  else if (gi < 80){ int t=gi-16, e=t>>3, h=t&7; fm=fmk1; ws=k_w + (size_t)(e*8+h)*131072; wd=wB + (size_t)e*2097152 + (size_t)h*262144; }
  else             { int t=gi-80, e=t>>3, h=t&7; fm=fmk2; ws=k_w + (size_t)(e*8+h)*131072; wd=wB + (size_t)e*2097152 + (size_t)h*262144 + 131072; }
  int c0 = blockIdx.x*128;
  __shared__ __align__(16) u16 Af[128*136];
  __shared__ __align__(16) u16 Bf[128*136];
  int tid = threadIdx.x;
  for (int i=tid; i<4096; i+=256){
    int row = i>>5, col = (i&31)*4;
    f32x4 v = *(const f32x4*)&fm[row*128 + col];
    u16* dp = &Af[row*136 + col];
    *(u32*)dp     = pack2(v[0],v[1]);
    *(u32*)(dp+2) = pack2(v[2],v[3]);
  }
  for (int i=tid; i<4096; i+=256){
    int dd = i>>5, cq = (i&31)*4;
    f32x4 v = *(const f32x4*)&ws[(size_t)dd*1024 + c0 + cq];
    #pragma unroll
    for (int j=0;j<4;j++){
      int c = cq+j;
      Bf[c*136 + (dd ^ (((c>>2)&3)<<3))] = f2bf(v[j]);
    }
  }
  __syncthreads();
  int lane=tid&63, w=tid>>6, wr=w>>1, wc=w&1, lc=lane&15, lr=lane>>4;
  const f32x4 Z4 = {0.f,0.f,0.f,0.f};
  f32x4 acc[4][4];
  #pragma unroll
  for (int i=0;i<4;i++){
    #pragma unroll
    for (int j=0;j<4;j++) acc[i][j]=Z4;
  }
  #pragma unroll
  for (int kk=0; kk<4; ++kk){
    bf16x8 a[4], b[4];
    #pragma unroll
    for (int mi=0;mi<4;mi++)
      a[mi] = *(const bf16x8*)&Af[(wr*64+mi*16+lc)*136 + kk*32 + lr*8];
    #pragma unroll
    for (int ni=0;ni<4;ni++){
      int c = wc*64+ni*16+lc;
      b[ni] = *(const bf16x8*)&Bf[c*136 + ((kk*32 + lr*8) ^ (((c>>2)&3)<<3))];
    }
    #pragma unroll
    for (int mi=0;mi<4;mi++){
      #pragma unroll
      for (int ni=0;ni<4;ni++)
        acc[mi][ni] = MFMA16(a[mi], b[ni], acc[mi][ni]);
    }
  }
  int r0=lr*4;
  #pragma unroll
  for (int mi=0;mi<4;mi++){
    #pragma unroll
    for (int ni=0;ni<4;ni++){
      int col = c0 + wc*64 + ni*16 + lc;
      #pragma unroll
      for (int r=0;r<4;r++){
        int row = wr*64 + mi*16 + r0 + r;
        wd[(size_t)row*1024 + col] = f2bf(acc[mi][ni][r]);
      }
    }
  }
}

// ---------- routing ----------
__global__ __launch_bounds__(256) void k_route(const float* __restrict__ x, const float* __restrict__ gw,
  int* __restrict__ sel, float* __restrict__ rw)
{
  int w = threadIdx.x>>6, lane = threadIdx.x&63;
  int tok = blockIdx.x*4 + w;
  const float* xr = x + (size_t)tok*1024 + lane*16;
  f32x4 xv[4];
  #pragma unroll
  for (int q=0;q<4;q++) xv[q] = *(const f32x4*)(xr + q*4);
  float part[8];
  #pragma unroll
  for (int e=0;e<8;e++){
    const float* g = gw + e*1024 + lane*16;
    float s = 0.f;
    #pragma unroll
    for (int q=0;q<4;q++){
      f32x4 gv = *(const f32x4*)(g + q*4);
      s += xv[q][0]*gv[0] + xv[q][1]*gv[1] + xv[q][2]*gv[2] + xv[q][3]*gv[3];
    }
    part[e]=s;
  }
  #pragma unroll
  for (int e=0;e<8;e++){
    float v = part[e];
    #pragma unroll
    for (int off=32; off>0; off>>=1) v += __shfl_xor(v, off, 64);
    part[e]=v;
  }
  if (lane==0){
    int i0=0; float m0=part[0];
    #pragma unroll
    for (int e=1;e<8;e++) if (part[e]>m0){ m0=part[e]; i0=e; }
    int i1=0; float m1=-3.4e38f;
    #pragma unroll
    for (int e=0;e<8;e++) if (e!=i0 && part[e]>m1){ m1=part[e]; i1=e; }
    sel[tok] = i0 | (i1<<8);
    float e1 = expf(m1-m0);
    float inv = 1.f/(1.f+e1);
    rw[tok*2+0] = inv;
    rw[tok*2+1] = e1*inv;
  }
}

// ---------- per-(b,e) counting sort ----------
__global__ __launch_bounds__(256) void k_count(const int* __restrict__ sel,
  int* __restrict__ slot_of, int* __restrict__ src_of, int* __restrict__ meta)
{
  int g = blockIdx.x, b = g>>3, e = g&7;
  int tid = threadIdx.x;
  __shared__ int cn[256];
  unsigned char ex[16];
  int cnt=0;
  #pragma unroll
  for (int i=0;i<16;i++){
    int t = tid*16+i;
    int sv = sel[b*2048 + (t>>1)];
    int ee = (t&1) ? ((sv>>8)&255) : (sv&255);
    ex[i]=(unsigned char)ee;
    cnt += (ee==e);
  }
  cn[tid]=cnt;
  __syncthreads();
  for (int off=1; off<256; off<<=1){
    int v = (tid>=off) ? cn[tid-off] : 0;
    __syncthreads();
    cn[tid] += v;
    __syncthreads();
  }
  int total = cn[255];
  int run = cn[tid]-cnt;
  int shift = total>2048 ? total-2048 : 0;
  #pragma unroll
  for (int i=0;i<16;i++){
    int t = tid*16+i;
    if (ex[i]==e){
      int j = run - shift;
      run++;
      slot_of[b*4096 + t] = (j>=0)? j : -1;
      if (j>=0) src_of[g*2048 + j] = t;
    }
  }
  if (tid==0) meta[g]=total;
}

// ---------- group bases + tile->group map ----------
__global__ void k_bases(int* meta){
  if (threadIdx.x || blockIdx.x) return;
  int basev=0, t=0;
  meta[96]=0;
  for (int g=0; g<32; ++g){
    int n = meta[g];
    int nact = n<2048 ? n : 2048;
    int npad = (nact+127)&~127;
    meta[32+g]=nact;
    meta[64+g]=npad;
    meta[129+g]=(nact+63)>>6;
    for (int i=0;i<(npad>>7);++i) meta[192+t++]=g;
    basev += npad;
    meta[97+g]=basev;
  }
  meta[161]=basev;
}

// ---------- gather x rows -> compact bf16 ----------
__global__ __launch_bounds__(256) void k_gather(const float* __restrict__ x,
  const int* __restrict__ src_of, const int* __restrict__ meta, u16* __restrict__ xg)
{
  int g = blockIdx.y, jb = blockIdx.x;
  int npad = meta[64+g];
  if (jb*64 >= npad) return;
  int nact = meta[32+g], base = meta[96+g];
  int tid = threadIdx.x;
  int j = jb*64 + (tid>>2);
  int quart = tid&3;
  int src = (j<nact) ? src_of[g*2048+j] : -1;
  u16* orow = xg + ((size_t)(base+j))*1024 + quart*256;
  if (src>=0){
    const float* xr = x + ((size_t)((g>>3)*2048 + (src>>1)))*1024 + quart*256;
    for (int i=0;i<256;i+=8){
      f32x4 a  = *(const f32x4*)(xr+i);
      f32x4 bv = *(const f32x4*)(xr+i+4);
      u32x4 o;
      o[0]=pack2(a[0],a[1]); o[1]=pack2(a[2],a[3]); o[2]=pack2(bv[0],bv[1]); o[3]=pack2(bv[2],bv[3]);
      *(u32x4*)(orow+i)=o;
    }
  } else {
    u32x4 z = {0,0,0,0};
    for (int i=0;i<256;i+=8) *(u32x4*)(orow+i)=z;
  }
}

// ======== 128x256 8-wave GEMM, depth-2 counted-vmcnt pipeline (T4) + LDS swizzle (T2) ========
// 3 buffers: A at {0,8192,16384}, B at 24576+{0,16384,32768}  (144 KB total)
// LDS slot (row, cc) holds global chunk cc^(row&7); read chunk (kk*4+lr)^(lc&7).
// k_gemmP: C[r][tn*128+c] = (A.W1^T)*(A.W2^T) [*QSCALE if MODE==0]; MODE1: per-expert W
template<int MODE>
__global__ __launch_bounds__(512) void k_gemmP(const u16* __restrict__ A, const u16* __restrict__ W,
  u16* __restrict__ outB, const int* __restrict__ meta)
{
  int tnN = gridDim.x;
  int bid = blockIdx.y*tnN + blockIdx.x;
  int chunk = gridDim.y >> 3;
  int xcd = bid & 7, j = bid >> 3;
  int jd = j / tnN;
  int tm = xcd*chunk + jd;
  int tn = j - jd*tnN;
  if (tm*128 >= meta[161]) return;
  const u16* Wp = W;
  if (MODE==1) Wp = W + (size_t)(meta[192+tm]&7)*2097152;

  __shared__ __align__(16) u16 smem[73728];   // 144 KB

  int tid=threadIdx.x, lane=tid&63;
  int w=tid>>6, wr=w>>2, wc=w&3, lc=lane&15, lr=lane>>4;
  int swz = lc&7;
  const f32x4 Z4 = {0.f,0.f,0.f,0.f};
  f32x4 acc[4][4];
  #pragma unroll
  for(int i=0;i<4;i++){
    #pragma unroll
    for(int j2=0;j2<4;j2++) acc[i][j2]=Z4;
  }
  // pre-swizzled global source: LDS linear dest + inverse-swizzled source chunk
  size_t lanoff = (size_t)(tid>>3)*1024 + (size_t)(((tid&7)^((tid>>3)&7))*8);
  const u16* Ag = A  + (size_t)tm*131072 + lanoff;
  const u16* Bg = Wp + (size_t)tn*262144 + lanoff;
  int lo = tid*8;

  #define STAGEP(ao, bo, kt) { \
    const u16* ga = Ag + (kt)*64; const u16* gb = Bg + (kt)*64; \
    gl_lds(ga,                 &smem[(ao) + lo]); \
    gl_lds(ga + (size_t)65536, &smem[(ao) + 4096 + lo]); \
    gl_lds(gb,                  &smem[(bo) + lo]); \
    gl_lds(gb + (size_t)65536,  &smem[(bo) + 4096 + lo]); \
    gl_lds(gb + (size_t)131072, &smem[(bo) + 8192 + lo]); \
    gl_lds(gb + (size_t)196608, &smem[(bo) + 12288 + lo]); }

  STAGEP(0, 24576, 0);
  STAGEP(8192, 40960, 1);
  int cur = 0;
  for (int kt=0; kt<16; ++kt){
    if (kt<15) asm volatile("s_waitcnt vmcnt(6)" ::: "memory");
    else       asm volatile("s_waitcnt vmcnt(0)" ::: "memory");
    __builtin_amdgcn_s_barrier();
    if (kt<14){
      int nid = kt+2; nid -= (nid/3)*3;
      STAGEP(nid*8192, 24576+nid*16384, kt+2);
    }
    int ao = cur*8192, bo = 24576 + cur*16384;
    __builtin_amdgcn_s_setprio(1);
    #pragma unroll
    for (int kk=0; kk<2; ++kk){
      bf16x8 a[4], b[4];
      #pragma unroll
      for (int mi=0;mi<4;mi++){
        int row = wr*64+mi*16+lc;
        a[mi] = *(const bf16x8*)&smem[ao + row*64 + (((kk*4+lr)^swz)<<3)];
      }
      #pragma unroll
      for (int ni=0;ni<4;ni++){
        int row = wc*64+ni*16+lc;
        b[ni] = *(const bf16x8*)&smem[bo + row*64 + (((kk*4+lr)^swz)<<3)];
      }
      #pragma unroll
      for (int mi=0;mi<4;mi++){
        #pragma unroll
        for (int ni=0;ni<4;ni++)
          acc[mi][ni] = MFMA16(a[mi], b[ni], acc[mi][ni]);
      }
    }
    __builtin_amdgcn_s_setprio(0);
    cur = (cur==2)?0:cur+1;
  }
  __syncthreads();
  // epilogue: waves wc>=2 hold factor-2 (cat rows 128..255); stash f32, multiply in wc<2
  if (wc >= 2){
    #pragma unroll
    for (int mi=0;mi<4;mi++){
      #pragma unroll
      for (int ni=0;ni<4;ni++){
        int col = (wc-2)*64 + ni*16 + lc;
        #pragma unroll
        for (int r=0;r<4;r++)
          ((float*)smem)[(wr*64+mi*16+lr*4+r)*129 + col] = acc[mi][ni][r];
      }
    }
  }
  __syncthreads();
  if (wc < 2){
    #pragma unroll
    for (int mi=0;mi<4;mi++){
      #pragma unroll
      for (int ni=0;ni<4;ni++){
        int col = wc*64 + ni*16 + lc;
        #pragma unroll
        for (int r=0;r<4;r++){
          int row = wr*64+mi*16+lr*4+r;
          float v = acc[mi][ni][r] * ((float*)smem)[row*129 + col];
          if (MODE==0) v *= QSCALE;
          outB[(size_t)(tm*128+row)*1024 + tn*128 + col] = f2bf(v);
        }
      }
    }
  }
  #undef STAGEP
}

// ======== 128x256 8-wave single GEMM, same T4+T2 pipeline (bf16 W) ========
template<int PEREXP, int OUTF>
__global__ __launch_bounds__(512) void k_gemmS(const u16* __restrict__ A, const u16* __restrict__ W,
  u16* __restrict__ outB, float* __restrict__ outF, const int* __restrict__ meta, int Mfixed)
{
  int tnN = gridDim.x;
  int bid = blockIdx.y*tnN + blockIdx.x;
  int chunk = gridDim.y >> 3;
  int xcd = bid & 7, j = bid >> 3;
  int jd = j / tnN;
  int tm = xcd*chunk + jd;
  int tn = j - jd*tnN;
  int M = Mfixed ? Mfixed : meta[161];
  if (tm*128 >= M) return;
  const u16* Wp = W;
  if (PEREXP) Wp = W + (size_t)(meta[192+tm]&7)*1048576;

  __shared__ __align__(16) u16 smem[73728];

  int tid=threadIdx.x, lane=tid&63;
  int w=tid>>6, wr=w>>2, wc=w&3, lc=lane&15, lr=lane>>4;
  int swz = lc&7;
  const f32x4 Z4 = {0.f,0.f,0.f,0.f};
  f32x4 acc[4][4];
  #pragma unroll
  for(int i=0;i<4;i++){
    #pragma unroll
    for(int j2=0;j2<4;j2++) acc[i][j2]=Z4;
  }
  size_t lanoff = (size_t)(tid>>3)*1024 + (size_t)(((tid&7)^((tid>>3)&7))*8);
  const u16* Ag = A  + (size_t)tm*131072 + lanoff;
  const u16* Bg = Wp + (size_t)tn*262144 + lanoff;
  int lo = tid*8;

  #define STAGES(ao, bo, kt) { \
    const u16* ga = Ag + (kt)*64; const u16* gb = Bg + (kt)*64; \
    gl_lds(ga,                 &smem[(ao) + lo]); \
    gl_lds(ga + (size_t)65536, &smem[(ao) + 4096 + lo]); \
    gl_lds(gb,                  &smem[(bo) + lo]); \
    gl_lds(gb + (size_t)65536,  &smem[(bo) + 4096 + lo]); \
    gl_lds(gb + (size_t)131072, &smem[(bo) + 8192 + lo]); \
    gl_lds(gb + (size_t)196608, &smem[(bo) + 12288 + lo]); }

  STAGES(0, 24576, 0);
  STAGES(8192, 40960, 1);
  int cur = 0;
  for (int kt=0; kt<16; ++kt){
    if (kt<15) asm volatile("s_waitcnt vmcnt(6)" ::: "memory");
    else       asm volatile("s_waitcnt vmcnt(0)" ::: "memory");
    __builtin_amdgcn_s_barrier();
    if (kt<14){
      int nid = kt+2; nid -= (nid/3)*3;
      STAGES(nid*8192, 24576+nid*16384, kt+2);
    }
    int ao = cur*8192, bo = 24576 + cur*16384;
    __builtin_amdgcn_s_setprio(1);
    #pragma unroll
    for (int kk=0; kk<2; ++kk){
      bf16x8 a[4], b[4];
      #pragma unroll
      for (int mi=0;mi<4;mi++){
        int row = wr*64+mi*16+lc;
        a[mi] = *(const bf16x8*)&smem[ao + row*64 + (((kk*4+lr)^swz)<<3)];
      }
      #pragma unroll
      for (int ni=0;ni<4;ni++){
        int row = wc*64+ni*16+lc;
        b[ni] = *(const bf16x8*)&smem[bo + row*64 + (((kk*4+lr)^swz)<<3)];
      }
      #pragma unroll
      for (int mi=0;mi<4;mi++){
        #pragma unroll
        for (int ni=0;ni<4;ni++)
          acc[mi][ni] = MFMA16(a[mi], b[ni], acc[mi][ni]);
      }
    }
    __builtin_amdgcn_s_setprio(0);
    cur = (cur==2)?0:cur+1;
  }
  #pragma unroll
  for (int mi=0;mi<4;mi++){
    #pragma unroll
    for (int ni=0;ni<4;ni++){
      int col = tn*256 + wc*64 + ni*16 + lc;
      #pragma unroll
      for (int r=0;r<4;r++){
        int row = tm*128 + wr*64 + mi*16 + lr*4 + r;
        if (OUTF) outF[(size_t)row*1024 + col] = acc[mi][ni][r];
        else      outB[(size_t)row*1024 + col] = f2bf(acc[mi][ni][r]);
      }
    }
  }
  #undef STAGES
}

// ---------- chunked causal linear attention, one block per (group, head) ----------
__global__ __launch_bounds__(256,1) void k_attn(const u16* __restrict__ qv, const u16* __restrict__ kv,
  const u16* __restrict__ vv, u16* __restrict__ o, const int* __restrict__ meta)
{
  int g = blockIdx.x>>3, h = blockIdx.x&7;
  int nch = meta[129+g];
  if (nch==0) return;
  int base = meta[96+g];
  __shared__ __align__(16) u16 Qs[64*136];
  __shared__ __align__(16) u16 Ks[64*136];
  __shared__ __align__(16) u16 KTs[128*72];
  __shared__ __align__(16) u16 VTs[128*72];
  __shared__ __align__(16) u16 Ts[128*136];
  __shared__ __align__(16) u16 Ps[64*72];
  int tid=threadIdx.x, w=tid>>6, lane=tid&63;
  int wr=w>>1, wc=w&1;
  int lr=lane>>4, lc=lane&15;
  {
    u32x4 z={0,0,0,0};
    for (int i=tid; i<128*136/8; i+=256) *(u32x4*)&Ts[i*8]=z;
  }
  const f32x4 Z4 = {0.f,0.f,0.f,0.f};
  f32x4 accT[4][4];
  #pragma unroll
  for (int i=0;i<4;i++){
    #pragma unroll
    for (int j=0;j<4;j++) accT[i][j]=Z4;
  }
  __syncthreads();
  const u16* qb = qv + (size_t)base*1024 + h*128;
  const u16* kb = kv + (size_t)base*1024 + h*128;
  const u16* vb = vv + (size_t)base*1024 + h*128;
  u16* ob = o + (size_t)base*1024 + h*128;

  for (int c=0; c<nch; ++c){
    #pragma unroll
    for (int it=0; it<4; ++it){
      int id = tid + it*256;
      int row = id>>4, kc = id&15;
      *(u32x4*)&Qs[row*136 + kc*8] = *(const u32x4*)(qb + (size_t)(c*64+row)*1024 + kc*8);
      *(u32x4*)&Ks[row*136 + kc*8] = *(const u32x4*)(kb + (size_t)(c*64+row)*1024 + kc*8);
    }
    #pragma unroll
    for (int it=0; it<4; ++it){
      int id = tid + it*256;
      int j = id>>4, dg = id&15;
      u32x4 kx = *(const u32x4*)(kb + (size_t)(c*64+j)*1024 + dg*8);
      u32x4 vx = *(const u32x4*)(vb + (size_t)(c*64+j)*1024 + dg*8);
      #pragma unroll
      for (int t=0;t<4;t++){
        KTs[(dg*8+t*2  )*72 + j] = (u16)(kx[t]&0xffff);
        KTs[(dg*8+t*2+1)*72 + j] = (u16)(kx[t]>>16);
        VTs[(dg*8+t*2  )*72 + j] = (u16)(vx[t]&0xffff);
        VTs[(dg*8+t*2+1)*72 + j] = (u16)(vx[t]>>16);
      }
    }
    __syncthreads();
    bf16x8 qf[2][4];
    #pragma unroll
    for (int ti=0; ti<2; ++ti){
      #pragma unroll
      for (int ks=0; ks<4; ++ks)
        qf[ti][ks] = *(const bf16x8*)&Qs[(wr*32+ti*16+lc)*136 + ks*32 + lr*8];
    }
    f32x4 accO[2][4];
    #pragma unroll
    for (int i=0;i<2;i++){
      #pragma unroll
      for (int j=0;j<4;j++) accO[i][j]=Z4;
    }
    #pragma unroll
    for (int ks=0; ks<4; ++ks){
      bf16x8 bt[4];
      #pragma unroll
      for (int te=0; te<4; ++te)
        bt[te] = *(const bf16x8*)&Ts[(wc*64+te*16+lc)*136 + ks*32 + lr*8];
      #pragma unroll
      for (int ti=0; ti<2; ++ti){
        #pragma unroll
        for (int te=0; te<4; ++te)
          accO[ti][te] = MFMA16(qf[ti][ks], bt[te], accO[ti][te]);
      }
    }
    f32x4 accP[2][2];
    #pragma unroll
    for (int i=0;i<2;i++){
      #pragma unroll
      for (int j=0;j<2;j++) accP[i][j]=Z4;
    }
    #pragma unroll
    for (int ks=0; ks<4; ++ks){
      bf16x8 bk[2];
      #pragma unroll
      for (int tj=0; tj<2; ++tj)
        bk[tj] = *(const bf16x8*)&Ks[(wc*32+tj*16+lc)*136 + ks*32 + lr*8];
      #pragma unroll
      for (int ti=0; ti<2; ++ti){
        #pragma unroll
        for (int tj=0; tj<2; ++tj)
          accP[ti][tj] = MFMA16(qf[ti][ks], bk[tj], accP[ti][tj]);
      }
    }
    #pragma unroll
    for (int ti=0; ti<2; ++ti){
      #pragma unroll
      for (int tj=0; tj<2; ++tj){
        #pragma unroll
        for (int r=0;r<4;r++){
          int i = wr*32+ti*16+lr*4+r;
          int j = wc*32+tj*16+lc;
          Ps[i*72 + j] = f2bf( (j<=i) ? accP[ti][tj][r] : 0.f );
        }
      }
    }
    __syncthreads();
    #pragma unroll
    for (int ks=0; ks<2; ++ks){
      bf16x8 ap[2], bv[4];
      #pragma unroll
      for (int ti=0; ti<2; ++ti)
        ap[ti] = *(const bf16x8*)&Ps[(wr*32+ti*16+lc)*72 + ks*32 + lr*8];
      #pragma unroll
      for (int te=0; te<4; ++te)
        bv[te] = *(const bf16x8*)&VTs[(wc*64+te*16+lc)*72 + ks*32 + lr*8];
      #pragma unroll
      for (int ti=0; ti<2; ++ti){
        #pragma unroll
        for (int te=0; te<4; ++te)
          accO[ti][te] = MFMA16(ap[ti], bv[te], accO[ti][te]);
      }
    }
    #pragma unroll
    for (int ks=0; ks<2; ++ks){
      bf16x8 av[4], bk2[4];
      #pragma unroll
      for (int te=0; te<4; ++te)
        av[te] = *(const bf16x8*)&VTs[(wr*64+te*16+lc)*72 + ks*32 + lr*8];
      #pragma unroll
      for (int td=0; td<4; ++td)
        bk2[td] = *(const bf16x8*)&KTs[(wc*64+td*16+lc)*72 + ks*32 + lr*8];
      #pragma unroll
      for (int te=0; te<4; ++te){
        #pragma unroll
        for (int td=0; td<4; ++td)
          accT[te][td] = MFMA16(av[te], bk2[td], accT[te][td]);
      }
    }
    #pragma unroll
    for (int ti=0; ti<2; ++ti){
      #pragma unroll
      for (int te=0; te<4; ++te){
        int ecol = wc*64+te*16+lc;
        #pragma unroll
        for (int r=0;r<4;r++){
          int i = wr*32+ti*16+lr*4+r;
          ob[(size_t)(c*64+i)*1024 + ecol] = f2bf(accO[ti][te][r]);
        }
      }
    }
    __syncthreads();
    #pragma unroll
    for (int te=0; te<4; ++te){
      #pragma unroll
      for (int td=0; td<4; ++td){
        int dk = wc*64+td*16+lc;
        #pragma unroll
        for (int r=0;r<4;r++){
          int erow = wr*64+te*16+lr*4+r;
          Ts[erow*136 + dk] = f2bf(accT[te][td][r]);
        }
      }
    }
    __syncthreads();
  }
}

// ---------- combine + per-head RMSNorm ----------
__global__ __launch_bounds__(256) void k_comb(const u16* __restrict__ o, const int* __restrict__ sel,
  const float* __restrict__ rw, const int* __restrict__ slot_of, const int* __restrict__ meta,
  const float* __restrict__ nw, u16* __restrict__ fin)
{
  int w=threadIdx.x>>6, lane=threadIdx.x&63;
  int tok = blockIdx.x*4 + w;
  int b = tok>>11;
  int sv = sel[tok];
  float acc[16];
  #pragma unroll
  for (int i=0;i<16;i++) acc[i]=0.f;
  #pragma unroll
  for (int kk=0; kk<2; ++kk){
    int e = kk ? ((sv>>8)&255) : (sv&255);
    int j = slot_of[tok*2 + kk];
    if (j < 0) continue;
    float wgt = rw[tok*2+kk];
    int row = meta[96 + b*8 + e] + j;
    const u16* orow = o + (size_t)row*1024 + lane*16;
    #pragma unroll
    for (int q=0;q<2;q++){
      u32x4 v = *(const u32x4*)(orow + q*8);
      #pragma unroll
      for (int t=0;t<4;t++){
        acc[q*8+t*2]   += wgt * bf2f((u16)(v[t]&0xffff));
        acc[q*8+t*2+1] += wgt * bf2f((u16)(v[t]>>16));
      }
    }
  }
  float ssq=0.f;
  #pragma unroll
  for (int i=0;i<16;i++) ssq += acc[i]*acc[i];
  ssq += __shfl_xor(ssq,1,64);
  ssq += __shfl_xor(ssq,2,64);
  ssq += __shfl_xor(ssq,4,64);
  float sc = rsqrtf(ssq*(1.f/128.f) + 1e-5f);
  int cbase = (lane&7)*16;
  u32x4 o0, o1;
  #pragma unroll
  for (int t=0;t<4;t++)
    o0[t] = pack2(acc[2*t]*sc*nw[cbase+2*t], acc[2*t+1]*sc*nw[cbase+2*t+1]);
  #pragma unroll
  for (int t=0;t<4;t++)
    o1[t] = pack2(acc[8+2*t]*sc*nw[cbase+8+2*t], acc[8+2*t+1]*sc*nw[cbase+8+2*t+1]);
  u16* fp = fin + (size_t)tok*1024 + lane*16;
  *(u32x4*)fp     = o0;
  *(u32x4*)(fp+8) = o1;
}

// ---------- host launcher ----------
extern "C" void kernel_launch(void* const* d_in, const int* in_sizes, int n_in,
                              void* d_out, int out_size, void* d_ws, size_t ws_size,
                              hipStream_t stream)
{
  (void)in_sizes; (void)n_in;
  const float* x     = (const float*)d_in[0];
  const float* gate  = (const float*)d_in[1];
  const float* q_w   = (const float*)d_in[2];
  const float* k_w   = (const float*)d_in[3];
  const float* v_w   = (const float*)d_in[4];
  const float* fmq1  = (const float*)d_in[5];
  const float* fmq2  = (const float*)d_in[6];
  const float* fmk1  = (const float*)d_in[7];
  const float* fmk2  = (const float*)d_in[8];
  const float* norm_w= (const float*)d_in[9];
  const float* o_w   = (const float*)d_in[10];
  float* out = (float*)d_out;

  uint8_t* ws = (uint8_t*)d_ws;
  size_t off = 0;
  auto alloc = [&](size_t bytes)->void*{ void* p = ws + off; off += (bytes + 255) & ~(size_t)255; return p; };
  int*   meta = (int*)alloc(4096);
  int*   sel  = (int*)alloc(8192*4);
  float* rwb  = (float*)alloc(8192*2*4);
  int*   slot = (int*)alloc(16384*4);
  int*   srcf = (int*)alloc((size_t)32*2048*4);
  u16* wA = (u16*)alloc((size_t)2097152*2);            // q cat weights (2048x1024)
  u16* wB = (u16*)alloc((size_t)8*2097152*2);          // k cat weights per expert
  u16* xg  = (u16*)alloc((size_t)RMAX*1024*2);
  u16* qh  = (u16*)alloc((size_t)RMAX*1024*2);
  u16* kh  = (u16*)alloc((size_t)RMAX*1024*2);
  u16* vv  = (u16*)alloc((size_t)RMAX*1024*2);
  if (off > ws_size){
    hipMemsetAsync(d_out, 0x7F, (size_t)out_size*4, stream);
    return;
  }
  u16* ob  = xg;    // reuse after GEMMs consumed xg
  u16* fin = qh;    // reuse after attn consumed qh
  u16* wOb = wA;    // reuse after q-GEMM consumed wA
  u16* wVb = wB;    // reuse after k-GEMM consumed wB

  k_route<<<2048,256,0,stream>>>(x, gate, sel, rwb);
  k_count<<<32,256,0,stream>>>(sel, slot, srcf, meta);
  k_bases<<<1,64,0,stream>>>(meta);
  k_gather<<<dim3(32,32),256,0,stream>>>(x, srcf, meta, xg);
  k_prep<<<dim3(8,144),256,0,stream>>>(q_w, k_w, fmq1, fmq2, fmk1, fmk2, wA, wB);
  k_gemmP<0><<<dim3(8,160),512,0,stream>>>(xg, wA, qh, meta);
  k_cvt<<<256,256,0,stream>>>(o_w, wOb, 131072L);
  k_gemmP<1><<<dim3(8,160),512,0,stream>>>(xg, wB, kh, meta);
  k_cvt<<<1024,256,0,stream>>>(v_w, wVb, 1048576L);
  k_gemmS<1,0><<<dim3(4,160),512,0,stream>>>(xg, wVb, vv, nullptr, meta, 0);
  k_attn<<<256,256,0,stream>>>(qh, kh, vv, ob, meta);
  k_comb<<<2048,256,0,stream>>>(ob, sel, rwb, slot, meta, norm_w, fin);
  k_gemmS<0,1><<<dim3(4,64),512,0,stream>>>(fin, wOb, nullptr, out, meta, 8192);
}

// Round 7
// 462.717 us; speedup vs baseline: 1.7450x; 1.0864x over previous
//
#include <hip/hip_runtime.h>
#include <stdint.h>

// ---------- types / helpers ----------
typedef unsigned short u16;
typedef unsigned int   u32;
typedef __attribute__((ext_vector_type(4))) float f32x4;
typedef __attribute__((ext_vector_type(4))) u32   u32x4;
typedef __attribute__((ext_vector_type(8))) __bf16 bf16x8;

#define MFMA16(a,b,c) __builtin_amdgcn_mfma_f32_16x16x32_bf16((a),(b),(c),0,0,0)

#define QSCALE 0.08838834764831845f   // 128^-0.5
#define RMAX   20480                  // sum roundup(min(n,2048),128) <= 16384+32*127

__device__ __forceinline__ float bf2f(u16 x){ u32 u=((u32)x)<<16; float f; __builtin_memcpy(&f,&u,4); return f; }
__device__ __forceinline__ u16 f2bf(float f){ u32 u; __builtin_memcpy(&u,&f,4); u = u + 0x7FFFu + ((u>>16)&1u); return (u16)(u>>16); }
__device__ __forceinline__ u32 pack2(float a, float b){ return (u32)f2bf(a) | ((u32)f2bf(b)<<16); }

// async global->LDS, 16B per lane
__device__ __forceinline__ void gl_lds(const u16* g, u16* l){
  __builtin_amdgcn_global_load_lds(
      (const __attribute__((address_space(1))) void*)g,
      (__attribute__((address_space(3))) void*)l, 16, 0, 0);
}

// meta layout (ints): [0,32) n  [32,64) nact  [64,96) npad  [96,129) base
// [129,161) nchunks  [161] R_total  [192,352) 128-tile -> group map

// ---------- f32 -> bf16 convert ----------
__global__ __launch_bounds__(256) void k_cvt(const float* __restrict__ s, u16* __restrict__ d, long n8){
  long idx = (long)blockIdx.x*256 + threadIdx.x;
  long stride = (long)gridDim.x*256;
  for (long i=idx; i<n8; i+=stride){
    const float* p = s + i*8;
    f32x4 a = *(const f32x4*)p;
    f32x4 b = *(const f32x4*)(p+4);
    u32x4 o;
    o[0]=pack2(a[0],a[1]); o[1]=pack2(a[2],a[3]); o[2]=pack2(b[0],b[1]); o[3]=pack2(b[2],b[3]);
    *(u32x4*)(d + i*8) = o;
  }
}

// ---------- combined weights via MFMA into CAT layout ----------
__global__ __launch_bounds__(256) void k_prep(
  const float* __restrict__ q_w, const float* __restrict__ k_w,
  const float* __restrict__ fmq1, const float* __restrict__ fmq2,
  const float* __restrict__ fmk1, const float* __restrict__ fmk2,
  u16* __restrict__ wA, u16* __restrict__ wB)
{
  int gi = blockIdx.y;
  const float* fm; const float* ws; u16* wd;
  if (gi < 8)      { int h=gi;    fm=fmq1; ws=q_w + (size_t)h*131072; wd=wA + (size_t)h*262144; }
  else if (gi < 16){ int h=gi-8;  fm=fmq2; ws=q_w + (size_t)h*131072; wd=wA + (size_t)h*262144 + 131072; }
  else if (gi < 80){ int t=gi-16, e=t>>3, h=t&7; fm=fmk1; ws=k_w + (size_t)(e*8+h)*131072; wd=wB + (size_t)e*2097152 + (size_t)h*262144; }
  else             { int t=gi-80, e=t>>3, h=t&7; fm=fmk2; ws=k_w + (size_t)(e*8+h)*131072; wd=wB + (size_t)e*2097152 + (size_t)h*262144 + 131072; }
  int c0 = blockIdx.x*128;
  __shared__ __align__(16) u16 Af[128*136];
  __shared__ __align__(16) u16 Bf[128*136];
  int tid = threadIdx.x;
  for (int i=tid; i<4096; i+=256){
    int row = i>>5, col = (i&31)*4;
    f32x4 v = *(const f32x4*)&fm[row*128 + col];
    u16* dp = &Af[row*136 + col];
    *(u32*)dp     = pack2(v[0],v[1]);
    *(u32*)(dp+2) = pack2(v[2],v[3]);
  }
  for (int i=tid; i<4096; i+=256){
    int dd = i>>5, cq = (i&31)*4;
    f32x4 v = *(const f32x4*)&ws[(size_t)dd*1024 + c0 + cq];
    #pragma unroll
    for (int j=0;j<4;j++){
      int c = cq+j;
      Bf[c*136 + (dd ^ (((c>>2)&3)<<3))] = f2bf(v[j]);
    }
  }
  __syncthreads();
  int lane=tid&63, w=tid>>6, wr=w>>1, wc=w&1, lc=lane&15, lr=lane>>4;
  const f32x4 Z4 = {0.f,0.f,0.f,0.f};
  f32x4 acc[4][4];
  #pragma unroll
  for (int i=0;i<4;i++){
    #pragma unroll
    for (int j=0;j<4;j++) acc[i][j]=Z4;
  }
  #pragma unroll
  for (int kk=0; kk<4; ++kk){
    bf16x8 a[4], b[4];
    #pragma unroll
    for (int mi=0;mi<4;mi++)
      a[mi] = *(const bf16x8*)&Af[(wr*64+mi*16+lc)*136 + kk*32 + lr*8];
    #pragma unroll
    for (int ni=0;ni<4;ni++){
      int c = wc*64+ni*16+lc;
      b[ni] = *(const bf16x8*)&Bf[c*136 + ((kk*32 + lr*8) ^ (((c>>2)&3)<<3))];
    }
    #pragma unroll
    for (int mi=0;mi<4;mi++){
      #pragma unroll
      for (int ni=0;ni<4;ni++)
        acc[mi][ni] = MFMA16(a[mi], b[ni], acc[mi][ni]);
    }
  }
  int r0=lr*4;
  #pragma unroll
  for (int mi=0;mi<4;mi++){
    #pragma unroll
    for (int ni=0;ni<4;ni++){
      int col = c0 + wc*64 + ni*16 + lc;
      #pragma unroll
      for (int r=0;r<4;r++){
        int row = wr*64 + mi*16 + r0 + r;
        wd[(size_t)row*1024 + col] = f2bf(acc[mi][ni][r]);
      }
    }
  }
}

// ---------- routing ----------
__global__ __launch_bounds__(256) void k_route(const float* __restrict__ x, const float* __restrict__ gw,
  int* __restrict__ sel, float* __restrict__ rw)
{
  int w = threadIdx.x>>6, lane = threadIdx.x&63;
  int tok = blockIdx.x*4 + w;
  const float* xr = x + (size_t)tok*1024 + lane*16;
  f32x4 xv[4];
  #pragma unroll
  for (int q=0;q<4;q++) xv[q] = *(const f32x4*)(xr + q*4);
  float part[8];
  #pragma unroll
  for (int e=0;e<8;e++){
    const float* g = gw + e*1024 + lane*16;
    float s = 0.f;
    #pragma unroll
    for (int q=0;q<4;q++){
      f32x4 gv = *(const f32x4*)(g + q*4);
      s += xv[q][0]*gv[0] + xv[q][1]*gv[1] + xv[q][2]*gv[2] + xv[q][3]*gv[3];
    }
    part[e]=s;
  }
  #pragma unroll
  for (int e=0;e<8;e++){
    float v = part[e];
    #pragma unroll
    for (int off=32; off>0; off>>=1) v += __shfl_xor(v, off, 64);
    part[e]=v;
  }
  if (lane==0){
    int i0=0; float m0=part[0];
    #pragma unroll
    for (int e=1;e<8;e++) if (part[e]>m0){ m0=part[e]; i0=e; }
    int i1=0; float m1=-3.4e38f;
    #pragma unroll
    for (int e=0;e<8;e++) if (e!=i0 && part[e]>m1){ m1=part[e]; i1=e; }
    sel[tok] = i0 | (i1<<8);
    float e1 = expf(m1-m0);
    float inv = 1.f/(1.f+e1);
    rw[tok*2+0] = inv;
    rw[tok*2+1] = e1*inv;
  }
}

// ---------- per-(b,e) counting sort ----------
__global__ __launch_bounds__(256) void k_count(const int* __restrict__ sel,
  int* __restrict__ slot_of, int* __restrict__ src_of, int* __restrict__ meta)
{
  int g = blockIdx.x, b = g>>3, e = g&7;
  int tid = threadIdx.x;
  __shared__ int cn[256];
  unsigned char ex[16];
  int cnt=0;
  #pragma unroll
  for (int i=0;i<16;i++){
    int t = tid*16+i;
    int sv = sel[b*2048 + (t>>1)];
    int ee = (t&1) ? ((sv>>8)&255) : (sv&255);
    ex[i]=(unsigned char)ee;
    cnt += (ee==e);
  }
  cn[tid]=cnt;
  __syncthreads();
  for (int off=1; off<256; off<<=1){
    int v = (tid>=off) ? cn[tid-off] : 0;
    __syncthreads();
    cn[tid] += v;
    __syncthreads();
  }
  int total = cn[255];
  int run = cn[tid]-cnt;
  int shift = total>2048 ? total-2048 : 0;
  #pragma unroll
  for (int i=0;i<16;i++){
    int t = tid*16+i;
    if (ex[i]==e){
      int j = run - shift;
      run++;
      slot_of[b*4096 + t] = (j>=0)? j : -1;
      if (j>=0) src_of[g*2048 + j] = t;
    }
  }
  if (tid==0) meta[g]=total;
}

// ---------- group bases + tile->group map ----------
__global__ void k_bases(int* meta){
  if (threadIdx.x || blockIdx.x) return;
  int basev=0, t=0;
  meta[96]=0;
  for (int g=0; g<32; ++g){
    int n = meta[g];
    int nact = n<2048 ? n : 2048;
    int npad = (nact+127)&~127;
    meta[32+g]=nact;
    meta[64+g]=npad;
    meta[129+g]=(nact+63)>>6;
    for (int i=0;i<(npad>>7);++i) meta[192+t++]=g;
    basev += npad;
    meta[97+g]=basev;
  }
  meta[161]=basev;
}

// ---------- gather x rows -> compact bf16 + row->token map ----------
__global__ __launch_bounds__(256) void k_gather(const float* __restrict__ x,
  const int* __restrict__ src_of, const int* __restrict__ meta, u16* __restrict__ xg,
  int* __restrict__ tokmap)
{
  int g = blockIdx.y, jb = blockIdx.x;
  int npad = meta[64+g];
  if (jb*64 >= npad) return;
  int nact = meta[32+g], base = meta[96+g];
  int tid = threadIdx.x;
  int j = jb*64 + (tid>>2);
  int quart = tid&3;
  int src = (j<nact) ? src_of[g*2048+j] : -1;
  int token = (src>=0) ? ((g>>3)*2048 + (src>>1)) : 0;
  if (quart==0) tokmap[base+j] = token;
  u16* orow = xg + ((size_t)(base+j))*1024 + quart*256;
  if (src>=0){
    const float* xr = x + ((size_t)token)*1024 + quart*256;
    for (int i=0;i<256;i+=8){
      f32x4 a  = *(const f32x4*)(xr+i);
      f32x4 bv = *(const f32x4*)(xr+i+4);
      u32x4 o;
      o[0]=pack2(a[0],a[1]); o[1]=pack2(a[2],a[3]); o[2]=pack2(bv[0],bv[1]); o[3]=pack2(bv[2],bv[3]);
      *(u32x4*)(orow+i)=o;
    }
  } else {
    u32x4 z = {0,0,0,0};
    for (int i=0;i<256;i+=8) *(u32x4*)(orow+i)=z;
  }
}

// ======== 128x256 8-wave GEMM, depth-2 counted-vmcnt pipeline (T4) + LDS swizzle (T2) ========
// 3 buffers: A at {0,8192,16384}, B at 24576+{0,16384,32768}  (144 KB total)
// MODE 0: q path — shared W, M=8192 token space, *QSCALE. MODE 1: k path — per-expert W, M=meta[161].
template<int MODE>
__global__ __launch_bounds__(512) void k_gemmP(const u16* __restrict__ A, const u16* __restrict__ W,
  u16* __restrict__ outB, const int* __restrict__ meta)
{
  int tnN = gridDim.x;
  int bid = blockIdx.y*tnN + blockIdx.x;
  int chunk = gridDim.y >> 3;
  int xcd = bid & 7, j = bid >> 3;
  int jd = j / tnN;
  int tm = xcd*chunk + jd;
  int tn = j - jd*tnN;
  int M = (MODE==0) ? 8192 : meta[161];
  if (tm*128 >= M) return;
  const u16* Wp = W;
  if (MODE==1) Wp = W + (size_t)(meta[192+tm]&7)*2097152;

  __shared__ __align__(16) u16 smem[73728];   // 144 KB

  int tid=threadIdx.x, lane=tid&63;
  int w=tid>>6, wr=w>>2, wc=w&3, lc=lane&15, lr=lane>>4;
  int swz = lc&7;
  const f32x4 Z4 = {0.f,0.f,0.f,0.f};
  f32x4 acc[4][4];
  #pragma unroll
  for(int i=0;i<4;i++){
    #pragma unroll
    for(int j2=0;j2<4;j2++) acc[i][j2]=Z4;
  }
  // pre-swizzled global source: LDS linear dest + inverse-swizzled source chunk
  size_t lanoff = (size_t)(tid>>3)*1024 + (size_t)(((tid&7)^((tid>>3)&7))*8);
  const u16* Ag = A  + (size_t)tm*131072 + lanoff;
  const u16* Bg = Wp + (size_t)tn*262144 + lanoff;
  int lo = tid*8;

  #define STAGEP(ao, bo, kt) { \
    const u16* ga = Ag + (kt)*64; const u16* gb = Bg + (kt)*64; \
    gl_lds(ga,                 &smem[(ao) + lo]); \
    gl_lds(ga + (size_t)65536, &smem[(ao) + 4096 + lo]); \
    gl_lds(gb,                  &smem[(bo) + lo]); \
    gl_lds(gb + (size_t)65536,  &smem[(bo) + 4096 + lo]); \
    gl_lds(gb + (size_t)131072, &smem[(bo) + 8192 + lo]); \
    gl_lds(gb + (size_t)196608, &smem[(bo) + 12288 + lo]); }

  STAGEP(0, 24576, 0);
  STAGEP(8192, 40960, 1);
  int cur = 0;
  for (int kt=0; kt<16; ++kt){
    if (kt<15) asm volatile("s_waitcnt vmcnt(6)" ::: "memory");
    else       asm volatile("s_waitcnt vmcnt(0)" ::: "memory");
    __builtin_amdgcn_s_barrier();
    if (kt<14){
      int nid = kt+2; nid -= (nid/3)*3;
      STAGEP(nid*8192, 24576+nid*16384, kt+2);
    }
    int ao = cur*8192, bo = 24576 + cur*16384;
    __builtin_amdgcn_s_setprio(1);
    #pragma unroll
    for (int kk=0; kk<2; ++kk){
      bf16x8 a[4], b[4];
      #pragma unroll
      for (int mi=0;mi<4;mi++){
        int row = wr*64+mi*16+lc;
        a[mi] = *(const bf16x8*)&smem[ao + row*64 + (((kk*4+lr)^swz)<<3)];
      }
      #pragma unroll
      for (int ni=0;ni<4;ni++){
        int row = wc*64+ni*16+lc;
        b[ni] = *(const bf16x8*)&smem[bo + row*64 + (((kk*4+lr)^swz)<<3)];
      }
      #pragma unroll
      for (int mi=0;mi<4;mi++){
        #pragma unroll
        for (int ni=0;ni<4;ni++)
          acc[mi][ni] = MFMA16(a[mi], b[ni], acc[mi][ni]);
      }
    }
    __builtin_amdgcn_s_setprio(0);
    cur = (cur==2)?0:cur+1;
  }
  __syncthreads();
  // epilogue: waves wc>=2 hold factor-2 (cat rows 128..255); stash f32, multiply in wc<2
  if (wc >= 2){
    #pragma unroll
    for (int mi=0;mi<4;mi++){
      #pragma unroll
      for (int ni=0;ni<4;ni++){
        int col = (wc-2)*64 + ni*16 + lc;
        #pragma unroll
        for (int r=0;r<4;r++)
          ((float*)smem)[(wr*64+mi*16+lr*4+r)*129 + col] = acc[mi][ni][r];
      }
    }
  }
  __syncthreads();
  if (wc < 2){
    #pragma unroll
    for (int mi=0;mi<4;mi++){
      #pragma unroll
      for (int ni=0;ni<4;ni++){
        int col = wc*64 + ni*16 + lc;
        #pragma unroll
        for (int r=0;r<4;r++){
          int row = wr*64+mi*16+lr*4+r;
          float v = acc[mi][ni][r] * ((float*)smem)[row*129 + col];
          if (MODE==0) v *= QSCALE;
          outB[(size_t)(tm*128+row)*1024 + tn*128 + col] = f2bf(v);
        }
      }
    }
  }
  #undef STAGEP
}

// ======== 128x256 8-wave single GEMM, same T4+T2 pipeline (bf16 W) ========
template<int PEREXP, int OUTF>
__global__ __launch_bounds__(512) void k_gemmS(const u16* __restrict__ A, const u16* __restrict__ W,
  u16* __restrict__ outB, float* __restrict__ outF, const int* __restrict__ meta, int Mfixed)
{
  int tnN = gridDim.x;
  int bid = blockIdx.y*tnN + blockIdx.x;
  int chunk = gridDim.y >> 3;
  int xcd = bid & 7, j = bid >> 3;
  int jd = j / tnN;
  int tm = xcd*chunk + jd;
  int tn = j - jd*tnN;
  int M = Mfixed ? Mfixed : meta[161];
  if (tm*128 >= M) return;
  const u16* Wp = W;
  if (PEREXP) Wp = W + (size_t)(meta[192+tm]&7)*1048576;

  __shared__ __align__(16) u16 smem[73728];

  int tid=threadIdx.x, lane=tid&63;
  int w=tid>>6, wr=w>>2, wc=w&3, lc=lane&15, lr=lane>>4;
  int swz = lc&7;
  const f32x4 Z4 = {0.f,0.f,0.f,0.f};
  f32x4 acc[4][4];
  #pragma unroll
  for(int i=0;i<4;i++){
    #pragma unroll
    for(int j2=0;j2<4;j2++) acc[i][j2]=Z4;
  }
  size_t lanoff = (size_t)(tid>>3)*1024 + (size_t)(((tid&7)^((tid>>3)&7))*8);
  const u16* Ag = A  + (size_t)tm*131072 + lanoff;
  const u16* Bg = Wp + (size_t)tn*262144 + lanoff;
  int lo = tid*8;

  #define STAGES(ao, bo, kt) { \
    const u16* ga = Ag + (kt)*64; const u16* gb = Bg + (kt)*64; \
    gl_lds(ga,                 &smem[(ao) + lo]); \
    gl_lds(ga + (size_t)65536, &smem[(ao) + 4096 + lo]); \
    gl_lds(gb,                  &smem[(bo) + lo]); \
    gl_lds(gb + (size_t)65536,  &smem[(bo) + 4096 + lo]); \
    gl_lds(gb + (size_t)131072, &smem[(bo) + 8192 + lo]); \
    gl_lds(gb + (size_t)196608, &smem[(bo) + 12288 + lo]); }

  STAGES(0, 24576, 0);
  STAGES(8192, 40960, 1);
  int cur = 0;
  for (int kt=0; kt<16; ++kt){
    if (kt<15) asm volatile("s_waitcnt vmcnt(6)" ::: "memory");
    else       asm volatile("s_waitcnt vmcnt(0)" ::: "memory");
    __builtin_amdgcn_s_barrier();
    if (kt<14){
      int nid = kt+2; nid -= (nid/3)*3;
      STAGES(nid*8192, 24576+nid*16384, kt+2);
    }
    int ao = cur*8192, bo = 24576 + cur*16384;
    __builtin_amdgcn_s_setprio(1);
    #pragma unroll
    for (int kk=0; kk<2; ++kk){
      bf16x8 a[4], b[4];
      #pragma unroll
      for (int mi=0;mi<4;mi++){
        int row = wr*64+mi*16+lc;
        a[mi] = *(const bf16x8*)&smem[ao + row*64 + (((kk*4+lr)^swz)<<3)];
      }
      #pragma unroll
      for (int ni=0;ni<4;ni++){
        int row = wc*64+ni*16+lc;
        b[ni] = *(const bf16x8*)&smem[bo + row*64 + (((kk*4+lr)^swz)<<3)];
      }
      #pragma unroll
      for (int mi=0;mi<4;mi++){
        #pragma unroll
        for (int ni=0;ni<4;ni++)
          acc[mi][ni] = MFMA16(a[mi], b[ni], acc[mi][ni]);
      }
    }
    __builtin_amdgcn_s_setprio(0);
    cur = (cur==2)?0:cur+1;
  }
  #pragma unroll
  for (int mi=0;mi<4;mi++){
    #pragma unroll
    for (int ni=0;ni<4;ni++){
      int col = tn*256 + wc*64 + ni*16 + lc;
      #pragma unroll
      for (int r=0;r<4;r++){
        int row = tm*128 + wr*64 + mi*16 + lr*4 + r;
        if (OUTF) outF[(size_t)row*1024 + col] = acc[mi][ni][r];
        else      outB[(size_t)row*1024 + col] = f2bf(acc[mi][ni][r]);
      }
    }
  }
  #undef STAGES
}

// ---------- chunked causal linear attention, one block per (group, head) ----------
// q in TOKEN space (8192 rows), resolved via tokmap[base+row]
__global__ __launch_bounds__(256,1) void k_attn(const u16* __restrict__ qv, const u16* __restrict__ kv,
  const u16* __restrict__ vv, u16* __restrict__ o, const int* __restrict__ meta,
  const int* __restrict__ tokmap)
{
  int g = blockIdx.x>>3, h = blockIdx.x&7;
  int nch = meta[129+g];
  if (nch==0) return;
  int base = meta[96+g];
  __shared__ __align__(16) u16 Qs[64*136];
  __shared__ __align__(16) u16 Ks[64*136];
  __shared__ __align__(16) u16 KTs[128*72];
  __shared__ __align__(16) u16 VTs[128*72];
  __shared__ __align__(16) u16 Ts[128*136];
  __shared__ __align__(16) u16 Ps[64*72];
  int tid=threadIdx.x, w=tid>>6, lane=tid&63;
  int wr=w>>1, wc=w&1;
  int lr=lane>>4, lc=lane&15;
  {
    u32x4 z={0,0,0,0};
    for (int i=tid; i<128*136/8; i+=256) *(u32x4*)&Ts[i*8]=z;
  }
  const f32x4 Z4 = {0.f,0.f,0.f,0.f};
  f32x4 accT[4][4];
  #pragma unroll
  for (int i=0;i<4;i++){
    #pragma unroll
    for (int j=0;j<4;j++) accT[i][j]=Z4;
  }
  __syncthreads();
  const u16* kb = kv + (size_t)base*1024 + h*128;
  const u16* vb = vv + (size_t)base*1024 + h*128;
  u16* ob = o + (size_t)base*1024 + h*128;

  for (int c=0; c<nch; ++c){
    #pragma unroll
    for (int it=0; it<4; ++it){
      int id = tid + it*256;
      int row = id>>4, kc = id&15;
      int tok = tokmap[base + c*64 + row];
      *(u32x4*)&Qs[row*136 + kc*8] = *(const u32x4*)(qv + (size_t)tok*1024 + h*128 + kc*8);
      *(u32x4*)&Ks[row*136 + kc*8] = *(const u32x4*)(kb + (size_t)(c*64+row)*1024 + kc*8);
    }
    #pragma unroll
    for (int it=0; it<4; ++it){
      int id = tid + it*256;
      int j = id>>4, dg = id&15;
      u32x4 kx = *(const u32x4*)(kb + (size_t)(c*64+j)*1024 + dg*8);
      u32x4 vx = *(const u32x4*)(vb + (size_t)(c*64+j)*1024 + dg*8);
      #pragma unroll
      for (int t=0;t<4;t++){
        KTs[(dg*8+t*2  )*72 + j] = (u16)(kx[t]&0xffff);
        KTs[(dg*8+t*2+1)*72 + j] = (u16)(kx[t]>>16);
        VTs[(dg*8+t*2  )*72 + j] = (u16)(vx[t]&0xffff);
        VTs[(dg*8+t*2+1)*72 + j] = (u16)(vx[t]>>16);
      }
    }
    __syncthreads();
    bf16x8 qf[2][4];
    #pragma unroll
    for (int ti=0; ti<2; ++ti){
      #pragma unroll
      for (int ks=0; ks<4; ++ks)
        qf[ti][ks] = *(const bf16x8*)&Qs[(wr*32+ti*16+lc)*136 + ks*32 + lr*8];
    }
    f32x4 accO[2][4];
    #pragma unroll
    for (int i=0;i<2;i++){
      #pragma unroll
      for (int j=0;j<4;j++) accO[i][j]=Z4;
    }
    #pragma unroll
    for (int ks=0; ks<4; ++ks){
      bf16x8 bt[4];
      #pragma unroll
      for (int te=0; te<4; ++te)
        bt[te] = *(const bf16x8*)&Ts[(wc*64+te*16+lc)*136 + ks*32 + lr*8];
      #pragma unroll
      for (int ti=0; ti<2; ++ti){
        #pragma unroll
        for (int te=0; te<4; ++te)
          accO[ti][te] = MFMA16(qf[ti][ks], bt[te], accO[ti][te]);
      }
    }
    f32x4 accP[2][2];
    #pragma unroll
    for (int i=0;i<2;i++){
      #pragma unroll
      for (int j=0;j<2;j++) accP[i][j]=Z4;
    }
    #pragma unroll
    for (int ks=0; ks<4; ++ks){
      bf16x8 bk[2];
      #pragma unroll
      for (int tj=0; tj<2; ++tj)
        bk[tj] = *(const bf16x8*)&Ks[(wc*32+tj*16+lc)*136 + ks*32 + lr*8];
      #pragma unroll
      for (int ti=0; ti<2; ++ti){
        #pragma unroll
        for (int tj=0; tj<2; ++tj)
          accP[ti][tj] = MFMA16(qf[ti][ks], bk[tj], accP[ti][tj]);
      }
    }
    #pragma unroll
    for (int ti=0; ti<2; ++ti){
      #pragma unroll
      for (int tj=0; tj<2; ++tj){
        #pragma unroll
        for (int r=0;r<4;r++){
          int i = wr*32+ti*16+lr*4+r;
          int j = wc*32+tj*16+lc;
          Ps[i*72 + j] = f2bf( (j<=i) ? accP[ti][tj][r] : 0.f );
        }
      }
    }
    __syncthreads();
    #pragma unroll
    for (int ks=0; ks<2; ++ks){
      bf16x8 ap[2], bv[4];
      #pragma unroll
      for (int ti=0; ti<2; ++ti)
        ap[ti] = *(const bf16x8*)&Ps[(wr*32+ti*16+lc)*72 + ks*32 + lr*8];
      #pragma unroll
      for (int te=0; te<4; ++te)
        bv[te] = *(const bf16x8*)&VTs[(wc*64+te*16+lc)*72 + ks*32 + lr*8];
      #pragma unroll
      for (int ti=0; ti<2; ++ti){
        #pragma unroll
        for (int te=0; te<4; ++te)
          accO[ti][te] = MFMA16(ap[ti], bv[te], accO[ti][te]);
      }
    }
    #pragma unroll
    for (int ks=0; ks<2; ++ks){
      bf16x8 av[4], bk2[4];
      #pragma unroll
      for (int te=0; te<4; ++te)
        av[te] = *(const bf16x8*)&VTs[(wr*64+te*16+lc)*72 + ks*32 + lr*8];
      #pragma unroll
      for (int td=0; td<4; ++td)
        bk2[td] = *(const bf16x8*)&KTs[(wc*64+td*16+lc)*72 + ks*32 + lr*8];
      #pragma unroll
      for (int te=0; te<4; ++te){
        #pragma unroll
        for (int td=0; td<4; ++td)
          accT[te][td] = MFMA16(av[te], bk2[td], accT[te][td]);
      }
    }
    #pragma unroll
    for (int ti=0; ti<2; ++ti){
      #pragma unroll
      for (int te=0; te<4; ++te){
        int ecol = wc*64+te*16+lc;
        #pragma unroll
        for (int r=0;r<4;r++){
          int i = wr*32+ti*16+lr*4+r;
          ob[(size_t)(c*64+i)*1024 + ecol] = f2bf(accO[ti][te][r]);
        }
      }
    }
    __syncthreads();
    #pragma unroll
    for (int te=0; te<4; ++te){
      #pragma unroll
      for (int td=0; td<4; ++td){
        int dk = wc*64+td*16+lc;
        #pragma unroll
        for (int r=0;r<4;r++){
          int erow = wr*64+te*16+lr*4+r;
          Ts[erow*136 + dk] = f2bf(accT[te][td][r]);
        }
      }
    }
    __syncthreads();
  }
}

// ---------- combine + per-head RMSNorm ----------
__global__ __launch_bounds__(256) void k_comb(const u16* __restrict__ o, const int* __restrict__ sel,
  const float* __restrict__ rw, const int* __restrict__ slot_of, const int* __restrict__ meta,
  const float* __restrict__ nw, u16* __restrict__ fin)
{
  int w=threadIdx.x>>6, lane=threadIdx.x&63;
  int tok = blockIdx.x*4 + w;
  int b = tok>>11;
  int sv = sel[tok];
  float acc[16];
  #pragma unroll
  for (int i=0;i<16;i++) acc[i]=0.f;
  #pragma unroll
  for (int kk=0; kk<2; ++kk){
    int e = kk ? ((sv>>8)&255) : (sv&255);
    int j = slot_of[tok*2 + kk];
    if (j < 0) continue;
    float wgt = rw[tok*2+kk];
    int row = meta[96 + b*8 + e] + j;
    const u16* orow = o + (size_t)row*1024 + lane*16;
    #pragma unroll
    for (int q=0;q<2;q++){
      u32x4 v = *(const u32x4*)(orow + q*8);
      #pragma unroll
      for (int t=0;t<4;t++){
        acc[q*8+t*2]   += wgt * bf2f((u16)(v[t]&0xffff));
        acc[q*8+t*2+1] += wgt * bf2f((u16)(v[t]>>16));
      }
    }
  }
  float ssq=0.f;
  #pragma unroll
  for (int i=0;i<16;i++) ssq += acc[i]*acc[i];
  ssq += __shfl_xor(ssq,1,64);
  ssq += __shfl_xor(ssq,2,64);
  ssq += __shfl_xor(ssq,4,64);
  float sc = rsqrtf(ssq*(1.f/128.f) + 1e-5f);
  int cbase = (lane&7)*16;
  u32x4 o0, o1;
  #pragma unroll
  for (int t=0;t<4;t++)
    o0[t] = pack2(acc[2*t]*sc*nw[cbase+2*t], acc[2*t+1]*sc*nw[cbase+2*t+1]);
  #pragma unroll
  for (int t=0;t<4;t++)
    o1[t] = pack2(acc[8+2*t]*sc*nw[cbase+8+2*t], acc[8+2*t+1]*sc*nw[cbase+8+2*t+1]);
  u16* fp = fin + (size_t)tok*1024 + lane*16;
  *(u32x4*)fp     = o0;
  *(u32x4*)(fp+8) = o1;
}

// ---------- host launcher ----------
extern "C" void kernel_launch(void* const* d_in, const int* in_sizes, int n_in,
                              void* d_out, int out_size, void* d_ws, size_t ws_size,
                              hipStream_t stream)
{
  (void)in_sizes; (void)n_in;
  const float* x     = (const float*)d_in[0];
  const float* gate  = (const float*)d_in[1];
  const float* q_w   = (const float*)d_in[2];
  const float* k_w   = (const float*)d_in[3];
  const float* v_w   = (const float*)d_in[4];
  const float* fmq1  = (const float*)d_in[5];
  const float* fmq2  = (const float*)d_in[6];
  const float* fmk1  = (const float*)d_in[7];
  const float* fmk2  = (const float*)d_in[8];
  const float* norm_w= (const float*)d_in[9];
  const float* o_w   = (const float*)d_in[10];
  float* out = (float*)d_out;

  uint8_t* ws = (uint8_t*)d_ws;
  size_t off = 0;
  auto alloc = [&](size_t bytes)->void*{ void* p = ws + off; off += (bytes + 255) & ~(size_t)255; return p; };
  int*   meta = (int*)alloc(4096);
  int*   sel  = (int*)alloc(8192*4);
  float* rwb  = (float*)alloc(8192*2*4);
  int*   slot = (int*)alloc(16384*4);
  int*   srcf = (int*)alloc((size_t)32*2048*4);
  int*   tokm = (int*)alloc((size_t)RMAX*4);
  u16* wA = (u16*)alloc((size_t)2097152*2);            // q cat weights (2048x1024)
  u16* wB = (u16*)alloc((size_t)8*2097152*2);          // k cat weights per expert
  u16* xb  = (u16*)alloc((size_t)8192*1024*2);         // bf16(x), token space
  u16* xg  = (u16*)alloc((size_t)RMAX*1024*2);
  u16* qh  = (u16*)alloc((size_t)8192*1024*2);         // q-hat, token space
  u16* kh  = (u16*)alloc((size_t)RMAX*1024*2);
  u16* vv  = (u16*)alloc((size_t)RMAX*1024*2);
  if (off > ws_size){
    hipMemsetAsync(d_out, 0x7F, (size_t)out_size*4, stream);
    return;
  }
  u16* ob  = xg;    // reuse after GEMMs consumed xg
  u16* fin = qh;    // reuse after attn consumed qh
  u16* wOb = wA;    // reuse after q-GEMM consumed wA
  u16* wVb = wB;    // reuse after k-GEMM consumed wB

  k_route<<<2048,256,0,stream>>>(x, gate, sel, rwb);
  k_count<<<32,256,0,stream>>>(sel, slot, srcf, meta);
  k_bases<<<1,64,0,stream>>>(meta);
  k_cvt<<<1024,256,0,stream>>>(x, xb, 1048576L);
  k_gather<<<dim3(32,32),256,0,stream>>>(x, srcf, meta, xg, tokm);
  k_prep<<<dim3(8,144),256,0,stream>>>(q_w, k_w, fmq1, fmq2, fmk1, fmk2, wA, wB);
  k_gemmP<0><<<dim3(8,64),512,0,stream>>>(xb, wA, qh, meta);
  k_cvt<<<256,256,0,stream>>>(o_w, wOb, 131072L);
  k_gemmP<1><<<dim3(8,160),512,0,stream>>>(xg, wB, kh, meta);
  k_cvt<<<1024,256,0,stream>>>(v_w, wVb, 1048576L);
  k_gemmS<1,0><<<dim3(4,160),512,0,stream>>>(xg, wVb, vv, nullptr, meta, 0);
  k_attn<<<256,256,0,stream>>>(qh, kh, vv, ob, meta, tokm);
  k_comb<<<2048,256,0,stream>>>(ob, sel, rwb, slot, meta, norm_w, fin);
  k_gemmS<0,1><<<dim3(4,64),512,0,stream>>>(fin, wOb, nullptr, out, meta, 8192);
}

// Round 8
// 433.853 us; speedup vs baseline: 1.8611x; 1.0665x over previous
//
#include <hip/hip_runtime.h>
#include <stdint.h>

// ---------- types / helpers ----------
typedef unsigned short u16;
typedef unsigned int   u32;
typedef __attribute__((ext_vector_type(4))) float f32x4;
typedef __attribute__((ext_vector_type(4))) u32   u32x4;
typedef __attribute__((ext_vector_type(8))) __bf16 bf16x8;

#define MFMA16(a,b,c) __builtin_amdgcn_mfma_f32_16x16x32_bf16((a),(b),(c),0,0,0)

#define QSCALE 0.08838834764831845f   // 128^-0.5
#define RMAX   20480                  // sum roundup(min(n,2048),128) <= 16384+32*127

__device__ __forceinline__ float bf2f(u16 x){ u32 u=((u32)x)<<16; float f; __builtin_memcpy(&f,&u,4); return f; }
__device__ __forceinline__ u16 f2bf(float f){ u32 u; __builtin_memcpy(&u,&f,4); u = u + 0x7FFFu + ((u>>16)&1u); return (u16)(u>>16); }
__device__ __forceinline__ u32 pack2(float a, float b){ return (u32)f2bf(a) | ((u32)f2bf(b)<<16); }

// async global->LDS, 16B per lane
__device__ __forceinline__ void gl_lds(const u16* g, u16* l){
  __builtin_amdgcn_global_load_lds(
      (const __attribute__((address_space(1))) void*)g,
      (__attribute__((address_space(3))) void*)l, 16, 0, 0);
}

// transposed-tile addr with octet swizzle: row stride 72 u16; octet = (off8)>>3
#define TSW(row, oct) ((row)*72 + ((((oct) ^ (((row)>>3)&7)))<<3))

// meta layout (ints): [0,32) n  [32,64) nact  [64,96) npad  [96,129) base
// [129,161) nchunks  [161] R_total  [192,352) 128-tile -> group map

// ---------- device bodies for fused pre-pass ----------
__device__ __forceinline__ void cvt_body(const float* __restrict__ s, u16* __restrict__ d,
                                         long n8, int lb, int nb){
  long idx = (long)lb*256 + threadIdx.x;
  long stride = (long)nb*256;
  for (long i=idx; i<n8; i+=stride){
    const float* p = s + i*8;
    f32x4 a = *(const f32x4*)p;
    f32x4 b = *(const f32x4*)(p+4);
    u32x4 o;
    o[0]=pack2(a[0],a[1]); o[1]=pack2(a[2],a[3]); o[2]=pack2(b[0],b[1]); o[3]=pack2(b[2],b[3]);
    *(u32x4*)(d + i*8) = o;
  }
}

__device__ __forceinline__ void route_body(const float* __restrict__ x, const float* __restrict__ gw,
  int* __restrict__ sel, float* __restrict__ rw, int lb)
{
  int w = threadIdx.x>>6, lane = threadIdx.x&63;
  int tok = lb*4 + w;
  const float* xr = x + (size_t)tok*1024 + lane*16;
  f32x4 xv[4];
  #pragma unroll
  for (int q=0;q<4;q++) xv[q] = *(const f32x4*)(xr + q*4);
  float part[8];
  #pragma unroll
  for (int e=0;e<8;e++){
    const float* g = gw + e*1024 + lane*16;
    float s = 0.f;
    #pragma unroll
    for (int q=0;q<4;q++){
      f32x4 gv = *(const f32x4*)(g + q*4);
      s += xv[q][0]*gv[0] + xv[q][1]*gv[1] + xv[q][2]*gv[2] + xv[q][3]*gv[3];
    }
    part[e]=s;
  }
  #pragma unroll
  for (int e=0;e<8;e++){
    float v = part[e];
    #pragma unroll
    for (int off=32; off>0; off>>=1) v += __shfl_xor(v, off, 64);
    part[e]=v;
  }
  if (lane==0){
    int i0=0; float m0=part[0];
    #pragma unroll
    for (int e=1;e<8;e++) if (part[e]>m0){ m0=part[e]; i0=e; }
    int i1=0; float m1=-3.4e38f;
    #pragma unroll
    for (int e=0;e<8;e++) if (e!=i0 && part[e]>m1){ m1=part[e]; i1=e; }
    sel[tok] = i0 | (i1<<8);
    float e1 = expf(m1-m0);
    float inv = 1.f/(1.f+e1);
    rw[tok*2+0] = inv;
    rw[tok*2+1] = e1*inv;
  }
}

__device__ __forceinline__ void prep_body(
  const float* __restrict__ q_w, const float* __restrict__ k_w,
  const float* __restrict__ fmq1, const float* __restrict__ fmq2,
  const float* __restrict__ fmk1, const float* __restrict__ fmk2,
  u16* __restrict__ wA, u16* __restrict__ wB, int l, u16* shmem)
{
  int gi = l>>3;
  int c0 = (l&7)*128;
  const float* fm; const float* ws; u16* wd;
  if (gi < 8)      { int h=gi;    fm=fmq1; ws=q_w + (size_t)h*131072; wd=wA + (size_t)h*262144; }
  else if (gi < 16){ int h=gi-8;  fm=fmq2; ws=q_w + (size_t)h*131072; wd=wA + (size_t)h*262144 + 131072; }
  else if (gi < 80){ int t=gi-16, e=t>>3, h=t&7; fm=fmk1; ws=k_w + (size_t)(e*8+h)*131072; wd=wB + (size_t)e*2097152 + (size_t)h*262144; }
  else             { int t=gi-80, e=t>>3, h=t&7; fm=fmk2; ws=k_w + (size_t)(e*8+h)*131072; wd=wB + (size_t)e*2097152 + (size_t)h*262144 + 131072; }
  u16* Af = shmem;
  u16* Bf = shmem + 128*136;
  int tid = threadIdx.x;
  for (int i=tid; i<4096; i+=256){
    int row = i>>5, col = (i&31)*4;
    f32x4 v = *(const f32x4*)&fm[row*128 + col];
    u16* dp = &Af[row*136 + col];
    *(u32*)dp     = pack2(v[0],v[1]);
    *(u32*)(dp+2) = pack2(v[2],v[3]);
  }
  for (int i=tid; i<4096; i+=256){
    int dd = i>>5, cq = (i&31)*4;
    f32x4 v = *(const f32x4*)&ws[(size_t)dd*1024 + c0 + cq];
    #pragma unroll
    for (int j=0;j<4;j++){
      int c = cq+j;
      Bf[c*136 + (dd ^ (((c>>2)&3)<<3))] = f2bf(v[j]);
    }
  }
  __syncthreads();
  int lane=tid&63, w=tid>>6, wr=w>>1, wc=w&1, lc=lane&15, lr=lane>>4;
  const f32x4 Z4 = {0.f,0.f,0.f,0.f};
  f32x4 acc[4][4];
  #pragma unroll
  for (int i=0;i<4;i++){
    #pragma unroll
    for (int j=0;j<4;j++) acc[i][j]=Z4;
  }
  #pragma unroll
  for (int kk=0; kk<4; ++kk){
    bf16x8 a[4], b[4];
    #pragma unroll
    for (int mi=0;mi<4;mi++)
      a[mi] = *(const bf16x8*)&Af[(wr*64+mi*16+lc)*136 + kk*32 + lr*8];
    #pragma unroll
    for (int ni=0;ni<4;ni++){
      int c = wc*64+ni*16+lc;
      b[ni] = *(const bf16x8*)&Bf[c*136 + ((kk*32 + lr*8) ^ (((c>>2)&3)<<3))];
    }
    #pragma unroll
    for (int mi=0;mi<4;mi++){
      #pragma unroll
      for (int ni=0;ni<4;ni++)
        acc[mi][ni] = MFMA16(a[mi], b[ni], acc[mi][ni]);
    }
  }
  int r0=lr*4;
  #pragma unroll
  for (int mi=0;mi<4;mi++){
    #pragma unroll
    for (int ni=0;ni<4;ni++){
      int col = c0 + wc*64 + ni*16 + lc;
      #pragma unroll
      for (int r=0;r<4;r++){
        int row = wr*64 + mi*16 + r0 + r;
        wd[(size_t)row*1024 + col] = f2bf(acc[mi][ni][r]);
      }
    }
  }
}

// ---------- fused pre-pass: route (0..2047) + prep (2048..3199) + cvt x (3200..3455) ----------
__global__ __launch_bounds__(256) void k_pre(
  const float* __restrict__ x, const float* __restrict__ gw,
  int* __restrict__ sel, float* __restrict__ rw,
  const float* __restrict__ q_w, const float* __restrict__ k_w,
  const float* __restrict__ fmq1, const float* __restrict__ fmq2,
  const float* __restrict__ fmk1, const float* __restrict__ fmk2,
  u16* __restrict__ wA, u16* __restrict__ wB, u16* __restrict__ xb)
{
  __shared__ __align__(16) u16 shmem[2*128*136];
  int bid = blockIdx.x;
  if (bid < 2048)      route_body(x, gw, sel, rw, bid);
  else if (bid < 3200) prep_body(q_w, k_w, fmq1, fmq2, fmk1, fmk2, wA, wB, bid-2048, shmem);
  else                 cvt_body(x, xb, 1048576L, bid-3200, 256);
}

// ---------- fused cvt: v_w (0..255) + o_w (256..287) ----------
__global__ __launch_bounds__(256) void k_cvtVO(const float* __restrict__ v_w, const float* __restrict__ o_w,
  u16* __restrict__ wVb, u16* __restrict__ wOb)
{
  int bid = blockIdx.x;
  if (bid < 256) cvt_body(v_w, wVb, 1048576L, bid, 256);
  else           cvt_body(o_w, wOb, 131072L, bid-256, 32);
}

// ---------- per-(b,e) counting sort ----------
__global__ __launch_bounds__(256) void k_count(const int* __restrict__ sel,
  int* __restrict__ slot_of, int* __restrict__ src_of, int* __restrict__ meta)
{
  int g = blockIdx.x, b = g>>3, e = g&7;
  int tid = threadIdx.x;
  __shared__ int cn[256];
  unsigned char ex[16];
  int cnt=0;
  #pragma unroll
  for (int i=0;i<16;i++){
    int t = tid*16+i;
    int sv = sel[b*2048 + (t>>1)];
    int ee = (t&1) ? ((sv>>8)&255) : (sv&255);
    ex[i]=(unsigned char)ee;
    cnt += (ee==e);
  }
  cn[tid]=cnt;
  __syncthreads();
  for (int off=1; off<256; off<<=1){
    int v = (tid>=off) ? cn[tid-off] : 0;
    __syncthreads();
    cn[tid] += v;
    __syncthreads();
  }
  int total = cn[255];
  int run = cn[tid]-cnt;
  int shift = total>2048 ? total-2048 : 0;
  #pragma unroll
  for (int i=0;i<16;i++){
    int t = tid*16+i;
    if (ex[i]==e){
      int j = run - shift;
      run++;
      slot_of[b*4096 + t] = (j>=0)? j : -1;
      if (j>=0) src_of[g*2048 + j] = t;
    }
  }
  if (tid==0) meta[g]=total;
}

// ---------- group bases + tile->group map ----------
__global__ void k_bases(int* meta){
  if (threadIdx.x || blockIdx.x) return;
  int basev=0, t=0;
  meta[96]=0;
  for (int g=0; g<32; ++g){
    int n = meta[g];
    int nact = n<2048 ? n : 2048;
    int npad = (nact+127)&~127;
    meta[32+g]=nact;
    meta[64+g]=npad;
    meta[129+g]=(nact+63)>>6;
    for (int i=0;i<(npad>>7);++i) meta[192+t++]=g;
    basev += npad;
    meta[97+g]=basev;
  }
  meta[161]=basev;
}

// ---------- gather x rows -> compact bf16 + row->token map ----------
__global__ __launch_bounds__(256) void k_gather(const float* __restrict__ x,
  const int* __restrict__ src_of, const int* __restrict__ meta, u16* __restrict__ xg,
  int* __restrict__ tokmap)
{
  int g = blockIdx.y, jb = blockIdx.x;
  int npad = meta[64+g];
  if (jb*64 >= npad) return;
  int nact = meta[32+g], base = meta[96+g];
  int tid = threadIdx.x;
  int j = jb*64 + (tid>>2);
  int quart = tid&3;
  int src = (j<nact) ? src_of[g*2048+j] : -1;
  int token = (src>=0) ? ((g>>3)*2048 + (src>>1)) : 0;
  if (quart==0) tokmap[base+j] = token;
  u16* orow = xg + ((size_t)(base+j))*1024 + quart*256;
  if (src>=0){
    const float* xr = x + ((size_t)token)*1024 + quart*256;
    for (int i=0;i<256;i+=8){
      f32x4 a  = *(const f32x4*)(xr+i);
      f32x4 bv = *(const f32x4*)(xr+i+4);
      u32x4 o;
      o[0]=pack2(a[0],a[1]); o[1]=pack2(a[2],a[3]); o[2]=pack2(bv[0],bv[1]); o[3]=pack2(bv[2],bv[3]);
      *(u32x4*)(orow+i)=o;
    }
  } else {
    u32x4 z = {0,0,0,0};
    for (int i=0;i<256;i+=8) *(u32x4*)(orow+i)=z;
  }
}

// ======== fused q+k 128x256 8-wave GEMM, depth-2 counted-vmcnt (T4) + swizzle (T2) ========
// blocks [0,512): q role (A=xb token space, W=wA, M=8192, *QSCALE)
// blocks [512,1792): k role (A=xg, W=wB per-expert, M=meta[161])
__global__ __launch_bounds__(512) void k_gemmQK(const u16* __restrict__ xb, const u16* __restrict__ xg,
  const u16* __restrict__ wA, const u16* __restrict__ wB,
  u16* __restrict__ qh, u16* __restrict__ kh, const int* __restrict__ meta)
{
  int bid = blockIdx.x;
  const u16 *A, *Wp; u16* outB; int tm, tn; float scl;
  if (bid < 512){
    int l=bid, xcd=l&7, j=l>>3, jd=j>>3;
    tm = xcd*8 + jd; tn = j - jd*8;
    A = xb; Wp = wA; outB = qh; scl = QSCALE;
  } else {
    int l=bid-512, xcd=l&7, j=l>>3, jd=j>>3;
    tm = xcd*20 + jd; tn = j - jd*8;
    if (tm*128 >= meta[161]) return;
    A = xg; Wp = wB + (size_t)(meta[192+tm]&7)*2097152; outB = kh; scl = 1.0f;
  }

  __shared__ __align__(16) u16 smem[73728];   // 144 KB

  int tid=threadIdx.x, lane=tid&63;
  int w=tid>>6, wr=w>>2, wc=w&3, lc=lane&15, lr=lane>>4;
  int swz = lc&7;
  const f32x4 Z4 = {0.f,0.f,0.f,0.f};
  f32x4 acc[4][4];
  #pragma unroll
  for(int i=0;i<4;i++){
    #pragma unroll
    for(int j2=0;j2<4;j2++) acc[i][j2]=Z4;
  }
  size_t lanoff = (size_t)(tid>>3)*1024 + (size_t)(((tid&7)^((tid>>3)&7))*8);
  const u16* Ag = A  + (size_t)tm*131072 + lanoff;
  const u16* Bg = Wp + (size_t)tn*262144 + lanoff;
  int lo = tid*8;

  #define STAGEQK(ao, bo, kt) { \
    const u16* ga = Ag + (kt)*64; const u16* gb = Bg + (kt)*64; \
    gl_lds(ga,                 &smem[(ao) + lo]); \
    gl_lds(ga + (size_t)65536, &smem[(ao) + 4096 + lo]); \
    gl_lds(gb,                  &smem[(bo) + lo]); \
    gl_lds(gb + (size_t)65536,  &smem[(bo) + 4096 + lo]); \
    gl_lds(gb + (size_t)131072, &smem[(bo) + 8192 + lo]); \
    gl_lds(gb + (size_t)196608, &smem[(bo) + 12288 + lo]); }

  STAGEQK(0, 24576, 0);
  STAGEQK(8192, 40960, 1);
  int cur = 0;
  for (int kt=0; kt<16; ++kt){
    if (kt<15) asm volatile("s_waitcnt vmcnt(6)" ::: "memory");
    else       asm volatile("s_waitcnt vmcnt(0)" ::: "memory");
    __builtin_amdgcn_s_barrier();
    if (kt<14){
      int nid = kt+2; nid -= (nid/3)*3;
      STAGEQK(nid*8192, 24576+nid*16384, kt+2);
    }
    int ao = cur*8192, bo = 24576 + cur*16384;
    __builtin_amdgcn_s_setprio(1);
    #pragma unroll
    for (int kk=0; kk<2; ++kk){
      bf16x8 a[4], b[4];
      #pragma unroll
      for (int mi=0;mi<4;mi++){
        int row = wr*64+mi*16+lc;
        a[mi] = *(const bf16x8*)&smem[ao + row*64 + (((kk*4+lr)^swz)<<3)];
      }
      #pragma unroll
      for (int ni=0;ni<4;ni++){
        int row = wc*64+ni*16+lc;
        b[ni] = *(const bf16x8*)&smem[bo + row*64 + (((kk*4+lr)^swz)<<3)];
      }
      #pragma unroll
      for (int mi=0;mi<4;mi++){
        #pragma unroll
        for (int ni=0;ni<4;ni++)
          acc[mi][ni] = MFMA16(a[mi], b[ni], acc[mi][ni]);
      }
    }
    __builtin_amdgcn_s_setprio(0);
    cur = (cur==2)?0:cur+1;
  }
  __syncthreads();
  if (wc >= 2){
    #pragma unroll
    for (int mi=0;mi<4;mi++){
      #pragma unroll
      for (int ni=0;ni<4;ni++){
        int col = (wc-2)*64 + ni*16 + lc;
        #pragma unroll
        for (int r=0;r<4;r++)
          ((float*)smem)[(wr*64+mi*16+lr*4+r)*129 + col] = acc[mi][ni][r];
      }
    }
  }
  __syncthreads();
  if (wc < 2){
    #pragma unroll
    for (int mi=0;mi<4;mi++){
      #pragma unroll
      for (int ni=0;ni<4;ni++){
        int col = wc*64 + ni*16 + lc;
        #pragma unroll
        for (int r=0;r<4;r++){
          int row = wr*64+mi*16+lr*4+r;
          float v = acc[mi][ni][r] * ((float*)smem)[row*129 + col] * scl;
          outB[(size_t)(tm*128+row)*1024 + tn*128 + col] = f2bf(v);
        }
      }
    }
  }
  #undef STAGEQK
}

// ======== 128x256 8-wave single GEMM, T4+T2 pipeline (bf16 W) ========
template<int PEREXP, int OUTF>
__global__ __launch_bounds__(512) void k_gemmS(const u16* __restrict__ A, const u16* __restrict__ W,
  u16* __restrict__ outB, float* __restrict__ outF, const int* __restrict__ meta, int Mfixed)
{
  int tnN = gridDim.x;
  int bid = blockIdx.y*tnN + blockIdx.x;
  int chunk = gridDim.y >> 3;
  int xcd = bid & 7, j = bid >> 3;
  int jd = j / tnN;
  int tm = xcd*chunk + jd;
  int tn = j - jd*tnN;
  int M = Mfixed ? Mfixed : meta[161];
  if (tm*128 >= M) return;
  const u16* Wp = W;
  if (PEREXP) Wp = W + (size_t)(meta[192+tm]&7)*1048576;

  __shared__ __align__(16) u16 smem[73728];

  int tid=threadIdx.x, lane=tid&63;
  int w=tid>>6, wr=w>>2, wc=w&3, lc=lane&15, lr=lane>>4;
  int swz = lc&7;
  const f32x4 Z4 = {0.f,0.f,0.f,0.f};
  f32x4 acc[4][4];
  #pragma unroll
  for(int i=0;i<4;i++){
    #pragma unroll
    for(int j2=0;j2<4;j2++) acc[i][j2]=Z4;
  }
  size_t lanoff = (size_t)(tid>>3)*1024 + (size_t)(((tid&7)^((tid>>3)&7))*8);
  const u16* Ag = A  + (size_t)tm*131072 + lanoff;
  const u16* Bg = Wp + (size_t)tn*262144 + lanoff;
  int lo = tid*8;

  #define STAGES(ao, bo, kt) { \
    const u16* ga = Ag + (kt)*64; const u16* gb = Bg + (kt)*64; \
    gl_lds(ga,                 &smem[(ao) + lo]); \
    gl_lds(ga + (size_t)65536, &smem[(ao) + 4096 + lo]); \
    gl_lds(gb,                  &smem[(bo) + lo]); \
    gl_lds(gb + (size_t)65536,  &smem[(bo) + 4096 + lo]); \
    gl_lds(gb + (size_t)131072, &smem[(bo) + 8192 + lo]); \
    gl_lds(gb + (size_t)196608, &smem[(bo) + 12288 + lo]); }

  STAGES(0, 24576, 0);
  STAGES(8192, 40960, 1);
  int cur = 0;
  for (int kt=0; kt<16; ++kt){
    if (kt<15) asm volatile("s_waitcnt vmcnt(6)" ::: "memory");
    else       asm volatile("s_waitcnt vmcnt(0)" ::: "memory");
    __builtin_amdgcn_s_barrier();
    if (kt<14){
      int nid = kt+2; nid -= (nid/3)*3;
      STAGES(nid*8192, 24576+nid*16384, kt+2);
    }
    int ao = cur*8192, bo = 24576 + cur*16384;
    __builtin_amdgcn_s_setprio(1);
    #pragma unroll
    for (int kk=0; kk<2; ++kk){
      bf16x8 a[4], b[4];
      #pragma unroll
      for (int mi=0;mi<4;mi++){
        int row = wr*64+mi*16+lc;
        a[mi] = *(const bf16x8*)&smem[ao + row*64 + (((kk*4+lr)^swz)<<3)];
      }
      #pragma unroll
      for (int ni=0;ni<4;ni++){
        int row = wc*64+ni*16+lc;
        b[ni] = *(const bf16x8*)&smem[bo + row*64 + (((kk*4+lr)^swz)<<3)];
      }
      #pragma unroll
      for (int mi=0;mi<4;mi++){
        #pragma unroll
        for (int ni=0;ni<4;ni++)
          acc[mi][ni] = MFMA16(a[mi], b[ni], acc[mi][ni]);
      }
    }
    __builtin_amdgcn_s_setprio(0);
    cur = (cur==2)?0:cur+1;
  }
  #pragma unroll
  for (int mi=0;mi<4;mi++){
    #pragma unroll
    for (int ni=0;ni<4;ni++){
      int col = tn*256 + wc*64 + ni*16 + lc;
      #pragma unroll
      for (int r=0;r<4;r++){
        int row = tm*128 + wr*64 + mi*16 + lr*4 + r;
        if (OUTF) outF[(size_t)row*1024 + col] = acc[mi][ni][r];
        else      outB[(size_t)row*1024 + col] = f2bf(acc[mi][ni][r]);
      }
    }
  }
  #undef STAGES
}

// ---------- chunked causal linear attention, one block per (group, head) ----------
__global__ __launch_bounds__(256,1) void k_attn(const u16* __restrict__ qv, const u16* __restrict__ kv,
  const u16* __restrict__ vv, u16* __restrict__ o, const int* __restrict__ meta,
  const int* __restrict__ tokmap)
{
  int g = blockIdx.x>>3, h = blockIdx.x&7;
  int nch = meta[129+g];
  if (nch==0) return;
  int base = meta[96+g];
  __shared__ __align__(16) u16 Qs[64*136];
  __shared__ __align__(16) u16 Ks[64*136];
  __shared__ __align__(16) u16 KTs[128*72];
  __shared__ __align__(16) u16 VTs[128*72];
  __shared__ __align__(16) u16 Ts[128*136];
  __shared__ __align__(16) u16 Ps[64*72];
  int tid=threadIdx.x, w=tid>>6, lane=tid&63;
  int wr=w>>1, wc=w&1;
  int lr=lane>>4, lc=lane&15;
  {
    u32x4 z={0,0,0,0};
    for (int i=tid; i<128*136/8; i+=256) *(u32x4*)&Ts[i*8]=z;
  }
  const f32x4 Z4 = {0.f,0.f,0.f,0.f};
  f32x4 accT[4][4];
  #pragma unroll
  for (int i=0;i<4;i++){
    #pragma unroll
    for (int j=0;j<4;j++) accT[i][j]=Z4;
  }
  __syncthreads();
  const u16* kb = kv + (size_t)base*1024 + h*128;
  const u16* vb = vv + (size_t)base*1024 + h*128;
  u16* ob = o + (size_t)base*1024 + h*128;

  for (int c=0; c<nch; ++c){
    #pragma unroll
    for (int it=0; it<4; ++it){
      int id = tid + it*256;
      int row = id>>4, kc = id&15;
      int tok = tokmap[base + c*64 + row];
      *(u32x4*)&Qs[row*136 + kc*8] = *(const u32x4*)(qv + (size_t)tok*1024 + h*128 + kc*8);
      *(u32x4*)&Ks[row*136 + kc*8] = *(const u32x4*)(kb + (size_t)(c*64+row)*1024 + kc*8);
    }
    // transpose-stage k^T, v^T with octet swizzle (4-way banks instead of 32-way)
    #pragma unroll
    for (int it=0; it<4; ++it){
      int id = tid + it*256;
      int j = id>>4, dg = id&15;
      int col = (((j>>3) ^ (dg&7))<<3) + (j&7);
      u32x4 kx = *(const u32x4*)(kb + (size_t)(c*64+j)*1024 + dg*8);
      u32x4 vx = *(const u32x4*)(vb + (size_t)(c*64+j)*1024 + dg*8);
      #pragma unroll
      for (int t=0;t<4;t++){
        KTs[(dg*8+t*2  )*72 + col] = (u16)(kx[t]&0xffff);
        KTs[(dg*8+t*2+1)*72 + col] = (u16)(kx[t]>>16);
        VTs[(dg*8+t*2  )*72 + col] = (u16)(vx[t]&0xffff);
        VTs[(dg*8+t*2+1)*72 + col] = (u16)(vx[t]>>16);
      }
    }
    __syncthreads();
    bf16x8 qf[2][4];
    #pragma unroll
    for (int ti=0; ti<2; ++ti){
      #pragma unroll
      for (int ks=0; ks<4; ++ks)
        qf[ti][ks] = *(const bf16x8*)&Qs[(wr*32+ti*16+lc)*136 + ks*32 + lr*8];
    }
    f32x4 accO[2][4];
    #pragma unroll
    for (int i=0;i<2;i++){
      #pragma unroll
      for (int j=0;j<4;j++) accO[i][j]=Z4;
    }
    #pragma unroll
    for (int ks=0; ks<4; ++ks){
      bf16x8 bt[4];
      #pragma unroll
      for (int te=0; te<4; ++te)
        bt[te] = *(const bf16x8*)&Ts[(wc*64+te*16+lc)*136 + ks*32 + lr*8];
      #pragma unroll
      for (int ti=0; ti<2; ++ti){
        #pragma unroll
        for (int te=0; te<4; ++te)
          accO[ti][te] = MFMA16(qf[ti][ks], bt[te], accO[ti][te]);
      }
    }
    f32x4 accP[2][2];
    #pragma unroll
    for (int i=0;i<2;i++){
      #pragma unroll
      for (int j=0;j<2;j++) accP[i][j]=Z4;
    }
    #pragma unroll
    for (int ks=0; ks<4; ++ks){
      bf16x8 bk[2];
      #pragma unroll
      for (int tj=0; tj<2; ++tj)
        bk[tj] = *(const bf16x8*)&Ks[(wc*32+tj*16+lc)*136 + ks*32 + lr*8];
      #pragma unroll
      for (int ti=0; ti<2; ++ti){
        #pragma unroll
        for (int tj=0; tj<2; ++tj)
          accP[ti][tj] = MFMA16(qf[ti][ks], bk[tj], accP[ti][tj]);
      }
    }
    #pragma unroll
    for (int ti=0; ti<2; ++ti){
      #pragma unroll
      for (int tj=0; tj<2; ++tj){
        #pragma unroll
        for (int r=0;r<4;r++){
          int i = wr*32+ti*16+lr*4+r;
          int j = wc*32+tj*16+lc;
          Ps[i*72 + j] = f2bf( (j<=i) ? accP[ti][tj][r] : 0.f );
        }
      }
    }
    __syncthreads();
    #pragma unroll
    for (int ks=0; ks<2; ++ks){
      bf16x8 ap[2], bv[4];
      #pragma unroll
      for (int ti=0; ti<2; ++ti)
        ap[ti] = *(const bf16x8*)&Ps[(wr*32+ti*16+lc)*72 + ks*32 + lr*8];
      #pragma unroll
      for (int te=0; te<4; ++te)
        bv[te] = *(const bf16x8*)&VTs[TSW(wc*64+te*16+lc, ks*4+lr)];
      #pragma unroll
      for (int ti=0; ti<2; ++ti){
        #pragma unroll
        for (int te=0; te<4; ++te)
          accO[ti][te] = MFMA16(ap[ti], bv[te], accO[ti][te]);
      }
    }
    #pragma unroll
    for (int ks=0; ks<2; ++ks){
      bf16x8 av[4], bk2[4];
      #pragma unroll
      for (int te=0; te<4; ++te)
        av[te] = *(const bf16x8*)&VTs[TSW(wr*64+te*16+lc, ks*4+lr)];
      #pragma unroll
      for (int td=0; td<4; ++td)
        bk2[td] = *(const bf16x8*)&KTs[TSW(wc*64+td*16+lc, ks*4+lr)];
      #pragma unroll
      for (int te=0; te<4; ++te){
        #pragma unroll
        for (int td=0; td<4; ++td)
          accT[te][td] = MFMA16(av[te], bk2[td], accT[te][td]);
      }
    }
    #pragma unroll
    for (int ti=0; ti<2; ++ti){
      #pragma unroll
      for (int te=0; te<4; ++te){
        int ecol = wc*64+te*16+lc;
        #pragma unroll
        for (int r=0;r<4;r++){
          int i = wr*32+ti*16+lr*4+r;
          ob[(size_t)(c*64+i)*1024 + ecol] = f2bf(accO[ti][te][r]);
        }
      }
    }
    __syncthreads();
    #pragma unroll
    for (int te=0; te<4; ++te){
      #pragma unroll
      for (int td=0; td<4; ++td){
        int dk = wc*64+td*16+lc;
        #pragma unroll
        for (int r=0;r<4;r++){
          int erow = wr*64+te*16+lr*4+r;
          Ts[erow*136 + dk] = f2bf(accT[te][td][r]);
        }
      }
    }
    __syncthreads();
  }
}

// ---------- combine + per-head RMSNorm ----------
__global__ __launch_bounds__(256) void k_comb(const u16* __restrict__ o, const int* __restrict__ sel,
  const float* __restrict__ rw, const int* __restrict__ slot_of, const int* __restrict__ meta,
  const float* __restrict__ nw, u16* __restrict__ fin)
{
  int w=threadIdx.x>>6, lane=threadIdx.x&63;
  int tok = blockIdx.x*4 + w;
  int b = tok>>11;
  int sv = sel[tok];
  float acc[16];
  #pragma unroll
  for (int i=0;i<16;i++) acc[i]=0.f;
  #pragma unroll
  for (int kk=0; kk<2; ++kk){
    int e = kk ? ((sv>>8)&255) : (sv&255);
    int j = slot_of[tok*2 + kk];
    if (j < 0) continue;
    float wgt = rw[tok*2+kk];
    int row = meta[96 + b*8 + e] + j;
    const u16* orow = o + (size_t)row*1024 + lane*16;
    #pragma unroll
    for (int q=0;q<2;q++){
      u32x4 v = *(const u32x4*)(orow + q*8);
      #pragma unroll
      for (int t=0;t<4;t++){
        acc[q*8+t*2]   += wgt * bf2f((u16)(v[t]&0xffff));
        acc[q*8+t*2+1] += wgt * bf2f((u16)(v[t]>>16));
      }
    }
  }
  float ssq=0.f;
  #pragma unroll
  for (int i=0;i<16;i++) ssq += acc[i]*acc[i];
  ssq += __shfl_xor(ssq,1,64);
  ssq += __shfl_xor(ssq,2,64);
  ssq += __shfl_xor(ssq,4,64);
  float sc = rsqrtf(ssq*(1.f/128.f) + 1e-5f);
  int cbase = (lane&7)*16;
  u32x4 o0, o1;
  #pragma unroll
  for (int t=0;t<4;t++)
    o0[t] = pack2(acc[2*t]*sc*nw[cbase+2*t], acc[2*t+1]*sc*nw[cbase+2*t+1]);
  #pragma unroll
  for (int t=0;t<4;t++)
    o1[t] = pack2(acc[8+2*t]*sc*nw[cbase+8+2*t], acc[8+2*t+1]*sc*nw[cbase+8+2*t+1]);
  u16* fp = fin + (size_t)tok*1024 + lane*16;
  *(u32x4*)fp     = o0;
  *(u32x4*)(fp+8) = o1;
}

// ---------- host launcher ----------
extern "C" void kernel_launch(void* const* d_in, const int* in_sizes, int n_in,
                              void* d_out, int out_size, void* d_ws, size_t ws_size,
                              hipStream_t stream)
{
  (void)in_sizes; (void)n_in;
  const float* x     = (const float*)d_in[0];
  const float* gate  = (const float*)d_in[1];
  const float* q_w   = (const float*)d_in[2];
  const float* k_w   = (const float*)d_in[3];
  const float* v_w   = (const float*)d_in[4];
  const float* fmq1  = (const float*)d_in[5];
  const float* fmq2  = (const float*)d_in[6];
  const float* fmk1  = (const float*)d_in[7];
  const float* fmk2  = (const float*)d_in[8];
  const float* norm_w= (const float*)d_in[9];
  const float* o_w   = (const float*)d_in[10];
  float* out = (float*)d_out;

  uint8_t* ws = (uint8_t*)d_ws;
  size_t off = 0;
  auto alloc = [&](size_t bytes)->void*{ void* p = ws + off; off += (bytes + 255) & ~(size_t)255; return p; };
  int*   meta = (int*)alloc(4096);
  int*   sel  = (int*)alloc(8192*4);
  float* rwb  = (float*)alloc(8192*2*4);
  int*   slot = (int*)alloc(16384*4);
  int*   srcf = (int*)alloc((size_t)32*2048*4);
  int*   tokm = (int*)alloc((size_t)RMAX*4);
  u16* wA = (u16*)alloc((size_t)2097152*2);            // q cat weights (2048x1024)
  u16* wB = (u16*)alloc((size_t)8*2097152*2);          // k cat weights per expert
  u16* xb  = (u16*)alloc((size_t)8192*1024*2);         // bf16(x), token space
  u16* xg  = (u16*)alloc((size_t)RMAX*1024*2);
  u16* qh  = (u16*)alloc((size_t)8192*1024*2);         // q-hat, token space
  u16* kh  = (u16*)alloc((size_t)RMAX*1024*2);
  u16* vv  = (u16*)alloc((size_t)RMAX*1024*2);
  if (off > ws_size){
    hipMemsetAsync(d_out, 0x7F, (size_t)out_size*4, stream);
    return;
  }
  u16* ob  = xg;    // reuse after GEMMs consumed xg
  u16* fin = qh;    // reuse after attn consumed qh
  u16* wOb = wA;    // reuse after k_gemmQK consumed wA
  u16* wVb = wB;    // reuse after k_gemmQK consumed wB

  k_pre<<<3456,256,0,stream>>>(x, gate, sel, rwb, q_w, k_w, fmq1, fmq2, fmk1, fmk2, wA, wB, xb);
  k_count<<<32,256,0,stream>>>(sel, slot, srcf, meta);
  k_bases<<<1,64,0,stream>>>(meta);
  k_gather<<<dim3(32,32),256,0,stream>>>(x, srcf, meta, xg, tokm);
  k_gemmQK<<<1792,512,0,stream>>>(xb, xg, wA, wB, qh, kh, meta);
  k_cvtVO<<<288,256,0,stream>>>(v_w, o_w, wVb, wOb);
  k_gemmS<1,0><<<dim3(4,160),512,0,stream>>>(xg, wVb, vv, nullptr, meta, 0);
  k_attn<<<256,256,0,stream>>>(qh, kh, vv, ob, meta, tokm);
  k_comb<<<2048,256,0,stream>>>(ob, sel, rwb, slot, meta, norm_w, fin);
  k_gemmS<0,1><<<dim3(4,64),512,0,stream>>>(fin, wOb, nullptr, out, meta, 8192);
}

// Round 9
// 416.652 us; speedup vs baseline: 1.9379x; 1.0413x over previous
//
#include <hip/hip_runtime.h>
#include <stdint.h>

// ---------- types / helpers ----------
typedef unsigned short u16;
typedef unsigned int   u32;
typedef __attribute__((ext_vector_type(4))) float f32x4;
typedef __attribute__((ext_vector_type(4))) u32   u32x4;
typedef __attribute__((ext_vector_type(8))) __bf16 bf16x8;

#define MFMA16(a,b,c) __builtin_amdgcn_mfma_f32_16x16x32_bf16((a),(b),(c),0,0,0)

#define QSCALE 0.08838834764831845f   // 128^-0.5
#define RMAX   20480                  // sum roundup(min(n,2048),128) <= 16384+32*127

__device__ __forceinline__ float bf2f(u16 x){ u32 u=((u32)x)<<16; float f; __builtin_memcpy(&f,&u,4); return f; }
__device__ __forceinline__ u16 f2bf(float f){ u32 u; __builtin_memcpy(&u,&f,4); u = u + 0x7FFFu + ((u>>16)&1u); return (u16)(u>>16); }
__device__ __forceinline__ u32 pack2(float a, float b){ return (u32)f2bf(a) | ((u32)f2bf(b)<<16); }

// async global->LDS, 16B per lane
__device__ __forceinline__ void gl_lds(const u16* g, u16* l){
  __builtin_amdgcn_global_load_lds(
      (const __attribute__((address_space(1))) void*)g,
      (__attribute__((address_space(3))) void*)l, 16, 0, 0);
}

// transposed-tile addr with octet swizzle: row stride 72 u16; octet = (off8)>>3
#define TSW(row, oct) ((row)*72 + ((((oct) ^ (((row)>>3)&7)))<<3))

// meta layout (ints): [0,32) n  [32,64) nact  [64,96) npad  [96,129) base
// [129,161) nchunks  [161] R_total  [192,352) 128-tile -> group map

// ---------- device bodies for fused pre-pass ----------
__device__ __forceinline__ void cvt_body(const float* __restrict__ s, u16* __restrict__ d,
                                         long n8, int lb, int nb){
  long idx = (long)lb*256 + threadIdx.x;
  long stride = (long)nb*256;
  for (long i=idx; i<n8; i+=stride){
    const float* p = s + i*8;
    f32x4 a = *(const f32x4*)p;
    f32x4 b = *(const f32x4*)(p+4);
    u32x4 o;
    o[0]=pack2(a[0],a[1]); o[1]=pack2(a[2],a[3]); o[2]=pack2(b[0],b[1]); o[3]=pack2(b[2],b[3]);
    *(u32x4*)(d + i*8) = o;
  }
}

// route + write bf16(x): wave w holds token row in xv registers
__device__ __forceinline__ void route_body(const float* __restrict__ x, const float* __restrict__ gw,
  int* __restrict__ sel, float* __restrict__ rw, u16* __restrict__ xb, int lb)
{
  int w = threadIdx.x>>6, lane = threadIdx.x&63;
  int tok = lb*4 + w;
  const float* xr = x + (size_t)tok*1024 + lane*16;
  f32x4 xv[4];
  #pragma unroll
  for (int q=0;q<4;q++) xv[q] = *(const f32x4*)(xr + q*4);
  // bf16 row store (two 16B stores per lane)
  {
    u16* xrow = xb + (size_t)tok*1024 + lane*16;
    u32x4 o0, o1;
    o0[0]=pack2(xv[0][0],xv[0][1]); o0[1]=pack2(xv[0][2],xv[0][3]);
    o0[2]=pack2(xv[1][0],xv[1][1]); o0[3]=pack2(xv[1][2],xv[1][3]);
    o1[0]=pack2(xv[2][0],xv[2][1]); o1[1]=pack2(xv[2][2],xv[2][3]);
    o1[2]=pack2(xv[3][0],xv[3][1]); o1[3]=pack2(xv[3][2],xv[3][3]);
    *(u32x4*)xrow     = o0;
    *(u32x4*)(xrow+8) = o1;
  }
  float part[8];
  #pragma unroll
  for (int e=0;e<8;e++){
    const float* g = gw + e*1024 + lane*16;
    float s = 0.f;
    #pragma unroll
    for (int q=0;q<4;q++){
      f32x4 gv = *(const f32x4*)(g + q*4);
      s += xv[q][0]*gv[0] + xv[q][1]*gv[1] + xv[q][2]*gv[2] + xv[q][3]*gv[3];
    }
    part[e]=s;
  }
  #pragma unroll
  for (int e=0;e<8;e++){
    float v = part[e];
    #pragma unroll
    for (int off=32; off>0; off>>=1) v += __shfl_xor(v, off, 64);
    part[e]=v;
  }
  if (lane==0){
    int i0=0; float m0=part[0];
    #pragma unroll
    for (int e=1;e<8;e++) if (part[e]>m0){ m0=part[e]; i0=e; }
    int i1=0; float m1=-3.4e38f;
    #pragma unroll
    for (int e=0;e<8;e++) if (e!=i0 && part[e]>m1){ m1=part[e]; i1=e; }
    sel[tok] = i0 | (i1<<8);
    float e1 = expf(m1-m0);
    float inv = 1.f/(1.f+e1);
    rw[tok*2+0] = inv;
    rw[tok*2+1] = e1*inv;
  }
}

__device__ __forceinline__ void prep_body(
  const float* __restrict__ q_w, const float* __restrict__ k_w,
  const float* __restrict__ fmq1, const float* __restrict__ fmq2,
  const float* __restrict__ fmk1, const float* __restrict__ fmk2,
  u16* __restrict__ wA, u16* __restrict__ wB, int l, u16* shmem)
{
  int gi = l>>3;
  int c0 = (l&7)*128;
  const float* fm; const float* ws; u16* wd;
  if (gi < 8)      { int h=gi;    fm=fmq1; ws=q_w + (size_t)h*131072; wd=wA + (size_t)h*262144; }
  else if (gi < 16){ int h=gi-8;  fm=fmq2; ws=q_w + (size_t)h*131072; wd=wA + (size_t)h*262144 + 131072; }
  else if (gi < 80){ int t=gi-16, e=t>>3, h=t&7; fm=fmk1; ws=k_w + (size_t)(e*8+h)*131072; wd=wB + (size_t)e*2097152 + (size_t)h*262144; }
  else             { int t=gi-80, e=t>>3, h=t&7; fm=fmk2; ws=k_w + (size_t)(e*8+h)*131072; wd=wB + (size_t)e*2097152 + (size_t)h*262144 + 131072; }
  u16* Af = shmem;
  u16* Bf = shmem + 128*136;
  int tid = threadIdx.x;
  for (int i=tid; i<4096; i+=256){
    int row = i>>5, col = (i&31)*4;
    f32x4 v = *(const f32x4*)&fm[row*128 + col];
    u16* dp = &Af[row*136 + col];
    *(u32*)dp     = pack2(v[0],v[1]);
    *(u32*)(dp+2) = pack2(v[2],v[3]);
  }
  for (int i=tid; i<4096; i+=256){
    int dd = i>>5, cq = (i&31)*4;
    f32x4 v = *(const f32x4*)&ws[(size_t)dd*1024 + c0 + cq];
    #pragma unroll
    for (int j=0;j<4;j++){
      int c = cq+j;
      Bf[c*136 + (dd ^ (((c>>2)&3)<<3))] = f2bf(v[j]);
    }
  }
  __syncthreads();
  int lane=tid&63, w=tid>>6, wr=w>>1, wc=w&1, lc=lane&15, lr=lane>>4;
  const f32x4 Z4 = {0.f,0.f,0.f,0.f};
  f32x4 acc[4][4];
  #pragma unroll
  for (int i=0;i<4;i++){
    #pragma unroll
    for (int j=0;j<4;j++) acc[i][j]=Z4;
  }
  #pragma unroll
  for (int kk=0; kk<4; ++kk){
    bf16x8 a[4], b[4];
    #pragma unroll
    for (int mi=0;mi<4;mi++)
      a[mi] = *(const bf16x8*)&Af[(wr*64+mi*16+lc)*136 + kk*32 + lr*8];
    #pragma unroll
    for (int ni=0;ni<4;ni++){
      int c = wc*64+ni*16+lc;
      b[ni] = *(const bf16x8*)&Bf[c*136 + ((kk*32 + lr*8) ^ (((c>>2)&3)<<3))];
    }
    #pragma unroll
    for (int mi=0;mi<4;mi++){
      #pragma unroll
      for (int ni=0;ni<4;ni++)
        acc[mi][ni] = MFMA16(a[mi], b[ni], acc[mi][ni]);
    }
  }
  int r0=lr*4;
  #pragma unroll
  for (int mi=0;mi<4;mi++){
    #pragma unroll
    for (int ni=0;ni<4;ni++){
      int col = c0 + wc*64 + ni*16 + lc;
      #pragma unroll
      for (int r=0;r<4;r++){
        int row = wr*64 + mi*16 + r0 + r;
        wd[(size_t)row*1024 + col] = f2bf(acc[mi][ni][r]);
      }
    }
  }
}

// ---------- fused pre-pass: route+xb (0..2047) + prep (2048..3199) + cvt v_w (3200..3455) ----------
__global__ __launch_bounds__(256) void k_pre(
  const float* __restrict__ x, const float* __restrict__ gw,
  int* __restrict__ sel, float* __restrict__ rw,
  const float* __restrict__ q_w, const float* __restrict__ k_w,
  const float* __restrict__ fmq1, const float* __restrict__ fmq2,
  const float* __restrict__ fmk1, const float* __restrict__ fmk2,
  u16* __restrict__ wA, u16* __restrict__ wB, u16* __restrict__ xb,
  const float* __restrict__ v_w, u16* __restrict__ wVb)
{
  __shared__ __align__(16) u16 shmem[2*128*136];
  int bid = blockIdx.x;
  if (bid < 2048)      route_body(x, gw, sel, rw, xb, bid);
  else if (bid < 3200) prep_body(q_w, k_w, fmq1, fmq2, fmk1, fmk2, wA, wB, bid-2048, shmem);
  else                 cvt_body(v_w, wVb, 1048576L, bid-3200, 256);
}

// ---------- small cvt: o_w -> wOb ----------
__global__ __launch_bounds__(256) void k_cvtO(const float* __restrict__ o_w, u16* __restrict__ wOb){
  cvt_body(o_w, wOb, 131072L, blockIdx.x, 32);
}

// ---------- per-(b,e) counting sort ----------
__global__ __launch_bounds__(256) void k_count(const int* __restrict__ sel,
  int* __restrict__ slot_of, int* __restrict__ src_of, int* __restrict__ meta)
{
  int g = blockIdx.x, b = g>>3, e = g&7;
  int tid = threadIdx.x;
  __shared__ int cn[256];
  unsigned char ex[16];
  int cnt=0;
  #pragma unroll
  for (int i=0;i<16;i++){
    int t = tid*16+i;
    int sv = sel[b*2048 + (t>>1)];
    int ee = (t&1) ? ((sv>>8)&255) : (sv&255);
    ex[i]=(unsigned char)ee;
    cnt += (ee==e);
  }
  cn[tid]=cnt;
  __syncthreads();
  for (int off=1; off<256; off<<=1){
    int v = (tid>=off) ? cn[tid-off] : 0;
    __syncthreads();
    cn[tid] += v;
    __syncthreads();
  }
  int total = cn[255];
  int run = cn[tid]-cnt;
  int shift = total>2048 ? total-2048 : 0;
  #pragma unroll
  for (int i=0;i<16;i++){
    int t = tid*16+i;
    if (ex[i]==e){
      int j = run - shift;
      run++;
      slot_of[b*4096 + t] = (j>=0)? j : -1;
      if (j>=0) src_of[g*2048 + j] = t;
    }
  }
  if (tid==0) meta[g]=total;
}

// ---------- group bases + tile->group map ----------
__global__ void k_bases(int* meta){
  if (threadIdx.x || blockIdx.x) return;
  int basev=0, t=0;
  meta[96]=0;
  for (int g=0; g<32; ++g){
    int n = meta[g];
    int nact = n<2048 ? n : 2048;
    int npad = (nact+127)&~127;
    meta[32+g]=nact;
    meta[64+g]=npad;
    meta[129+g]=(nact+63)>>6;
    for (int i=0;i<(npad>>7);++i) meta[192+t++]=g;
    basev += npad;
    meta[97+g]=basev;
  }
  meta[161]=basev;
}

// ---------- gather bf16 rows -> compact + row->token map ----------
__global__ __launch_bounds__(256) void k_gather(const u16* __restrict__ xb,
  const int* __restrict__ src_of, const int* __restrict__ meta, u16* __restrict__ xg,
  int* __restrict__ tokmap)
{
  int g = blockIdx.y, jb = blockIdx.x;
  int npad = meta[64+g];
  if (jb*64 >= npad) return;
  int nact = meta[32+g], base = meta[96+g];
  int tid = threadIdx.x;
  int j = jb*64 + (tid>>2);
  int quart = tid&3;
  int src = (j<nact) ? src_of[g*2048+j] : -1;
  int token = (src>=0) ? ((g>>3)*2048 + (src>>1)) : 0;
  if (quart==0) tokmap[base+j] = token;
  u16* orow = xg + ((size_t)(base+j))*1024 + quart*256;
  if (src>=0){
    const u16* xr = xb + (size_t)token*1024 + quart*256;
    #pragma unroll
    for (int i=0;i<256;i+=8) *(u32x4*)(orow+i) = *(const u32x4*)(xr+i);
  } else {
    u32x4 z = {0,0,0,0};
    #pragma unroll
    for (int i=0;i<256;i+=8) *(u32x4*)(orow+i)=z;
  }
}

// ======== fused q+k+v 128x256 8-wave GEMM, depth-2 counted-vmcnt (T4) + swizzle (T2) ========
// blocks [0,512): q dual (A=xb, W=wA, M=8192, *QSCALE)
// blocks [512,1792): k dual (A=xg, W=wB per-expert)
// blocks [1792,2432): v single (A=xg, W=wVb per-expert, N=1024)
__global__ __launch_bounds__(512) void k_gemmQKV(const u16* __restrict__ xb, const u16* __restrict__ xg,
  const u16* __restrict__ wA, const u16* __restrict__ wB, const u16* __restrict__ wVb,
  u16* __restrict__ qh, u16* __restrict__ kh, u16* __restrict__ vv, const int* __restrict__ meta)
{
  int bid = blockIdx.x;
  int role, tm, tn;
  const u16 *A, *Wp; u16* outB;
  if (bid < 512){
    role=0; int l=bid, xcd=l&7, jj=l>>3, jd=jj>>3;
    tm=xcd*8+jd; tn=jj&7;
    A=xb; Wp=wA + (size_t)tn*262144; outB=qh;
  } else if (bid < 1792){
    role=1; int l=bid-512, xcd=l&7, jj=l>>3, jd=jj>>3;
    tm=xcd*20+jd; tn=jj&7;
    if (tm*128 >= meta[161]) return;
    A=xg; Wp=wB + (size_t)(meta[192+tm]&7)*2097152 + (size_t)tn*262144; outB=kh;
  } else {
    role=2; int l=bid-1792, xcd=l&7, jj=l>>3, jd=jj>>2;
    tm=xcd*20+jd; tn=jj&3;
    if (tm*128 >= meta[161]) return;
    A=xg; Wp=wVb + (size_t)(meta[192+tm]&7)*1048576 + (size_t)tn*262144; outB=vv;
  }

  __shared__ __align__(16) u16 smem[73728];   // 144 KB

  int tid=threadIdx.x, lane=tid&63;
  int w=tid>>6, wr=w>>2, wc=w&3, lc=lane&15, lr=lane>>4;
  int swz = lc&7;
  const f32x4 Z4 = {0.f,0.f,0.f,0.f};
  f32x4 acc[4][4];
  #pragma unroll
  for(int i=0;i<4;i++){
    #pragma unroll
    for(int j2=0;j2<4;j2++) acc[i][j2]=Z4;
  }
  size_t lanoff = (size_t)(tid>>3)*1024 + (size_t)(((tid&7)^((tid>>3)&7))*8);
  const u16* Ag = A  + (size_t)tm*131072 + lanoff;
  const u16* Bg = Wp + lanoff;
  int lo = tid*8;

  #define STAGEF(ao, bo, kt) { \
    const u16* ga = Ag + (kt)*64; const u16* gb = Bg + (kt)*64; \
    gl_lds(ga,                 &smem[(ao) + lo]); \
    gl_lds(ga + (size_t)65536, &smem[(ao) + 4096 + lo]); \
    gl_lds(gb,                  &smem[(bo) + lo]); \
    gl_lds(gb + (size_t)65536,  &smem[(bo) + 4096 + lo]); \
    gl_lds(gb + (size_t)131072, &smem[(bo) + 8192 + lo]); \
    gl_lds(gb + (size_t)196608, &smem[(bo) + 12288 + lo]); }

  STAGEF(0, 24576, 0);
  STAGEF(8192, 40960, 1);
  int cur = 0;
  for (int kt=0; kt<16; ++kt){
    if (kt<15) asm volatile("s_waitcnt vmcnt(6)" ::: "memory");
    else       asm volatile("s_waitcnt vmcnt(0)" ::: "memory");
    __builtin_amdgcn_s_barrier();
    if (kt<14){
      int nid = kt+2; nid -= (nid/3)*3;
      STAGEF(nid*8192, 24576+nid*16384, kt+2);
    }
    int ao = cur*8192, bo = 24576 + cur*16384;
    __builtin_amdgcn_s_setprio(1);
    #pragma unroll
    for (int kk=0; kk<2; ++kk){
      bf16x8 a[4], b[4];
      #pragma unroll
      for (int mi=0;mi<4;mi++){
        int row = wr*64+mi*16+lc;
        a[mi] = *(const bf16x8*)&smem[ao + row*64 + (((kk*4+lr)^swz)<<3)];
      }
      #pragma unroll
      for (int ni=0;ni<4;ni++){
        int row = wc*64+ni*16+lc;
        b[ni] = *(const bf16x8*)&smem[bo + row*64 + (((kk*4+lr)^swz)<<3)];
      }
      #pragma unroll
      for (int mi=0;mi<4;mi++){
        #pragma unroll
        for (int ni=0;ni<4;ni++)
          acc[mi][ni] = MFMA16(a[mi], b[ni], acc[mi][ni]);
      }
    }
    __builtin_amdgcn_s_setprio(0);
    cur = (cur==2)?0:cur+1;
  }
  __syncthreads();
  if (role < 2){
    // dual Hadamard: waves wc>=2 hold factor-2 (cat rows 128..255)
    if (wc >= 2){
      #pragma unroll
      for (int mi=0;mi<4;mi++){
        #pragma unroll
        for (int ni=0;ni<4;ni++){
          int col = (wc-2)*64 + ni*16 + lc;
          #pragma unroll
          for (int r=0;r<4;r++)
            ((float*)smem)[(wr*64+mi*16+lr*4+r)*129 + col] = acc[mi][ni][r];
        }
      }
    }
    __syncthreads();
    if (wc < 2){
      float scl = (role==0) ? QSCALE : 1.0f;
      #pragma unroll
      for (int mi=0;mi<4;mi++){
        #pragma unroll
        for (int ni=0;ni<4;ni++){
          int col = wc*64 + ni*16 + lc;
          #pragma unroll
          for (int r=0;r<4;r++){
            int row = wr*64+mi*16+lr*4+r;
            float v = acc[mi][ni][r] * ((float*)smem)[row*129 + col] * scl;
            outB[(size_t)(tm*128+row)*1024 + tn*128 + col] = f2bf(v);
          }
        }
      }
    }
  } else {
    // v single: write full 256 cols
    #pragma unroll
    for (int mi=0;mi<4;mi++){
      #pragma unroll
      for (int ni=0;ni<4;ni++){
        int col = tn*256 + wc*64 + ni*16 + lc;
        #pragma unroll
        for (int r=0;r<4;r++){
          int row = tm*128 + wr*64 + mi*16 + lr*4 + r;
          outB[(size_t)row*1024 + col] = f2bf(acc[mi][ni][r]);
        }
      }
    }
  }
  #undef STAGEF
}

// ======== 128x256 8-wave single GEMM, T4+T2 pipeline (bf16 W) — final out proj ========
__global__ __launch_bounds__(512) void k_gemmO(const u16* __restrict__ A, const u16* __restrict__ W,
  float* __restrict__ outF)
{
  int tnN = gridDim.x;
  int bid = blockIdx.y*tnN + blockIdx.x;
  int chunk = gridDim.y >> 3;
  int xcd = bid & 7, j = bid >> 3;
  int jd = j / tnN;
  int tm = xcd*chunk + jd;
  int tn = j - jd*tnN;

  __shared__ __align__(16) u16 smem[73728];

  int tid=threadIdx.x, lane=tid&63;
  int w=tid>>6, wr=w>>2, wc=w&3, lc=lane&15, lr=lane>>4;
  int swz = lc&7;
  const f32x4 Z4 = {0.f,0.f,0.f,0.f};
  f32x4 acc[4][4];
  #pragma unroll
  for(int i=0;i<4;i++){
    #pragma unroll
    for(int j2=0;j2<4;j2++) acc[i][j2]=Z4;
  }
  size_t lanoff = (size_t)(tid>>3)*1024 + (size_t)(((tid&7)^((tid>>3)&7))*8);
  const u16* Ag = A + (size_t)tm*131072 + lanoff;
  const u16* Bg = W + (size_t)tn*262144 + lanoff;
  int lo = tid*8;

  #define STAGEO(ao, bo, kt) { \
    const u16* ga = Ag + (kt)*64; const u16* gb = Bg + (kt)*64; \
    gl_lds(ga,                 &smem[(ao) + lo]); \
    gl_lds(ga + (size_t)65536, &smem[(ao) + 4096 + lo]); \
    gl_lds(gb,                  &smem[(bo) + lo]); \
    gl_lds(gb + (size_t)65536,  &smem[(bo) + 4096 + lo]); \
    gl_lds(gb + (size_t)131072, &smem[(bo) + 8192 + lo]); \
    gl_lds(gb + (size_t)196608, &smem[(bo) + 12288 + lo]); }

  STAGEO(0, 24576, 0);
  STAGEO(8192, 40960, 1);
  int cur = 0;
  for (int kt=0; kt<16; ++kt){
    if (kt<15) asm volatile("s_waitcnt vmcnt(6)" ::: "memory");
    else       asm volatile("s_waitcnt vmcnt(0)" ::: "memory");
    __builtin_amdgcn_s_barrier();
    if (kt<14){
      int nid = kt+2; nid -= (nid/3)*3;
      STAGEO(nid*8192, 24576+nid*16384, kt+2);
    }
    int ao = cur*8192, bo = 24576 + cur*16384;
    __builtin_amdgcn_s_setprio(1);
    #pragma unroll
    for (int kk=0; kk<2; ++kk){
      bf16x8 a[4], b[4];
      #pragma unroll
      for (int mi=0;mi<4;mi++){
        int row = wr*64+mi*16+lc;
        a[mi] = *(const bf16x8*)&smem[ao + row*64 + (((kk*4+lr)^swz)<<3)];
      }
      #pragma unroll
      for (int ni=0;ni<4;ni++){
        int row = wc*64+ni*16+lc;
        b[ni] = *(const bf16x8*)&smem[bo + row*64 + (((kk*4+lr)^swz)<<3)];
      }
      #pragma unroll
      for (int mi=0;mi<4;mi++){
        #pragma unroll
        for (int ni=0;ni<4;ni++)
          acc[mi][ni] = MFMA16(a[mi], b[ni], acc[mi][ni]);
      }
    }
    __builtin_amdgcn_s_setprio(0);
    cur = (cur==2)?0:cur+1;
  }
  #pragma unroll
  for (int mi=0;mi<4;mi++){
    #pragma unroll
    for (int ni=0;ni<4;ni++){
      int col = tn*256 + wc*64 + ni*16 + lc;
      #pragma unroll
      for (int r=0;r<4;r++){
        int row = tm*128 + wr*64 + mi*16 + lr*4 + r;
        outF[(size_t)row*1024 + col] = acc[mi][ni][r];
      }
    }
  }
  #undef STAGEO
}

// ---------- chunked causal linear attention, one block per (group, head) ----------
// Ts ping-pong: 3 barriers/chunk instead of 4
__global__ __launch_bounds__(256,1) void k_attn(const u16* __restrict__ qv, const u16* __restrict__ kv,
  const u16* __restrict__ vv, u16* __restrict__ o, const int* __restrict__ meta,
  const int* __restrict__ tokmap)
{
  int g = blockIdx.x>>3, h = blockIdx.x&7;
  int nch = meta[129+g];
  if (nch==0) return;
  int base = meta[96+g];
  __shared__ __align__(16) u16 Qs[64*136];
  __shared__ __align__(16) u16 Ks[64*136];
  __shared__ __align__(16) u16 KTs[128*72];
  __shared__ __align__(16) u16 VTs[128*72];
  __shared__ __align__(16) u16 Ts[2*128*136];
  __shared__ __align__(16) u16 Ps[64*72];
  int tid=threadIdx.x, w=tid>>6, lane=tid&63;
  int wr=w>>1, wc=w&1;
  int lr=lane>>4, lc=lane&15;
  {
    u32x4 z={0,0,0,0};
    for (int i=tid; i<128*136/8; i+=256) *(u32x4*)&Ts[i*8]=z;
  }
  const f32x4 Z4 = {0.f,0.f,0.f,0.f};
  f32x4 accT[4][4];
  #pragma unroll
  for (int i=0;i<4;i++){
    #pragma unroll
    for (int j=0;j<4;j++) accT[i][j]=Z4;
  }
  __syncthreads();
  const u16* kb = kv + (size_t)base*1024 + h*128;
  const u16* vb = vv + (size_t)base*1024 + h*128;
  u16* ob = o + (size_t)base*1024 + h*128;
  int tso = 0;                      // current Ts buffer offset (u16 units)

  for (int c=0; c<nch; ++c){
    #pragma unroll
    for (int it=0; it<4; ++it){
      int id = tid + it*256;
      int row = id>>4, kc = id&15;
      int tok = tokmap[base + c*64 + row];
      *(u32x4*)&Qs[row*136 + kc*8] = *(const u32x4*)(qv + (size_t)tok*1024 + h*128 + kc*8);
      *(u32x4*)&Ks[row*136 + kc*8] = *(const u32x4*)(kb + (size_t)(c*64+row)*1024 + kc*8);
    }
    #pragma unroll
    for (int it=0; it<4; ++it){
      int id = tid + it*256;
      int j = id>>4, dg = id&15;
      int col = (((j>>3) ^ (dg&7))<<3) + (j&7);
      u32x4 kx = *(const u32x4*)(kb + (size_t)(c*64+j)*1024 + dg*8);
      u32x4 vx = *(const u32x4*)(vb + (size_t)(c*64+j)*1024 + dg*8);
      #pragma unroll
      for (int t=0;t<4;t++){
        KTs[(dg*8+t*2  )*72 + col] = (u16)(kx[t]&0xffff);
        KTs[(dg*8+t*2+1)*72 + col] = (u16)(kx[t]>>16);
        VTs[(dg*8+t*2  )*72 + col] = (u16)(vx[t]&0xffff);
        VTs[(dg*8+t*2+1)*72 + col] = (u16)(vx[t]>>16);
      }
    }
    __syncthreads();
    bf16x8 qf[2][4];
    #pragma unroll
    for (int ti=0; ti<2; ++ti){
      #pragma unroll
      for (int ks=0; ks<4; ++ks)
        qf[ti][ks] = *(const bf16x8*)&Qs[(wr*32+ti*16+lc)*136 + ks*32 + lr*8];
    }
    f32x4 accO[2][4];
    #pragma unroll
    for (int i=0;i<2;i++){
      #pragma unroll
      for (int j=0;j<4;j++) accO[i][j]=Z4;
    }
    #pragma unroll
    for (int ks=0; ks<4; ++ks){
      bf16x8 bt[4];
      #pragma unroll
      for (int te=0; te<4; ++te)
        bt[te] = *(const bf16x8*)&Ts[tso + (wc*64+te*16+lc)*136 + ks*32 + lr*8];
      #pragma unroll
      for (int ti=0; ti<2; ++ti){
        #pragma unroll
        for (int te=0; te<4; ++te)
          accO[ti][te] = MFMA16(qf[ti][ks], bt[te], accO[ti][te]);
      }
    }
    f32x4 accP[2][2];
    #pragma unroll
    for (int i=0;i<2;i++){
      #pragma unroll
      for (int j=0;j<2;j++) accP[i][j]=Z4;
    }
    #pragma unroll
    for (int ks=0; ks<4; ++ks){
      bf16x8 bk[2];
      #pragma unroll
      for (int tj=0; tj<2; ++tj)
        bk[tj] = *(const bf16x8*)&Ks[(wc*32+tj*16+lc)*136 + ks*32 + lr*8];
      #pragma unroll
      for (int ti=0; ti<2; ++ti){
        #pragma unroll
        for (int tj=0; tj<2; ++tj)
          accP[ti][tj] = MFMA16(qf[ti][ks], bk[tj], accP[ti][tj]);
      }
    }
    #pragma unroll
    for (int ti=0; ti<2; ++ti){
      #pragma unroll
      for (int tj=0; tj<2; ++tj){
        #pragma unroll
        for (int r=0;r<4;r++){
          int i = wr*32+ti*16+lr*4+r;
          int j = wc*32+tj*16+lc;
          Ps[i*72 + j] = f2bf( (j<=i) ? accP[ti][tj][r] : 0.f );
        }
      }
    }
    __syncthreads();
    #pragma unroll
    for (int ks=0; ks<2; ++ks){
      bf16x8 ap[2], bv[4];
      #pragma unroll
      for (int ti=0; ti<2; ++ti)
        ap[ti] = *(const bf16x8*)&Ps[(wr*32+ti*16+lc)*72 + ks*32 + lr*8];
      #pragma unroll
      for (int te=0; te<4; ++te)
        bv[te] = *(const bf16x8*)&VTs[TSW(wc*64+te*16+lc, ks*4+lr)];
      #pragma unroll
      for (int ti=0; ti<2; ++ti){
        #pragma unroll
        for (int te=0; te<4; ++te)
          accO[ti][te] = MFMA16(ap[ti], bv[te], accO[ti][te]);
      }
    }
    #pragma unroll
    for (int ks=0; ks<2; ++ks){
      bf16x8 av[4], bk2[4];
      #pragma unroll
      for (int te=0; te<4; ++te)
        av[te] = *(const bf16x8*)&VTs[TSW(wr*64+te*16+lc, ks*4+lr)];
      #pragma unroll
      for (int td=0; td<4; ++td)
        bk2[td] = *(const bf16x8*)&KTs[TSW(wc*64+td*16+lc, ks*4+lr)];
      #pragma unroll
      for (int te=0; te<4; ++te){
        #pragma unroll
        for (int td=0; td<4; ++td)
          accT[te][td] = MFMA16(av[te], bk2[td], accT[te][td]);
      }
    }
    // refresh bf16 state into the OTHER Ts buffer (no extra barrier needed)
    int tsn = tso ^ (128*136);
    #pragma unroll
    for (int te=0; te<4; ++te){
      #pragma unroll
      for (int td=0; td<4; ++td){
        int dk = wc*64+td*16+lc;
        #pragma unroll
        for (int r=0;r<4;r++){
          int erow = wr*64+te*16+lr*4+r;
          Ts[tsn + erow*136 + dk] = f2bf(accT[te][td][r]);
        }
      }
    }
    // write O chunk (global)
    #pragma unroll
    for (int ti=0; ti<2; ++ti){
      #pragma unroll
      for (int te=0; te<4; ++te){
        int ecol = wc*64+te*16+lc;
        #pragma unroll
        for (int r=0;r<4;r++){
          int i = wr*32+ti*16+lr*4+r;
          ob[(size_t)(c*64+i)*1024 + ecol] = f2bf(accO[ti][te][r]);
        }
      }
    }
    __syncthreads();
    tso = tsn;
  }
}

// ---------- combine + per-head RMSNorm ----------
__global__ __launch_bounds__(256) void k_comb(const u16* __restrict__ o, const int* __restrict__ sel,
  const float* __restrict__ rw, const int* __restrict__ slot_of, const int* __restrict__ meta,
  const float* __restrict__ nw, u16* __restrict__ fin)
{
  int w=threadIdx.x>>6, lane=threadIdx.x&63;
  int tok = blockIdx.x*4 + w;
  int b = tok>>11;
  int sv = sel[tok];
  float acc[16];
  #pragma unroll
  for (int i=0;i<16;i++) acc[i]=0.f;
  #pragma unroll
  for (int kk=0; kk<2; ++kk){
    int e = kk ? ((sv>>8)&255) : (sv&255);
    int j = slot_of[tok*2 + kk];
    if (j < 0) continue;
    float wgt = rw[tok*2+kk];
    int row = meta[96 + b*8 + e] + j;
    const u16* orow = o + (size_t)row*1024 + lane*16;
    #pragma unroll
    for (int q=0;q<2;q++){
      u32x4 v = *(const u32x4*)(orow + q*8);
      #pragma unroll
      for (int t=0;t<4;t++){
        acc[q*8+t*2]   += wgt * bf2f((u16)(v[t]&0xffff));
        acc[q*8+t*2+1] += wgt * bf2f((u16)(v[t]>>16));
      }
    }
  }
  float ssq=0.f;
  #pragma unroll
  for (int i=0;i<16;i++) ssq += acc[i]*acc[i];
  ssq += __shfl_xor(ssq,1,64);
  ssq += __shfl_xor(ssq,2,64);
  ssq += __shfl_xor(ssq,4,64);
  float sc = rsqrtf(ssq*(1.f/128.f) + 1e-5f);
  int cbase = (lane&7)*16;
  u32x4 o0, o1;
  #pragma unroll
  for (int t=0;t<4;t++)
    o0[t] = pack2(acc[2*t]*sc*nw[cbase+2*t], acc[2*t+1]*sc*nw[cbase+2*t+1]);
  #pragma unroll
  for (int t=0;t<4;t++)
    o1[t] = pack2(acc[8+2*t]*sc*nw[cbase+8+2*t], acc[8+2*t+1]*sc*nw[cbase+8+2*t+1]);
  u16* fp = fin + (size_t)tok*1024 + lane*16;
  *(u32x4*)fp     = o0;
  *(u32x4*)(fp+8) = o1;
}

// ---------- host launcher ----------
extern "C" void kernel_launch(void* const* d_in, const int* in_sizes, int n_in,
                              void* d_out, int out_size, void* d_ws, size_t ws_size,
                              hipStream_t stream)
{
  (void)in_sizes; (void)n_in;
  const float* x     = (const float*)d_in[0];
  const float* gate  = (const float*)d_in[1];
  const float* q_w   = (const float*)d_in[2];
  const float* k_w   = (const float*)d_in[3];
  const float* v_w   = (const float*)d_in[4];
  const float* fmq1  = (const float*)d_in[5];
  const float* fmq2  = (const float*)d_in[6];
  const float* fmk1  = (const float*)d_in[7];
  const float* fmk2  = (const float*)d_in[8];
  const float* norm_w= (const float*)d_in[9];
  const float* o_w   = (const float*)d_in[10];
  float* out = (float*)d_out;

  uint8_t* ws = (uint8_t*)d_ws;
  size_t off = 0;
  auto alloc = [&](size_t bytes)->void*{ void* p = ws + off; off += (bytes + 255) & ~(size_t)255; return p; };
  int*   meta = (int*)alloc(4096);
  int*   sel  = (int*)alloc(8192*4);
  float* rwb  = (float*)alloc(8192*2*4);
  int*   slot = (int*)alloc(16384*4);
  int*   srcf = (int*)alloc((size_t)32*2048*4);
  int*   tokm = (int*)alloc((size_t)RMAX*4);
  u16* wA = (u16*)alloc((size_t)2097152*2);            // q cat weights (2048x1024)
  u16* wB = (u16*)alloc((size_t)8*2097152*2);          // k cat weights per expert
  u16* xb  = (u16*)alloc((size_t)8192*1024*2);         // bf16(x), token space
  u16* xg  = (u16*)alloc((size_t)RMAX*1024*2);
  u16* qh  = (u16*)alloc((size_t)8192*1024*2);         // q-hat, token space
  u16* kh  = (u16*)alloc((size_t)RMAX*1024*2);
  u16* vv  = (u16*)alloc((size_t)RMAX*1024*2);
  if (off > ws_size){
    hipMemsetAsync(d_out, 0x7F, (size_t)out_size*4, stream);
    return;
  }
  u16* wVb = (u16*)d_out;   // 17 MB of the 33.5 MB output buffer as scratch (overwritten by k_gemmO)
  u16* ob  = xg;            // reuse after GEMMs consumed xg
  u16* fin = qh;            // reuse after attn consumed qh
  u16* wOb = wA;            // reuse after k_gemmQKV consumed wA

  k_pre<<<3456,256,0,stream>>>(x, gate, sel, rwb, q_w, k_w, fmq1, fmq2, fmk1, fmk2, wA, wB, xb, v_w, wVb);
  k_count<<<32,256,0,stream>>>(sel, slot, srcf, meta);
  k_bases<<<1,64,0,stream>>>(meta);
  k_gather<<<dim3(32,32),256,0,stream>>>(xb, srcf, meta, xg, tokm);
  k_gemmQKV<<<2432,512,0,stream>>>(xb, xg, wA, wB, wVb, qh, kh, vv, meta);
  k_cvtO<<<32,256,0,stream>>>(o_w, wOb);
  k_attn<<<256,256,0,stream>>>(qh, kh, vv, ob, meta, tokm);
  k_comb<<<2048,256,0,stream>>>(ob, sel, rwb, slot, meta, norm_w, fin);
  k_gemmO<<<dim3(4,64),512,0,stream>>>(fin, wOb, out);
}